// Round 10
// baseline (677.212 us; speedup 1.0000x reference)
//
#include <hip/hip_runtime.h>
#include <math.h>

#define B_ 4
#define S_ 2048
#define D_ 1024
#define H_ 2048
#define N_TOK 8192
#define HALO 256
#define VOCAB_ 32000

typedef short bf16x8 __attribute__((ext_vector_type(8)));
typedef float f32x4 __attribute__((ext_vector_type(4)));

__device__ __forceinline__ float sigf(float x) {
  return 1.0f / (1.0f + __expf(-x));
}
__device__ __forceinline__ float bf2f(unsigned short u) {
  union { unsigned int i; float f; } x; x.i = ((unsigned int)u) << 16; return x.f;
}
__device__ __forceinline__ unsigned short f2bf(float f) {
  union { float f; unsigned int i; } x; x.f = f;
  unsigned int r = x.i + 0x7fffu + ((x.i >> 16) & 1u);
  return (unsigned short)(r >> 16);
}

// ---------------------------------------------------------------- gains (f32 tanh)
__global__ __launch_bounds__(256) void k_gains(const int* __restrict__ ids,
    const float* __restrict__ table, float* __restrict__ gains) {
  int i = blockIdx.x*256 + threadIdx.x;
  int id = ids[i];
  id = id < 0 ? 0 : (id >= VOCAB_ ? VOCAB_-1 : id);
  gains[i] = 1.0f + tanhf(table[id]);
}

// ---------------------------------------------------------------- f32 SIMT GEMM (fallback enc/dec)
__global__ __launch_bounds__(256) void k_genc(
    const float* __restrict__ A, int lda,
    const float* __restrict__ W, int ldw, int c0,
    const float* __restrict__ bias,
    const float* __restrict__ gains,
    float* __restrict__ C, int ldc,
    int K, int mode)
{
  __shared__ float As2[16][132];
  __shared__ float Bs[16][128];
  const int tid = threadIdx.x;
  const int tx = tid & 15;
  const int ty = tid >> 4;
  const int bm = blockIdx.y * 128;
  const int bn = blockIdx.x * 128;

  double acc[8][8];
  float part[8][8];
  #pragma unroll
  for (int i = 0; i < 8; ++i)
    #pragma unroll
    for (int j = 0; j < 8; ++j) { acc[i][j] = 0.0; part[i][j] = 0.f; }

  const int e = tid * 8;
  const int ar = e >> 4, ak = e & 15;
  const int bk = e >> 7, bc = e & 127;

  for (int k0 = 0; k0 < K; k0 += 16) {
    {
      const float* pa = A + (size_t)(bm + ar)*lda + k0 + ak;
      float4 v0 = *(const float4*)pa;
      float4 v1 = *(const float4*)(pa + 4);
      As2[ak+0][ar] = v0.x; As2[ak+1][ar] = v0.y;
      As2[ak+2][ar] = v0.z; As2[ak+3][ar] = v0.w;
      As2[ak+4][ar] = v1.x; As2[ak+5][ar] = v1.y;
      As2[ak+6][ar] = v1.z; As2[ak+7][ar] = v1.w;
    }
    {
      const float* pw = W + (size_t)(k0 + bk)*ldw + c0 + bn + bc;
      *(float4*)&Bs[bk][bc]   = *(const float4*)pw;
      *(float4*)&Bs[bk][bc+4] = *(const float4*)(pw + 4);
    }
    __syncthreads();
    #pragma unroll
    for (int kk = 0; kk < 16; ++kk) {
      float a8[8], b8[8];
      *(float4*)&a8[0] = *(const float4*)&As2[kk][ty*8];
      *(float4*)&a8[4] = *(const float4*)&As2[kk][ty*8+4];
      *(float4*)&b8[0] = *(const float4*)&Bs[kk][tx*8];
      *(float4*)&b8[4] = *(const float4*)&Bs[kk][tx*8+4];
      #pragma unroll
      for (int i = 0; i < 8; ++i)
        #pragma unroll
        for (int j = 0; j < 8; ++j)
          part[i][j] += a8[i]*b8[j];
    }
    __syncthreads();
    #pragma unroll
    for (int i = 0; i < 8; ++i)
      #pragma unroll
      for (int j = 0; j < 8; ++j) { acc[i][j] += (double)part[i][j]; part[i][j] = 0.f; }
  }

  #pragma unroll
  for (int i = 0; i < 8; ++i) {
    const int row = bm + ty*8 + i;
    const double g = (mode >= 2) ? (double)gains[row] : 0.0;
    #pragma unroll
    for (int j = 0; j < 8; ++j) {
      const int col = bn + tx*8 + j;
      const size_t idx = (size_t)row*ldc + col;
      if (mode == 0)      C[idx] = (float)acc[i][j];
      else if (mode == 1) C[idx] += (float)acc[i][j];
      else if (mode == 2) C[idx] = (float)(g*((double)C[idx] + acc[i][j]) + (double)bias[c0+col]);
      else                C[idx] = (float)(g*acc[i][j] + (double)bias[c0+col]);
    }
  }
}

// ---------------------------------------------------------------- transpose+split enc_W [1024][2048] f32 -> WhT/WlT [2048][1024] bf16
__global__ __launch_bounds__(256) void k_splitT(const float* __restrict__ in,
    unsigned short* __restrict__ outh, unsigned short* __restrict__ outl) {
  __shared__ unsigned short th[32][33];
  __shared__ unsigned short tl[32][33];
  int c0 = blockIdx.x*32, r0 = blockIdx.y*32;
  int tx = threadIdx.x & 31, ty = threadIdx.x >> 5;
  #pragma unroll
  for (int i = 0; i < 32; i += 8) {
    float x = in[(size_t)(r0+ty+i)*H_ + (c0+tx)];
    unsigned short h = f2bf(x);
    th[ty+i][tx] = h;
    tl[ty+i][tx] = f2bf(x - bf2f(h));
  }
  __syncthreads();
  #pragma unroll
  for (int i = 0; i < 32; i += 8) {
    outh[(size_t)(c0+ty+i)*D_ + (r0+tx)] = th[tx][ty+i];
    outl[(size_t)(c0+ty+i)*D_ + (r0+tx)] = tl[tx][ty+i];
  }
}

// ---------------------------------------------------------------- generic batched transpose+split: in [Z][R][C] f32 -> oh/ol [Z][C][R] bf16
__global__ __launch_bounds__(256) void k_tsplit(const float* __restrict__ in,
    unsigned short* __restrict__ oh, unsigned short* __restrict__ ol,
    int R, int C) {
  __shared__ unsigned short th[32][33];
  __shared__ unsigned short tl[32][33];
  const size_t mat = (size_t)R*C;
  in += (size_t)blockIdx.z * mat;
  oh += (size_t)blockIdx.z * mat;
  ol += (size_t)blockIdx.z * mat;
  int c0 = blockIdx.x*32, r0 = blockIdx.y*32;
  int tx = threadIdx.x & 31, ty = threadIdx.x >> 5;
  #pragma unroll
  for (int i = 0; i < 32; i += 8) {
    float x = in[(size_t)(r0+ty+i)*C + (c0+tx)];
    unsigned short h = f2bf(x);
    th[ty+i][tx] = h;
    tl[ty+i][tx] = f2bf(x - bf2f(h));
  }
  __syncthreads();
  #pragma unroll
  for (int i = 0; i < 32; i += 8) {
    oh[(size_t)(c0+ty+i)*R + (r0+tx)] = th[tx][ty+i];
    ol[(size_t)(c0+ty+i)*R + (r0+tx)] = tl[tx][ty+i];
  }
}

// ---------------------------------------------------------------- row-major f32 -> bf16 hi/lo split (no transpose), 8 elems/thread
__global__ __launch_bounds__(256) void k_asplit(const float* __restrict__ in,
    unsigned short* __restrict__ oh, unsigned short* __restrict__ ol) {
  const size_t i = ((size_t)blockIdx.x*256 + threadIdx.x) * 8;
  float4 v0 = *(const float4*)(in + i);
  float4 v1 = *(const float4*)(in + i + 4);
  float xs[8] = {v0.x, v0.y, v0.z, v0.w, v1.x, v1.y, v1.z, v1.w};
  unsigned int hp[4], lp[4];
  #pragma unroll
  for (int t = 0; t < 4; ++t) {
    unsigned short h0 = f2bf(xs[2*t]);
    unsigned short h1 = f2bf(xs[2*t+1]);
    unsigned short l0 = f2bf(xs[2*t]   - bf2f(h0));
    unsigned short l1 = f2bf(xs[2*t+1] - bf2f(h1));
    hp[t] = (unsigned)h0 | ((unsigned)h1 << 16);
    lp[t] = (unsigned)l0 | ((unsigned)l1 << 16);
  }
  *(uint4*)(oh + i) = make_uint4(hp[0], hp[1], hp[2], hp[3]);
  *(uint4*)(ol + i) = make_uint4(lp[0], lp[1], lp[2], lp[3]);
}

// ---------------------------------------------------------------- enc MFMA GEMM (legacy, in-kernel A split) — fallback tier
__global__ __launch_bounds__(256) void k_egemm(
    const float* __restrict__ A,              // embeds f32 [8192][1024]
    const unsigned short* __restrict__ Bh,    // WhT + chunk offset, [1024][1024] bf16
    const unsigned short* __restrict__ Bl,
    const float* __restrict__ bias,           // enc_b + chunk offset
    const float* __restrict__ gains,
    float* __restrict__ C)                    // cur [8192][1024]
{
  __shared__ __align__(16) unsigned short Ahs[128*40];
  __shared__ __align__(16) unsigned short Als[128*40];
  __shared__ __align__(16) unsigned short Bhs[128*40];
  __shared__ __align__(16) unsigned short Bls[128*40];
  const int tid  = threadIdx.x;
  const int lane = tid & 63;
  const int wave = tid >> 6;
  const int wm = (wave >> 1) * 64;
  const int wn = (wave & 1) * 64;
  const int bm = blockIdx.y * 128;
  const int bn = blockIdx.x * 128;
  const int fml = lane & 15;
  const int q  = lane >> 4;
  const int r0a  = tid >> 2;
  const int sseg = tid & 3;

  f32x4 acc[4][4] = {};

  for (int k0 = 0; k0 < 1024; k0 += 32) {
    #pragma unroll
    for (int half = 0; half < 2; ++half) {
      int r = r0a + half*64;
      const float* pa = A + (size_t)(bm + r)*1024 + k0 + sseg*8;
      float4 v0 = *(const float4*)pa;
      float4 v1 = *(const float4*)(pa + 4);
      float xs[8] = {v0.x, v0.y, v0.z, v0.w, v1.x, v1.y, v1.z, v1.w};
      unsigned int hp[4], lp[4];
      #pragma unroll
      for (int t = 0; t < 4; ++t) {
        unsigned short h0 = f2bf(xs[2*t]);
        unsigned short h1 = f2bf(xs[2*t+1]);
        unsigned short l0 = f2bf(xs[2*t]   - bf2f(h0));
        unsigned short l1 = f2bf(xs[2*t+1] - bf2f(h1));
        hp[t] = (unsigned)h0 | ((unsigned)h1 << 16);
        lp[t] = (unsigned)l0 | ((unsigned)l1 << 16);
      }
      *(uint4*)(&Ahs[r*40 + sseg*8]) = make_uint4(hp[0], hp[1], hp[2], hp[3]);
      *(uint4*)(&Als[r*40 + sseg*8]) = make_uint4(lp[0], lp[1], lp[2], lp[3]);
      *(uint4*)(&Bhs[r*40 + sseg*8]) = *(const uint4*)(Bh + (size_t)(bn + r)*1024 + k0 + sseg*8);
      *(uint4*)(&Bls[r*40 + sseg*8]) = *(const uint4*)(Bl + (size_t)(bn + r)*1024 + k0 + sseg*8);
    }
    __syncthreads();
    bf16x8 afh[4], afl[4], bfh[4], bfl[4];
    #pragma unroll
    for (int i = 0; i < 4; ++i) {
      afh[i] = *(const bf16x8*)(&Ahs[(wm + i*16 + fml)*40 + q*8]);
      afl[i] = *(const bf16x8*)(&Als[(wm + i*16 + fml)*40 + q*8]);
    }
    #pragma unroll
    for (int j = 0; j < 4; ++j) {
      bfh[j] = *(const bf16x8*)(&Bhs[(wn + j*16 + fml)*40 + q*8]);
      bfl[j] = *(const bf16x8*)(&Bls[(wn + j*16 + fml)*40 + q*8]);
    }
    #pragma unroll
    for (int i = 0; i < 4; ++i)
      #pragma unroll
      for (int j = 0; j < 4; ++j) {
        acc[i][j] = __builtin_amdgcn_mfma_f32_16x16x32_bf16(afl[i], bfh[j], acc[i][j], 0, 0, 0);
        acc[i][j] = __builtin_amdgcn_mfma_f32_16x16x32_bf16(afh[i], bfl[j], acc[i][j], 0, 0, 0);
        acc[i][j] = __builtin_amdgcn_mfma_f32_16x16x32_bf16(afh[i], bfh[j], acc[i][j], 0, 0, 0);
      }
    __syncthreads();
  }
  #pragma unroll
  for (int i = 0; i < 4; ++i) {
    #pragma unroll
    for (int j = 0; j < 4; ++j) {
      int col = bn + wn + j*16 + fml;
      float bv = bias[col];
      #pragma unroll
      for (int r = 0; r < 4; ++r) {
        int row = bm + wm + i*16 + q*4 + r;   // C/D: col=lane&15, row=quad*4+reg
        C[(size_t)row*D_ + col] = gains[row]*acc[i][j][r] + bv;
      }
    }
  }
}

// ---------------------------------------------------------------- enc MFMA GEMM v3: pre-split A, B chunk [1024][1024], C ld=1024, XCD swizzle
__global__ __launch_bounds__(256) void k_egemm3(
    const unsigned short* __restrict__ Ah, const unsigned short* __restrict__ Al, // [8192][1024]
    const unsigned short* __restrict__ Bh, const unsigned short* __restrict__ Bl, // [1024][1024]
    const float* __restrict__ bias,           // enc_b + chunk offset
    const float* __restrict__ gains,
    float* __restrict__ C)                    // cur [8192][1024]
{
  __shared__ __align__(16) unsigned short Ahs[128*40];
  __shared__ __align__(16) unsigned short Als[128*40];
  __shared__ __align__(16) unsigned short Bhs[128*40];
  __shared__ __align__(16) unsigned short Bls[128*40];
  const int tid  = threadIdx.x;
  const int lane = tid & 63;
  const int wave = tid >> 6;
  const int wm = (wave >> 1) * 64;
  const int wn = (wave & 1) * 64;
  // XCD-aware bijective swizzle: nwg = 8*64 = 512 (%8==0)
  const int flat = blockIdx.y * 8 + blockIdx.x;
  const int swz  = (flat & 7) * 64 + (flat >> 3);
  const int bn = (swz & 7) * 128;
  const int bm = (swz >> 3) * 128;
  const int fml = lane & 15;
  const int q  = lane >> 4;
  const int r0a  = tid >> 2;
  const int sseg = tid & 3;

  f32x4 acc[4][4] = {};

  for (int k0 = 0; k0 < 1024; k0 += 32) {
    #pragma unroll
    for (int half = 0; half < 2; ++half) {
      int r = r0a + half*64;
      *(uint4*)(&Ahs[r*40 + sseg*8]) = *(const uint4*)(Ah + (size_t)(bm + r)*1024 + k0 + sseg*8);
      *(uint4*)(&Als[r*40 + sseg*8]) = *(const uint4*)(Al + (size_t)(bm + r)*1024 + k0 + sseg*8);
      *(uint4*)(&Bhs[r*40 + sseg*8]) = *(const uint4*)(Bh + (size_t)(bn + r)*1024 + k0 + sseg*8);
      *(uint4*)(&Bls[r*40 + sseg*8]) = *(const uint4*)(Bl + (size_t)(bn + r)*1024 + k0 + sseg*8);
    }
    __syncthreads();
    bf16x8 afh[4], afl[4], bfh[4], bfl[4];
    #pragma unroll
    for (int i = 0; i < 4; ++i) {
      afh[i] = *(const bf16x8*)(&Ahs[(wm + i*16 + fml)*40 + q*8]);
      afl[i] = *(const bf16x8*)(&Als[(wm + i*16 + fml)*40 + q*8]);
    }
    #pragma unroll
    for (int j = 0; j < 4; ++j) {
      bfh[j] = *(const bf16x8*)(&Bhs[(wn + j*16 + fml)*40 + q*8]);
      bfl[j] = *(const bf16x8*)(&Bls[(wn + j*16 + fml)*40 + q*8]);
    }
    #pragma unroll
    for (int i = 0; i < 4; ++i)
      #pragma unroll
      for (int j = 0; j < 4; ++j) {
        acc[i][j] = __builtin_amdgcn_mfma_f32_16x16x32_bf16(afl[i], bfh[j], acc[i][j], 0, 0, 0);
        acc[i][j] = __builtin_amdgcn_mfma_f32_16x16x32_bf16(afh[i], bfl[j], acc[i][j], 0, 0, 0);
        acc[i][j] = __builtin_amdgcn_mfma_f32_16x16x32_bf16(afh[i], bfh[j], acc[i][j], 0, 0, 0);
      }
    __syncthreads();
  }
  #pragma unroll
  for (int i = 0; i < 4; ++i) {
    #pragma unroll
    for (int j = 0; j < 4; ++j) {
      int col = bn + wn + j*16 + fml;
      float bv = bias[col];
      #pragma unroll
      for (int r = 0; r < 4; ++r) {
        int row = bm + wm + i*16 + q*4 + r;
        C[(size_t)row*D_ + col] = gains[row]*acc[i][j][r] + bv;
      }
    }
  }
}

// ---------------------------------------------------------------- GIF scan, f32 fast path (enc + dec)
__global__ __launch_bounds__(256) void k_gif_warm32(const float* __restrict__ buf,
    float* __restrict__ vinit, int Wd, int CS, int Stot)
{
  int c = blockIdx.x*256 + threadIdx.x;
  int channels = gridDim.x*256;
  int chunk = blockIdx.y;
  int b = c / Wd, h = c - b*Wd;
  int s_emit = chunk*CS;
  int s0 = s_emit - HALO; if (s0 < 0) s0 = 0;
  const float* p = buf + (size_t)b*Stot*Wd + h;
  float v = 0.f;
  for (int sg = s0; sg < s_emit; sg += 8) {
    float cv[8];
    #pragma unroll
    for (int i = 0; i < 8; ++i) cv[i] = p[(size_t)(sg+i)*Wd];
    #pragma unroll
    for (int i = 0; i < 8; ++i) {
      v = 0.9f*v + cv[i];
      float s = 1.0f/(1.0f + __expf(-4.0f*(v - 1.0f)));
      v -= s;
    }
  }
  vinit[(size_t)chunk*channels + c] = v;
}

__global__ __launch_bounds__(256) void k_gif_emit32(float* __restrict__ buf,
    const float* __restrict__ vinit, int Wd, int CS, int Stot)
{
  int c = blockIdx.x*256 + threadIdx.x;
  int channels = gridDim.x*256;
  int chunk = blockIdx.y;
  int b = c / Wd, h = c - b*Wd;
  float* p = buf + (size_t)b*Stot*Wd + h + (size_t)chunk*CS*Wd;
  float v = vinit[(size_t)chunk*channels + c];
  float cv[8], nv[8] = {0,0,0,0,0,0,0,0};
  #pragma unroll
  for (int i = 0; i < 8; ++i) cv[i] = p[(size_t)i*Wd];
  for (int sg = 0; sg < CS; sg += 8) {
    float sp[8];
    #pragma unroll
    for (int i = 0; i < 8; ++i) {
      v = 0.9f*v + cv[i];
      float s = 1.0f/(1.0f + __expf(-4.0f*(v - 1.0f)));
      v -= s; sp[i] = s;
    }
    if (sg + 8 < CS) {
      #pragma unroll
      for (int i = 0; i < 8; ++i) nv[i] = p[(size_t)(sg+8+i)*Wd];
    }
    #pragma unroll
    for (int i = 0; i < 8; ++i) p[(size_t)(sg+i)*Wd] = sp[i];
    #pragma unroll
    for (int i = 0; i < 8; ++i) cv[i] = nv[i];
  }
}

// ---------------------------------------------------------------- s2c partial, f32 FMA — 16 tokens/block (512 blocks)
__global__ __launch_bounds__(256) void k_s2c(const float* __restrict__ Sp, int ldS, int KH,
    const float* __restrict__ W, size_t woff, float* __restrict__ out, int accum,
    const float* __restrict__ bias2) {
  __shared__ float As_[16][17];
  __shared__ float Ws_[16][68];
  const int bm = blockIdx.x * 16;
  const int tid = threadIdx.x;
  const int rt = tid >> 4;   // row 0..15
  const int ct = tid & 15;   // col group 0..15
  float acc[4] = {};
  for (int k0 = 0; k0 < KH; k0 += 16) {
    As_[tid >> 4][tid & 15] = Sp[(size_t)(bm + (tid >> 4))*ldS + k0 + (tid & 15)];
    #pragma unroll
    for (int i = 0; i < 4; ++i) {
      int e = tid + i*256;
      Ws_[e >> 6][e & 63] = W[woff + (size_t)(k0 + (e >> 6))*64 + (e & 63)];
    }
    __syncthreads();
    #pragma unroll
    for (int kk = 0; kk < 16; ++kk) {
      float a = As_[rt][kk];
      #pragma unroll
      for (int j = 0; j < 4; ++j) acc[j] += a * Ws_[kk][ct*4+j];
    }
    __syncthreads();
  }
  #pragma unroll
  for (int j = 0; j < 4; ++j) {
    size_t idx = ((size_t)bm + rt)*64 + ct*4 + j;
    float a = acc[j];
    if (accum) {
      float v = out[idx] + a;
      if (bias2) v = v + bias2[ct*4+j]; // bias fold on final pass
      out[idx] = v;
    } else out[idx] = a;
  }
}

// ---------------------------------------------------------------- zero expert counters
__global__ void k_zero(int* p) { if (threadIdx.x < 8) p[threadIdx.x] = 0; }

// ---------------------------------------------------------------- fused router (f32): hidden in LDS, logits, top-2, block-agg append
// Same f32 ops in same order as R9's k_rhid+k_rtop -> identical routing.
__global__ __launch_bounds__(256) void k_router2(const float* __restrict__ cont,
    const float* __restrict__ rW1, const float* __restrict__ rb1,
    const float* __restrict__ rW2, const float* __restrict__ rb2,
    const float* __restrict__ gains,
    int* __restrict__ cnt, unsigned int* __restrict__ list, float* __restrict__ lw)
{
  __shared__ float W1s[64*64];
  __shared__ float W2s[64*8];
  __shared__ float b2s[8];
  __shared__ float cs[16][64];
  __shared__ float hs[16][65];
  __shared__ int bcnt[8];
  __shared__ int bbase[8];
  const int tid = threadIdx.x;
  const int j  = tid & 63;
  const int tg = tid >> 6;           // 0..3
  const int n0 = blockIdx.x * 16;
  for (int i = tid; i < 64*64; i += 256) W1s[i] = rW1[i];
  for (int i = tid; i < 64*8; i += 256)  W2s[i] = rW2[i];
  if (tid < 8) { b2s[tid] = rb2[tid]; bcnt[tid] = 0; }
  #pragma unroll
  for (int i = 0; i < 4; ++i) {
    int e = tid + i*256;             // 1024 = 16 tokens x 64
    cs[e >> 6][e & 63] = cont[(size_t)(n0 + (e >> 6))*64 + (e & 63)];
  }
  __syncthreads();
  {
    const float b1 = rb1[j];
    float t0 = b1, t1 = b1, t2 = b1, t3 = b1;
    #pragma unroll
    for (int m = 0; m < 64; ++m) {
      const float w = W1s[m*64 + j];
      t0 += cs[tg*4+0][m] * w;
      t1 += cs[tg*4+1][m] * w;
      t2 += cs[tg*4+2][m] * w;
      t3 += cs[tg*4+3][m] * w;
    }
    hs[tg*4+0][j] = tanhf(t0);
    hs[tg*4+1][j] = tanhf(t1);
    hs[tg*4+2][j] = tanhf(t2);
    hs[tg*4+3][j] = tanhf(t3);
  }
  __syncthreads();
  int i1 = 0, i2 = 0, p1l = 0, p2l = 0;
  float w1 = 0.f;
  if (tid < 16) {
    const int n = n0 + tid;
    float lg[8];
    #pragma unroll
    for (int e = 0; e < 8; ++e) lg[e] = b2s[e];
    #pragma unroll 8
    for (int jj = 0; jj < 64; ++jj) {
      float t = hs[tid][jj];
      #pragma unroll
      for (int e = 0; e < 8; ++e) lg[e] += t * W2s[jj*8 + e];
    }
    float g = gains[n];
    #pragma unroll
    for (int e = 0; e < 8; ++e) lg[e] *= g;
    float m1 = lg[0];
    #pragma unroll
    for (int e = 1; e < 8; ++e) if (lg[e] > m1) { m1 = lg[e]; i1 = e; }
    i2 = (i1 == 0) ? 1 : 0; float m2 = lg[i2];
    #pragma unroll
    for (int e = 0; e < 8; ++e) if (e != i1 && lg[e] > m2) { m2 = lg[e]; i2 = e; }
    w1 = 1.0f / (1.0f + __expf(m2 - m1));
    p1l = atomicAdd(&bcnt[i1], 1);
    p2l = atomicAdd(&bcnt[i2], 1);
  }
  __syncthreads();
  if (tid < 8) bbase[tid] = bcnt[tid] ? atomicAdd(&cnt[tid], bcnt[tid]) : 0;
  __syncthreads();
  if (tid < 16) {
    const int n = n0 + tid;
    const int p1 = bbase[i1] + p1l;
    list[i1*8192 + p1] = ((unsigned)n << 1);
    lw[i1*8192 + p1] = w1;
    const int p2 = bbase[i2] + p2l;
    list[i2*8192 + p2] = ((unsigned)n << 1) | 1u;
    lw[i2*8192 + p2] = 1.0f - w1;
  }
}

// ---------------------------------------------------------------- grouped experts — f32 SIMT (fallback tier only)
__global__ __launch_bounds__(256) void k_expgrp(
    const float* __restrict__ cont,
    const unsigned int* __restrict__ list, const float* __restrict__ lw,
    const int* __restrict__ cnt,
    const float* __restrict__ eW1, const float* __restrict__ eb1,
    const float* __restrict__ eW2, const float* __restrict__ eb2,
    float* __restrict__ eout)
{
  const int e = blockIdx.y;
  const int t0 = blockIdx.x * 64;
  const int ce = cnt[e];
  if (t0 >= ce) return;
  const int nt = (ce - t0 < 64) ? (ce - t0) : 64;
  __shared__ float ct[64][65];
  __shared__ float w1b[64][65];
  __shared__ float hbl[64][65];
  __shared__ float w2b[64][65];
  __shared__ unsigned int sl[64];
  __shared__ float swt[64];
  const int tid = threadIdx.x;
  if (tid < 64) {
    if (tid < nt) {
      sl[tid]  = list[e*8192 + t0 + tid];
      swt[tid] = lw[e*8192 + t0 + tid];
    } else { sl[tid] = 0; swt[tid] = 0.f; }
  }
  __syncthreads();
  for (int f = tid; f < 64*64; f += 256) {
    int r = f >> 6, m = f & 63;
    ct[r][m] = (r < nt) ? cont[(size_t)(sl[r] >> 1)*64 + m] : 0.f;
  }
  const float* W1 = eW1 + (size_t)e*64*1024;
  const float* W2 = eW2 + (size_t)e*1024*64;
  const float* B1 = eb1 + (size_t)e*1024;
  const int rt = tid >> 4, c16 = tid & 15;
  float outa[4][4] = {};
  for (int hc = 0; hc < 1024; hc += 64) {
    __syncthreads();
    for (int f = tid; f < 64*64; f += 256) {
      int m = f >> 6, j = f & 63;
      w1b[m][j] = W1[(size_t)m*1024 + hc + j];
      w2b[m][j] = W2[(size_t)(hc + m)*64 + j];
    }
    __syncthreads();
    float h4[4][4];
    #pragma unroll
    for (int i = 0; i < 4; ++i) {
      #pragma unroll
      for (int j = 0; j < 4; ++j) h4[i][j] = B1[hc + c16*4 + j];
    }
    #pragma unroll 16
    for (int m = 0; m < 64; ++m) {
      float a4[4], b4[4];
      #pragma unroll
      for (int i = 0; i < 4; ++i) a4[i] = ct[rt*4+i][m];
      #pragma unroll
      for (int j = 0; j < 4; ++j) b4[j] = w1b[m][c16*4+j];
      #pragma unroll
      for (int i = 0; i < 4; ++i)
        #pragma unroll
        for (int j = 0; j < 4; ++j) h4[i][j] += a4[i]*b4[j];
    }
    #pragma unroll
    for (int i = 0; i < 4; ++i)
      #pragma unroll
      for (int j = 0; j < 4; ++j)
        hbl[rt*4+i][c16*4+j] = fmaxf(h4[i][j], 0.f);
    __syncthreads();
    #pragma unroll 16
    for (int j = 0; j < 64; ++j) {
      float a4[4], b4[4];
      #pragma unroll
      for (int i = 0; i < 4; ++i) a4[i] = hbl[rt*4+i][j];
      #pragma unroll
      for (int nn = 0; nn < 4; ++nn) b4[nn] = w2b[j][c16*4+nn];
      #pragma unroll
      for (int i = 0; i < 4; ++i)
        #pragma unroll
        for (int nn = 0; nn < 4; ++nn) outa[i][nn] += a4[i]*b4[nn];
    }
  }
  #pragma unroll
  for (int i = 0; i < 4; ++i) {
    int r = rt*4 + i;
    if (r < nt) {
      float w = swt[r];
      #pragma unroll
      for (int nn = 0; nn < 4; ++nn) {
        int col = c16*4 + nn;
        eout[(size_t)sl[r]*64 + col] = w * (outa[i][nn] + eb2[(size_t)e*64 + col]);
      }
    }
  }
}

// ---------------------------------------------------------------- grouped experts — split-bf16 MFMA; expert = blockIdx.x (XCD pinning)
__global__ __launch_bounds__(256) void k_expmfma(
    const float* __restrict__ cont,
    const unsigned int* __restrict__ list, const float* __restrict__ lw,
    const int* __restrict__ cnt,
    const unsigned short* __restrict__ w1h, const unsigned short* __restrict__ w1l, // [E][1024][64]
    const float* __restrict__ eb1,                                                  // [E][1024]
    const unsigned short* __restrict__ w2h, const unsigned short* __restrict__ w2l, // [E][64][1024]
    const float* __restrict__ eb2,                                                  // [E][64]
    float* __restrict__ eout)
{
  const int e  = blockIdx.x;            // 8 experts -> flat%8==e -> one XCD per expert
  const int t0 = blockIdx.y * 64;
  const int ce = cnt[e];
  if (t0 >= ce) return;
  const int nt = (ce - t0 < 64) ? (ce - t0) : 64;

  // stride 72 shorts = 144 B = 36 words (36 % 32 = 4): 16-row frag reads are <=2-way.
  __shared__ __align__(16) unsigned short cth[64*72],  ctl[64*72];
  __shared__ __align__(16) unsigned short w1sh[64*72], w1sl[64*72];
  __shared__ __align__(16) unsigned short w2sh[64*72], w2sl[64*72];
  __shared__ __align__(16) unsigned short hsh[64*72],  hsl[64*72];
  __shared__ unsigned int sl[64];
  __shared__ float swt[64];

  const int tid  = threadIdx.x;
  const int lane = tid & 63;
  const int wave = tid >> 6;
  const int wm  = (wave >> 1) * 32;   // token offset of this wave
  const int wn  = (wave & 1) * 32;    // col offset of this wave
  const int fml = lane & 15;
  const int q   = lane >> 4;          // 0..3

  if (tid < 64) {
    if (tid < nt) { sl[tid] = list[e*8192 + t0 + tid]; swt[tid] = lw[e*8192 + t0 + tid]; }
    else          { sl[tid] = 0; swt[tid] = 0.f; }
  }
  __syncthreads();

  // gather cont rows + split to hi/lo bf16 (row = token, 16 f32 per thread)
  {
    const int row = tid >> 2;
    const int m0  = (tid & 3) * 16;
    float x[16] = {0.f,0.f,0.f,0.f,0.f,0.f,0.f,0.f,0.f,0.f,0.f,0.f,0.f,0.f,0.f,0.f};
    if (row < nt) {
      const float* p = cont + (size_t)(sl[row] >> 1)*64 + m0;
      *(float4*)&x[0]  = *(const float4*)(p);
      *(float4*)&x[4]  = *(const float4*)(p + 4);
      *(float4*)&x[8]  = *(const float4*)(p + 8);
      *(float4*)&x[12] = *(const float4*)(p + 12);
    }
    unsigned int hp[8], lp[8];
    #pragma unroll
    for (int t = 0; t < 8; ++t) {
      unsigned short h0 = f2bf(x[2*t]);
      unsigned short h1 = f2bf(x[2*t+1]);
      unsigned short l0 = f2bf(x[2*t]   - bf2f(h0));
      unsigned short l1 = f2bf(x[2*t+1] - bf2f(h1));
      hp[t] = (unsigned)h0 | ((unsigned)h1 << 16);
      lp[t] = (unsigned)l0 | ((unsigned)l1 << 16);
    }
    *(uint4*)&cth[row*72 + m0]     = make_uint4(hp[0], hp[1], hp[2], hp[3]);
    *(uint4*)&cth[row*72 + m0 + 8] = make_uint4(hp[4], hp[5], hp[6], hp[7]);
    *(uint4*)&ctl[row*72 + m0]     = make_uint4(lp[0], lp[1], lp[2], lp[3]);
    *(uint4*)&ctl[row*72 + m0 + 8] = make_uint4(lp[4], lp[5], lp[6], lp[7]);
  }

  f32x4 acc2[2][2] = {};

  for (int hc = 0; hc < 1024; hc += 64) {
    // stage this chunk's weights: w1 rows = h-cols (K=m), w2 rows = out-cols (K=h)
    {
      const int row = tid >> 2;
      const int seg = (tid & 3) * 16;
      const size_t o1 = ((size_t)(e*1024 + hc + row))*64 + seg;
      *(uint4*)&w1sh[row*72 + seg]     = *(const uint4*)(w1h + o1);
      *(uint4*)&w1sh[row*72 + seg + 8] = *(const uint4*)(w1h + o1 + 8);
      *(uint4*)&w1sl[row*72 + seg]     = *(const uint4*)(w1l + o1);
      *(uint4*)&w1sl[row*72 + seg + 8] = *(const uint4*)(w1l + o1 + 8);
      const size_t o2 = ((size_t)(e*64 + row))*1024 + hc + seg;
      *(uint4*)&w2sh[row*72 + seg]     = *(const uint4*)(w2h + o2);
      *(uint4*)&w2sh[row*72 + seg + 8] = *(const uint4*)(w2h + o2 + 8);
      *(uint4*)&w2sl[row*72 + seg]     = *(const uint4*)(w2l + o2);
      *(uint4*)&w2sl[row*72 + seg + 8] = *(const uint4*)(w2l + o2 + 8);
    }
    __syncthreads();

    // GEMM1: h[t][col] = sum_m ct[t][m] * w1[col][m], K=64
    f32x4 acc1[2][2] = {};
    #pragma unroll
    for (int ks = 0; ks < 2; ++ks) {
      bf16x8 ah[2], al[2], bh[2], bl[2];
      #pragma unroll
      for (int i = 0; i < 2; ++i) {
        ah[i] = *(const bf16x8*)&cth[(wm + i*16 + fml)*72 + ks*32 + q*8];
        al[i] = *(const bf16x8*)&ctl[(wm + i*16 + fml)*72 + ks*32 + q*8];
      }
      #pragma unroll
      for (int j = 0; j < 2; ++j) {
        bh[j] = *(const bf16x8*)&w1sh[(wn + j*16 + fml)*72 + ks*32 + q*8];
        bl[j] = *(const bf16x8*)&w1sl[(wn + j*16 + fml)*72 + ks*32 + q*8];
      }
      #pragma unroll
      for (int i = 0; i < 2; ++i)
        #pragma unroll
        for (int j = 0; j < 2; ++j) {
          acc1[i][j] = __builtin_amdgcn_mfma_f32_16x16x32_bf16(al[i], bh[j], acc1[i][j], 0, 0, 0);
          acc1[i][j] = __builtin_amdgcn_mfma_f32_16x16x32_bf16(ah[i], bl[j], acc1[i][j], 0, 0, 0);
          acc1[i][j] = __builtin_amdgcn_mfma_f32_16x16x32_bf16(ah[i], bh[j], acc1[i][j], 0, 0, 0);
        }
    }

    // bias + relu + split to hi/lo, write h to LDS (C/D: col=lane&15, row=q*4+r)
    #pragma unroll
    for (int j = 0; j < 2; ++j) {
      const int col = wn + j*16 + fml;
      const float b1 = eb1[(size_t)e*1024 + hc + col];
      #pragma unroll
      for (int i = 0; i < 2; ++i) {
        #pragma unroll
        for (int r = 0; r < 4; ++r) {
          const int trow = wm + i*16 + q*4 + r;
          float v = fmaxf(acc1[i][j][r] + b1, 0.f);
          unsigned short hh = f2bf(v);
          hsh[trow*72 + col] = hh;
          hsl[trow*72 + col] = f2bf(v - bf2f(hh));
        }
      }
    }
    __syncthreads();

    // GEMM2: out[t][n] += sum_h hs[t][h] * w2[n][h], K=64
    #pragma unroll
    for (int ks = 0; ks < 2; ++ks) {
      bf16x8 ah[2], al[2], bh[2], bl[2];
      #pragma unroll
      for (int i = 0; i < 2; ++i) {
        ah[i] = *(const bf16x8*)&hsh[(wm + i*16 + fml)*72 + ks*32 + q*8];
        al[i] = *(const bf16x8*)&hsl[(wm + i*16 + fml)*72 + ks*32 + q*8];
      }
      #pragma unroll
      for (int j = 0; j < 2; ++j) {
        bh[j] = *(const bf16x8*)&w2sh[(wn + j*16 + fml)*72 + ks*32 + q*8];
        bl[j] = *(const bf16x8*)&w2sl[(wn + j*16 + fml)*72 + ks*32 + q*8];
      }
      #pragma unroll
      for (int i = 0; i < 2; ++i)
        #pragma unroll
        for (int j = 0; j < 2; ++j) {
          acc2[i][j] = __builtin_amdgcn_mfma_f32_16x16x32_bf16(al[i], bh[j], acc2[i][j], 0, 0, 0);
          acc2[i][j] = __builtin_amdgcn_mfma_f32_16x16x32_bf16(ah[i], bl[j], acc2[i][j], 0, 0, 0);
          acc2[i][j] = __builtin_amdgcn_mfma_f32_16x16x32_bf16(ah[i], bh[j], acc2[i][j], 0, 0, 0);
        }
    }
    __syncthreads();   // before next chunk overwrites w1s/w2s/hs
  }

  // epilogue: eout[slot][n] = w * (acc + b2)
  #pragma unroll
  for (int j = 0; j < 2; ++j) {
    const int col = wn + j*16 + fml;
    const float b2 = eb2[(size_t)e*64 + col];
    #pragma unroll
    for (int i = 0; i < 2; ++i) {
      #pragma unroll
      for (int r = 0; r < 4; ++r) {
        const int trow = wm + i*16 + q*4 + r;
        if (trow < nt)
          eout[(size_t)sl[trow]*64 + col] = swt[trow]*(acc2[i][j][r] + b2);
      }
    }
  }
}

// ---------------------------------------------------------------- c2s MFMA GEMM, split-bf16 (3 products)
__global__ __launch_bounds__(256) void k_c2sM(
    const float* __restrict__ eoutTok,        // [T][128]
    const unsigned short* __restrict__ WTh,   // [2048][64] bf16 hi
    const unsigned short* __restrict__ WTl,   // [2048][64] bf16 lo
    const float* __restrict__ bias,           // [2048]
    unsigned short* __restrict__ rates)       // [T][2048]
{
  __shared__ __align__(16) unsigned short Ahs[128*72], Als[128*72];
  __shared__ __align__(16) unsigned short Bhs[128*72], Bls[128*72];
  const int tid  = threadIdx.x;
  const int lane = tid & 63;
  const int wave = tid >> 6;
  const int wm = (wave >> 1) * 64;
  const int wn = (wave & 1) * 64;
  const int bm = blockIdx.y * 128;
  const int bn = blockIdx.x * 128;
  const int fml = lane & 15;
  const int q  = lane >> 4;

  {
    const int row = tid >> 1;          // 0..127
    const int m0  = (tid & 1) * 32;    // 0 or 32
    const float* p = eoutTok + (size_t)(bm + row)*128 + m0;
    float x[32];
    #pragma unroll
    for (int i = 0; i < 8; ++i) {
      float4 a = *(const float4*)(p + i*4);
      float4 b = *(const float4*)(p + 64 + i*4);
      x[i*4+0] = a.x + b.x; x[i*4+1] = a.y + b.y;
      x[i*4+2] = a.z + b.z; x[i*4+3] = a.w + b.w;
    }
    unsigned int hp[16], lp[16];
    #pragma unroll
    for (int t = 0; t < 16; ++t) {
      unsigned short h0 = f2bf(x[2*t]);
      unsigned short h1 = f2bf(x[2*t+1]);
      unsigned short l0 = f2bf(x[2*t]   - bf2f(h0));
      unsigned short l1 = f2bf(x[2*t+1] - bf2f(h1));
      hp[t] = (unsigned)h0 | ((unsigned)h1 << 16);
      lp[t] = (unsigned)l0 | ((unsigned)l1 << 16);
    }
    #pragma unroll
    for (int t = 0; t < 4; ++t) {
      *(uint4*)&Ahs[row*72 + m0 + t*8] = make_uint4(hp[t*4+0],hp[t*4+1],hp[t*4+2],hp[t*4+3]);
      *(uint4*)&Als[row*72 + m0 + t*8] = make_uint4(lp[t*4+0],lp[t*4+1],lp[t*4+2],lp[t*4+3]);
    }
    const unsigned short* ph = WTh + (size_t)(bn + row)*64 + m0;
    const unsigned short* pl = WTl + (size_t)(bn + row)*64 + m0;
    #pragma unroll
    for (int t = 0; t < 4; ++t) {
      *(uint4*)&Bhs[row*72 + m0 + t*8] = *(const uint4*)(ph + t*8);
      *(uint4*)&Bls[row*72 + m0 + t*8] = *(const uint4*)(pl + t*8);
    }
  }
  __syncthreads();

  f32x4 acc[4][4] = {};
  #pragma unroll
  for (int ks = 0; ks < 2; ++ks) {
    bf16x8 ah[4], al[4], bh[4], bl[4];
    #pragma unroll
    for (int i = 0; i < 4; ++i) {
      ah[i] = *(const bf16x8*)&Ahs[(wm + i*16 + fml)*72 + ks*32 + q*8];
      al[i] = *(const bf16x8*)&Als[(wm + i*16 + fml)*72 + ks*32 + q*8];
    }
    #pragma unroll
    for (int j = 0; j < 4; ++j) {
      bh[j] = *(const bf16x8*)&Bhs[(wn + j*16 + fml)*72 + ks*32 + q*8];
      bl[j] = *(const bf16x8*)&Bls[(wn + j*16 + fml)*72 + ks*32 + q*8];
    }
    #pragma unroll
    for (int i = 0; i < 4; ++i)
      #pragma unroll
      for (int j = 0; j < 4; ++j) {
        acc[i][j] = __builtin_amdgcn_mfma_f32_16x16x32_bf16(al[i], bh[j], acc[i][j], 0, 0, 0);
        acc[i][j] = __builtin_amdgcn_mfma_f32_16x16x32_bf16(ah[i], bl[j], acc[i][j], 0, 0, 0);
        acc[i][j] = __builtin_amdgcn_mfma_f32_16x16x32_bf16(ah[i], bh[j], acc[i][j], 0, 0, 0);
      }
  }

  #pragma unroll
  for (int j = 0; j < 4; ++j) {
    const int col = bn + wn + j*16 + fml;
    const float bv = bias[col];
    #pragma unroll
    for (int i = 0; i < 4; ++i) {
      #pragma unroll
      for (int r = 0; r < 4; ++r) {
        const int row = bm + wm + i*16 + q*4 + r;
        rates[(size_t)row*H_ + col] = f2bf(sigf(acc[i][j][r] + bv));
      }
    }
  }
}

// ---------------------------------------------------------------- c2s 256-col slice -> f32 (fallback path)
__global__ __launch_bounds__(256) void k_c2sS(const float* __restrict__ eoutTok,
    const float* __restrict__ W, int coff,
    const float* __restrict__ bias, float* __restrict__ rat)
{
  __shared__ float ml[8][64];
  const int tid = threadIdx.x;
  const int n0 = blockIdx.x * 8;
  for (int i = tid; i < 512; i += 256) {
    int t = i >> 6, m = i & 63;
    ml[t][m] = eoutTok[(size_t)(n0+t)*128 + m] + eoutTok[(size_t)(n0+t)*128 + 64 + m];
  }
  __syncthreads();
  float acc[8] = {};
  for (int m = 0; m < 64; ++m) {
    float wv = W[(size_t)m*H_ + coff + tid];
    #pragma unroll
    for (int t = 0; t < 8; ++t) acc[t] += ml[t][m] * wv;
  }
  float bv = bias[coff + tid];
  #pragma unroll
  for (int t = 0; t < 8; ++t)
    rat[(size_t)(n0+t)*256 + tid] = sigf(acc[t] + bv);
}

// ---------------------------------------------------------------- f32 -> bf16 transpose (dec_W [R][C] -> out [C][R])
__global__ __launch_bounds__(256) void k_transb(const float* __restrict__ in,
    unsigned short* __restrict__ out, int R, int C) {
  __shared__ unsigned short t[32][33];
  int c0 = blockIdx.x*32, r0 = blockIdx.y*32;
  int tx = threadIdx.x & 31, ty = threadIdx.x >> 5;
  #pragma unroll
  for (int i = 0; i < 32; i += 8)
    t[ty+i][tx] = f2bf(in[(size_t)(r0+ty+i)*C + (c0+tx)]);
  __syncthreads();
  #pragma unroll
  for (int i = 0; i < 32; i += 8)
    out[(size_t)(c0+ty+i)*R + (r0+tx)] = t[tx][ty+i];
}

// ---------------------------------------------------------------- dec MFMA GEMM + XCD bijective swizzle
__global__ __launch_bounds__(256) void k_dgemm(
    const unsigned short* __restrict__ A,
    const unsigned short* __restrict__ BT,
    const float* __restrict__ bias,
    const float* __restrict__ gains,
    float* __restrict__ C)
{
  __shared__ __align__(16) unsigned short As[128*40];
  __shared__ __align__(16) unsigned short Bs[128*40];
  const int tid  = threadIdx.x;
  const int lane = tid & 63;
  const int wave = tid >> 6;
  const int wm = (wave >> 1) * 64;
  const int wn = (wave & 1) * 64;
  // XCD-aware bijective swizzle: nwg = 8*gy (%8==0); same pattern as k_egemm3
  const int gy   = gridDim.y;
  const int flat = blockIdx.y * 8 + blockIdx.x;
  const int swz  = (flat & 7) * gy + (flat >> 3);
  const int bn = (swz & 7) * 128;
  const int bm = (swz >> 3) * 128;
  const int fml = lane & 15;
  const int q  = lane >> 4;
  const int r0a  = tid >> 2;
  const int sseg = tid & 3;

  f32x4 acc[4][4] = {};

  for (int k0 = 0; k0 < H_; k0 += 32) {
    #pragma unroll
    for (int half = 0; half < 2; ++half) {
      int r = r0a + half*64;
      *(uint4*)(&As[r*40 + sseg*8]) = *(const uint4*)(A + (size_t)(bm + r)*H_ + k0 + sseg*8);
      *(uint4*)(&Bs[r*40 + sseg*8]) = *(const uint4*)(BT + (size_t)(bn + r)*H_ + k0 + sseg*8);
    }
    __syncthreads();
    bf16x8 af[4], bfr[4];
    #pragma unroll
    for (int i = 0; i < 4; ++i)
      af[i] = *(const bf16x8*)(&As[(wm + i*16 + fml)*40 + q*8]);
    #pragma unroll
    for (int j = 0; j < 4; ++j)
      bfr[j] = *(const bf16x8*)(&Bs[(wn + j*16 + fml)*40 + q*8]);
    #pragma unroll
    for (int i = 0; i < 4; ++i)
      #pragma unroll
      for (int j = 0; j < 4; ++j)
        acc[i][j] = __builtin_amdgcn_mfma_f32_16x16x32_bf16(af[i], bfr[j], acc[i][j], 0, 0, 0);
    __syncthreads();
  }
  #pragma unroll
  for (int i = 0; i < 4; ++i) {
    #pragma unroll
    for (int j = 0; j < 4; ++j) {
      int col = bn + wn + j*16 + fml;
      float bv = bias[col];
      #pragma unroll
      for (int r = 0; r < 4; ++r) {
        int row = bm + wm + i*16 + q*4 + r;
        C[(size_t)row*D_ + col] = gains[row]*acc[i][j][r] + bv;
      }
    }
  }
}

// ---------------------------------------------------------------- layernorm D=1024 in-place
__global__ __launch_bounds__(256) void k_ln(float* __restrict__ X,
    const float* __restrict__ g, const float* __restrict__ b)
{
  const int n = blockIdx.x, tid = threadIdx.x;
  float4* row = (float4*)(X + (size_t)n*D_);
  const float4 xv = row[tid];
  float xa[4] = {xv.x, xv.y, xv.z, xv.w};
  float s = xa[0]+xa[1]+xa[2]+xa[3];
  float ss = xa[0]*xa[0]+xa[1]*xa[1]+xa[2]*xa[2]+xa[3]*xa[3];
  #pragma unroll
  for (int off = 32; off >= 1; off >>= 1) {
    s  += __shfl_down(s, off);
    ss += __shfl_down(ss, off);
  }
  __shared__ float rs[4], rss[4];
  const int lane = tid & 63, wv = tid >> 6;
  if (lane == 0) { rs[wv] = s; rss[wv] = ss; }
  __syncthreads();
  float S0 = rs[0]+rs[1]+rs[2]+rs[3];
  float SS = rss[0]+rss[1]+rss[2]+rss[3];
  float mu = S0 * (1.f/(float)D_);
  float var = SS * (1.f/(float)D_) - mu*mu;
  float inv = rsqrtf(var + 1e-5f);
  int idx = tid*4;
  float4 o;
  o.x = (xa[0]-mu)*inv*g[idx+0] + b[idx+0];
  o.y = (xa[1]-mu)*inv*g[idx+1] + b[idx+1];
  o.z = (xa[2]-mu)*inv*g[idx+2] + b[idx+2];
  o.w = (xa[3]-mu)*inv*g[idx+3] + b[idx+3];
  row[tid] = o;
}

// ----------------------------------------------------------------
// ws layout:
//   [0x000000,0x200000) cont f32[8192][64]
//   [0x200000,0x300000) c2s_WT hi/lo bf16 [2048][64] (path A only)
//   [0x400000,0x800000) eout f32[16384][64]
//   0x800000 gains | 0x808000 cnt | 0x809000 list | 0x849000 lw
//   [0x890000,0x8D0000) vinitF float[16*4096] (enc GIF CS=128 + dec GIF)
//   0x900000 (4 MiB): WhT (enc) -> expert weights w1th/w1tl/w2th/w2tl -> decWT (dec)
//   0xD00000 (4 MiB): WlT (enc)  -> rates (dec path A, T*4 KiB from 0xD00000)
//   [0x1100000,0x3100000) encAh/encAl bf16 [8192][1024] each (enc pre-split, needs ws>=50 MiB)
// Enc scratch cur f32[8192][1024] = 32 MiB per H-chunk lives in d_out.
extern "C" void kernel_launch(void* const* d_in, const int* in_sizes, int n_in,
                              void* d_out, int out_size, void* d_ws, size_t ws_size,
                              hipStream_t stream) {
  (void)in_sizes; (void)n_in; (void)out_size;
  const float* embeds = (const float*)d_in[0];
  const int*   ids    = (const int*)d_in[1];
  const float* pros   = (const float*)d_in[2];
  const float* enc_W  = (const float*)d_in[3];
  const float* enc_b  = (const float*)d_in[4];
  const float* s2c_W  = (const float*)d_in[5];
  const float* s2c_b  = (const float*)d_in[6];
  const float* r_W1   = (const float*)d_in[7];
  const float* r_b1   = (const float*)d_in[8];
  const float* r_W2   = (const float*)d_in[9];
  const float* r_b2   = (const float*)d_in[10];
  const float* e_W1   = (const float*)d_in[11];
  const float* e_b1   = (const float*)d_in[12];
  const float* e_W2   = (const float*)d_in[13];
  const float* e_b2   = (const float*)d_in[14];
  const float* c2s_W  = (const float*)d_in[15];
  const float* c2s_b  = (const float*)d_in[16];
  const float* dec_W  = (const float*)d_in[17];
  const float* dec_b  = (const float*)d_in[18];
  const float* ln_g   = (const float*)d_in[19];
  const float* ln_b   = (const float*)d_in[20];

  char* ws = (char*)d_ws;
  float*          contp = (float*)ws;
  unsigned short* c2sWTh= (unsigned short*)(ws + (size_t)0x200000); // 256 KiB
  unsigned short* c2sWTl= (unsigned short*)(ws + (size_t)0x280000); // 256 KiB
  float*          eout  = (float*)(ws + (size_t)0x400000);
  float*          gains = (float*)(ws + (size_t)0x800000);
  int*            cnt   = (int*)(ws + (size_t)0x808000);
  unsigned int*   list  = (unsigned int*)(ws + (size_t)0x809000);
  float*          lw    = (float*)(ws + (size_t)0x849000);
  float*          vinitF= (float*)(ws + (size_t)0x890000);          // GIF f32 (256 KiB)
  unsigned short* WhT   = (unsigned short*)(ws + (size_t)0x900000); // -> expert w / decWT
  unsigned short* WlT   = (unsigned short*)(ws + (size_t)0xD00000); // -> rates
  unsigned short* encAh = (unsigned short*)(ws + (size_t)0x1100000); // 16 MiB (enc only)
  unsigned short* encAl = (unsigned short*)(ws + (size_t)0x2100000); // 16 MiB (enc only)
  unsigned short* decWT = WhT;
  unsigned short* rates = WlT;
  float*          ratSf = (float*)ws;              // fallback overlay of cont
  float*          cur   = (float*)d_out;           // enc scratch [8192][1024]

  // expert split-bf16 weights live in the WhT window between enc GEMM and k_transb
  unsigned short* w1th = WhT;                         // [8][1024][64] 1 MiB
  unsigned short* w1tl = w1th + (size_t)8*1024*64;    // 1 MiB
  unsigned short* w2th = w1tl + (size_t)8*1024*64;    // [8][64][1024] 1 MiB
  unsigned short* w2tl = w2th + (size_t)8*1024*64;    // 1 MiB (ends at 0xD00000)

  const int encM  = (ws_size >= (size_t)18*1024*1024) ? 1 : 0;
  const int encPA = (encM && ws_size >= (size_t)50*1024*1024) ? 1 : 0;
  const int T = (ws_size >= (size_t)46*1024*1024) ? 8192
              : (ws_size >= (size_t)30*1024*1024) ? 4096 : 0;

  k_gains<<<N_TOK/256, 256, 0, stream>>>(ids, pros, gains);
  k_zero<<<1, 64, 0, stream>>>(cnt);

  // ---- encoder: 2 H-chunks of 1024; GIF f32 at CS=128; fused s2c (KH=1024) ----
  if (encM) {
    k_splitT<<<dim3(64, 32), 256, 0, stream>>>(enc_W, WhT, WlT);
    if (encPA)
      k_asplit<<<4096, 256, 0, stream>>>(embeds, encAh, encAl);
    for (int c = 0; c < 2; ++c) {
      if (encPA) {
        k_egemm3<<<dim3(8, 64), 256, 0, stream>>>(
            encAh, encAl, WhT + (size_t)c*1024*1024, WlT + (size_t)c*1024*1024,
            enc_b + c*1024, gains, cur);
      } else {
        k_egemm<<<dim3(8, 64), 256, 0, stream>>>(
            embeds, WhT + (size_t)c*1024*1024, WlT + (size_t)c*1024*1024,
            enc_b + c*1024, gains, cur);
      }
      k_gif_warm32<<<dim3(16, 16), 256, 0, stream>>>(cur, vinitF, 1024, 128, S_);
      k_gif_emit32<<<dim3(16, 16), 256, 0, stream>>>(cur, vinitF, 1024, 128, S_);
      k_s2c<<<N_TOK/16, 256, 0, stream>>>(cur, 1024, 1024,
          s2c_W, (size_t)c*1024*64, contp, (c > 0),
          (c == 1) ? s2c_b : (const float*)nullptr);
    }
    // enc done reading WhT/WlT -> build expert split-bf16 weights in that window
    k_tsplit<<<dim3(32, 2, 8), 256, 0, stream>>>(e_W1, w1th, w1tl, 64, 1024);
    k_tsplit<<<dim3(2, 32, 8), 256, 0, stream>>>(e_W2, w2th, w2tl, 1024, 64);
  } else {
    for (int c = 0; c < 2; ++c) {
      k_genc<<<dim3(8, 64), 256, 0, stream>>>(
          embeds, D_, enc_W, H_, c*1024, enc_b, gains, cur, 1024, D_, 3);
      k_gif_warm32<<<dim3(16, 16), 256, 0, stream>>>(cur, vinitF, 1024, 128, S_);
      k_gif_emit32<<<dim3(16, 16), 256, 0, stream>>>(cur, vinitF, 1024, 128, S_);
      k_s2c<<<N_TOK/16, 256, 0, stream>>>(cur, 1024, 1024,
          s2c_W, (size_t)c*1024*64, contp, (c > 0),
          (c == 1) ? s2c_b : (const float*)nullptr);
    }
  }

  // ---- router: fused hidden + top-2 (f32, bit-identical routing vs split version) ----
  k_router2<<<N_TOK/16, 256, 0, stream>>>(contp, r_W1, r_b1, r_W2, r_b2,
                                          gains, cnt, list, lw);

  if (encM) {
    k_expmfma<<<dim3(8, 128), 256, 0, stream>>>(contp, list, lw, cnt,
        w1th, w1tl, e_b1, w2th, w2tl, e_b2, eout);
  } else {
    k_expgrp<<<dim3(128, 8), 256, 0, stream>>>(contp, list, lw, cnt,
        e_W1, e_b1, e_W2, e_b2, eout);
  }

  if (T > 0) {
    // ---- decoder path A: bf16 MFMA; GIF f32 ----
    k_transb<<<dim3(32, 64), 256, 0, stream>>>(dec_W, decWT, H_, D_);
    k_tsplit<<<dim3(64, 2, 1), 256, 0, stream>>>(c2s_W, c2sWTh, c2sWTl, 64, H_);
    for (int tok0 = 0; tok0 < N_TOK; tok0 += T) {
      k_c2sM<<<dim3(H_/128, T/128), 256, 0, stream>>>(eout + (size_t)tok0*128,
          c2sWTh, c2sWTl, c2s_b, rates);
      float* cur2 = (float*)d_out + (size_t)tok0*D_;
      k_dgemm<<<dim3(D_/128, T/128), 256, 0, stream>>>(
          rates, decWT, dec_b, gains + tok0, cur2);
      int channels = (T/2048)*1024;
      k_gif_warm32<<<dim3(channels/256, 8), 256, 0, stream>>>(cur2, vinitF, D_, 256, S_);
      k_gif_emit32<<<dim3(channels/256, 8), 256, 0, stream>>>(cur2, vinitF, D_, 256, S_);
      k_ln<<<T, 256, 0, stream>>>(cur2, ln_g, ln_b);
    }
  } else {
    // ---- decoder fallback: f32 SIMT, 2 halves x 8 K-slices ----
    for (int hb = 0; hb < 2; ++hb) {
      float* cur2 = (float*)d_out + (size_t)hb*4096*D_;
      for (int kh = 0; kh < 8; ++kh) {
        k_c2sS<<<4096/8, 256, 0, stream>>>(eout + (size_t)hb*4096*128,
            c2s_W, kh*256, c2s_b, ratSf);
        int mode = (kh == 0) ? 0 : ((kh < 7) ? 1 : 2);
        k_genc<<<dim3(8, 32), 256, 0, stream>>>(
            ratSf, 256, dec_W + (size_t)kh*256*D_, D_, 0, dec_b,
            gains + hb*4096, cur2, D_, 256, mode);
      }
      k_gif_warm32<<<dim3(8, 8), 256, 0, stream>>>(cur2, vinitF, D_, 256, S_);
      k_gif_emit32<<<dim3(8, 8), 256, 0, stream>>>(cur2, vinitF, D_, 256, S_);
      k_ln<<<4096, 256, 0, stream>>>(cur2, ln_g, ln_b);
    }
  }
}

// Round 12
// 657.925 us; speedup vs baseline: 1.0293x; 1.0293x over previous
//
#include <hip/hip_runtime.h>
#include <math.h>

#define B_ 4
#define S_ 2048
#define D_ 1024
#define H_ 2048
#define N_TOK 8192
#define HALO 256
#define VOCAB_ 32000

typedef short bf16x8 __attribute__((ext_vector_type(8)));
typedef float f32x4 __attribute__((ext_vector_type(4)));

__device__ __forceinline__ float sigf(float x) {
  return 1.0f / (1.0f + __expf(-x));
}
__device__ __forceinline__ float bf2f(unsigned short u) {
  union { unsigned int i; float f; } x; x.i = ((unsigned int)u) << 16; return x.f;
}
__device__ __forceinline__ unsigned short f2bf(float f) {
  union { float f; unsigned int i; } x; x.f = f;
  unsigned int r = x.i + 0x7fffu + ((x.i >> 16) & 1u);
  return (unsigned short)(r >> 16);
}

// ---------------------------------------------------------------- gains (f32 tanh)
__global__ __launch_bounds__(256) void k_gains(const int* __restrict__ ids,
    const float* __restrict__ table, float* __restrict__ gains) {
  int i = blockIdx.x*256 + threadIdx.x;
  int id = ids[i];
  id = id < 0 ? 0 : (id >= VOCAB_ ? VOCAB_-1 : id);
  gains[i] = 1.0f + tanhf(table[id]);
}

// ---------------------------------------------------------------- f32 SIMT GEMM (fallback enc/dec)
__global__ __launch_bounds__(256) void k_genc(
    const float* __restrict__ A, int lda,
    const float* __restrict__ W, int ldw, int c0,
    const float* __restrict__ bias,
    const float* __restrict__ gains,
    float* __restrict__ C, int ldc,
    int K, int mode)
{
  __shared__ float As2[16][132];
  __shared__ float Bs[16][128];
  const int tid = threadIdx.x;
  const int tx = tid & 15;
  const int ty = tid >> 4;
  const int bm = blockIdx.y * 128;
  const int bn = blockIdx.x * 128;

  double acc[8][8];
  float part[8][8];
  #pragma unroll
  for (int i = 0; i < 8; ++i)
    #pragma unroll
    for (int j = 0; j < 8; ++j) { acc[i][j] = 0.0; part[i][j] = 0.f; }

  const int e = tid * 8;
  const int ar = e >> 4, ak = e & 15;
  const int bk = e >> 7, bc = e & 127;

  for (int k0 = 0; k0 < K; k0 += 16) {
    {
      const float* pa = A + (size_t)(bm + ar)*lda + k0 + ak;
      float4 v0 = *(const float4*)pa;
      float4 v1 = *(const float4*)(pa + 4);
      As2[ak+0][ar] = v0.x; As2[ak+1][ar] = v0.y;
      As2[ak+2][ar] = v0.z; As2[ak+3][ar] = v0.w;
      As2[ak+4][ar] = v1.x; As2[ak+5][ar] = v1.y;
      As2[ak+6][ar] = v1.z; As2[ak+7][ar] = v1.w;
    }
    {
      const float* pw = W + (size_t)(k0 + bk)*ldw + c0 + bn + bc;
      *(float4*)&Bs[bk][bc]   = *(const float4*)pw;
      *(float4*)&Bs[bk][bc+4] = *(const float4*)(pw + 4);
    }
    __syncthreads();
    #pragma unroll
    for (int kk = 0; kk < 16; ++kk) {
      float a8[8], b8[8];
      *(float4*)&a8[0] = *(const float4*)&As2[kk][ty*8];
      *(float4*)&a8[4] = *(const float4*)&As2[kk][ty*8+4];
      *(float4*)&b8[0] = *(const float4*)&Bs[kk][tx*8];
      *(float4*)&b8[4] = *(const float4*)&Bs[kk][tx*8+4];
      #pragma unroll
      for (int i = 0; i < 8; ++i)
        #pragma unroll
        for (int j = 0; j < 8; ++j)
          part[i][j] += a8[i]*b8[j];
    }
    __syncthreads();
    #pragma unroll
    for (int i = 0; i < 8; ++i)
      #pragma unroll
      for (int j = 0; j < 8; ++j) { acc[i][j] += (double)part[i][j]; part[i][j] = 0.f; }
  }

  #pragma unroll
  for (int i = 0; i < 8; ++i) {
    const int row = bm + ty*8 + i;
    const double g = (mode >= 2) ? (double)gains[row] : 0.0;
    #pragma unroll
    for (int j = 0; j < 8; ++j) {
      const int col = bn + tx*8 + j;
      const size_t idx = (size_t)row*ldc + col;
      if (mode == 0)      C[idx] = (float)acc[i][j];
      else if (mode == 1) C[idx] += (float)acc[i][j];
      else if (mode == 2) C[idx] = (float)(g*((double)C[idx] + acc[i][j]) + (double)bias[c0+col]);
      else                C[idx] = (float)(g*acc[i][j] + (double)bias[c0+col]);
    }
  }
}

// ---------------------------------------------------------------- transpose+split enc_W [1024][2048] f32 -> WhT/WlT [2048][1024] bf16
__global__ __launch_bounds__(256) void k_splitT(const float* __restrict__ in,
    unsigned short* __restrict__ outh, unsigned short* __restrict__ outl) {
  __shared__ unsigned short th[32][33];
  __shared__ unsigned short tl[32][33];
  int c0 = blockIdx.x*32, r0 = blockIdx.y*32;
  int tx = threadIdx.x & 31, ty = threadIdx.x >> 5;
  #pragma unroll
  for (int i = 0; i < 32; i += 8) {
    float x = in[(size_t)(r0+ty+i)*H_ + (c0+tx)];
    unsigned short h = f2bf(x);
    th[ty+i][tx] = h;
    tl[ty+i][tx] = f2bf(x - bf2f(h));
  }
  __syncthreads();
  #pragma unroll
  for (int i = 0; i < 32; i += 8) {
    outh[(size_t)(c0+ty+i)*D_ + (r0+tx)] = th[tx][ty+i];
    outl[(size_t)(c0+ty+i)*D_ + (r0+tx)] = tl[tx][ty+i];
  }
}

// ---------------------------------------------------------------- generic batched transpose+split: in [Z][R][C] f32 -> oh/ol [Z][C][R] bf16
__global__ __launch_bounds__(256) void k_tsplit(const float* __restrict__ in,
    unsigned short* __restrict__ oh, unsigned short* __restrict__ ol,
    int R, int C) {
  __shared__ unsigned short th[32][33];
  __shared__ unsigned short tl[32][33];
  const size_t mat = (size_t)R*C;
  in += (size_t)blockIdx.z * mat;
  oh += (size_t)blockIdx.z * mat;
  ol += (size_t)blockIdx.z * mat;
  int c0 = blockIdx.x*32, r0 = blockIdx.y*32;
  int tx = threadIdx.x & 31, ty = threadIdx.x >> 5;
  #pragma unroll
  for (int i = 0; i < 32; i += 8) {
    float x = in[(size_t)(r0+ty+i)*C + (c0+tx)];
    unsigned short h = f2bf(x);
    th[ty+i][tx] = h;
    tl[ty+i][tx] = f2bf(x - bf2f(h));
  }
  __syncthreads();
  #pragma unroll
  for (int i = 0; i < 32; i += 8) {
    oh[(size_t)(c0+ty+i)*R + (r0+tx)] = th[tx][ty+i];
    ol[(size_t)(c0+ty+i)*R + (r0+tx)] = tl[tx][ty+i];
  }
}

// ---------------------------------------------------------------- row-major f32 -> bf16 hi/lo split (no transpose), 8 elems/thread
__global__ __launch_bounds__(256) void k_asplit(const float* __restrict__ in,
    unsigned short* __restrict__ oh, unsigned short* __restrict__ ol) {
  const size_t i = ((size_t)blockIdx.x*256 + threadIdx.x) * 8;
  float4 v0 = *(const float4*)(in + i);
  float4 v1 = *(const float4*)(in + i + 4);
  float xs[8] = {v0.x, v0.y, v0.z, v0.w, v1.x, v1.y, v1.z, v1.w};
  unsigned int hp[4], lp[4];
  #pragma unroll
  for (int t = 0; t < 4; ++t) {
    unsigned short h0 = f2bf(xs[2*t]);
    unsigned short h1 = f2bf(xs[2*t+1]);
    unsigned short l0 = f2bf(xs[2*t]   - bf2f(h0));
    unsigned short l1 = f2bf(xs[2*t+1] - bf2f(h1));
    hp[t] = (unsigned)h0 | ((unsigned)h1 << 16);
    lp[t] = (unsigned)l0 | ((unsigned)l1 << 16);
  }
  *(uint4*)(oh + i) = make_uint4(hp[0], hp[1], hp[2], hp[3]);
  *(uint4*)(ol + i) = make_uint4(lp[0], lp[1], lp[2], lp[3]);
}

// ---------------------------------------------------------------- enc MFMA GEMM (legacy, in-kernel A split) — fallback tier
__global__ __launch_bounds__(256) void k_egemm(
    const float* __restrict__ A,              // embeds f32 [8192][1024]
    const unsigned short* __restrict__ Bh,    // WhT + chunk offset, [1024][1024] bf16
    const unsigned short* __restrict__ Bl,
    const float* __restrict__ bias,           // enc_b + chunk offset
    const float* __restrict__ gains,
    float* __restrict__ C)                    // cur [8192][1024]
{
  __shared__ __align__(16) unsigned short Ahs[128*40];
  __shared__ __align__(16) unsigned short Als[128*40];
  __shared__ __align__(16) unsigned short Bhs[128*40];
  __shared__ __align__(16) unsigned short Bls[128*40];
  const int tid  = threadIdx.x;
  const int lane = tid & 63;
  const int wave = tid >> 6;
  const int wm = (wave >> 1) * 64;
  const int wn = (wave & 1) * 64;
  const int bm = blockIdx.y * 128;
  const int bn = blockIdx.x * 128;
  const int fml = lane & 15;
  const int q  = lane >> 4;
  const int r0a  = tid >> 2;
  const int sseg = tid & 3;

  f32x4 acc[4][4] = {};

  for (int k0 = 0; k0 < 1024; k0 += 32) {
    #pragma unroll
    for (int half = 0; half < 2; ++half) {
      int r = r0a + half*64;
      const float* pa = A + (size_t)(bm + r)*1024 + k0 + sseg*8;
      float4 v0 = *(const float4*)pa;
      float4 v1 = *(const float4*)(pa + 4);
      float xs[8] = {v0.x, v0.y, v0.z, v0.w, v1.x, v1.y, v1.z, v1.w};
      unsigned int hp[4], lp[4];
      #pragma unroll
      for (int t = 0; t < 4; ++t) {
        unsigned short h0 = f2bf(xs[2*t]);
        unsigned short h1 = f2bf(xs[2*t+1]);
        unsigned short l0 = f2bf(xs[2*t]   - bf2f(h0));
        unsigned short l1 = f2bf(xs[2*t+1] - bf2f(h1));
        hp[t] = (unsigned)h0 | ((unsigned)h1 << 16);
        lp[t] = (unsigned)l0 | ((unsigned)l1 << 16);
      }
      *(uint4*)(&Ahs[r*40 + sseg*8]) = make_uint4(hp[0], hp[1], hp[2], hp[3]);
      *(uint4*)(&Als[r*40 + sseg*8]) = make_uint4(lp[0], lp[1], lp[2], lp[3]);
      *(uint4*)(&Bhs[r*40 + sseg*8]) = *(const uint4*)(Bh + (size_t)(bn + r)*1024 + k0 + sseg*8);
      *(uint4*)(&Bls[r*40 + sseg*8]) = *(const uint4*)(Bl + (size_t)(bn + r)*1024 + k0 + sseg*8);
    }
    __syncthreads();
    bf16x8 afh[4], afl[4], bfh[4], bfl[4];
    #pragma unroll
    for (int i = 0; i < 4; ++i) {
      afh[i] = *(const bf16x8*)(&Ahs[(wm + i*16 + fml)*40 + q*8]);
      afl[i] = *(const bf16x8*)(&Als[(wm + i*16 + fml)*40 + q*8]);
    }
    #pragma unroll
    for (int j = 0; j < 4; ++j) {
      bfh[j] = *(const bf16x8*)(&Bhs[(wn + j*16 + fml)*40 + q*8]);
      bfl[j] = *(const bf16x8*)(&Bls[(wn + j*16 + fml)*40 + q*8]);
    }
    #pragma unroll
    for (int i = 0; i < 4; ++i)
      #pragma unroll
      for (int j = 0; j < 4; ++j) {
        acc[i][j] = __builtin_amdgcn_mfma_f32_16x16x32_bf16(afl[i], bfh[j], acc[i][j], 0, 0, 0);
        acc[i][j] = __builtin_amdgcn_mfma_f32_16x16x32_bf16(afh[i], bfl[j], acc[i][j], 0, 0, 0);
        acc[i][j] = __builtin_amdgcn_mfma_f32_16x16x32_bf16(afh[i], bfh[j], acc[i][j], 0, 0, 0);
      }
    __syncthreads();
  }
  #pragma unroll
  for (int i = 0; i < 4; ++i) {
    #pragma unroll
    for (int j = 0; j < 4; ++j) {
      int col = bn + wn + j*16 + fml;
      float bv = bias[col];
      #pragma unroll
      for (int r = 0; r < 4; ++r) {
        int row = bm + wm + i*16 + q*4 + r;   // C/D: col=lane&15, row=quad*4+reg
        C[(size_t)row*D_ + col] = gains[row]*acc[i][j][r] + bv;
      }
    }
  }
}

// ---------------------------------------------------------------- enc MFMA GEMM v3: pre-split A, B chunk [1024][1024], C ld=1024, XCD swizzle
__global__ __launch_bounds__(256) void k_egemm3(
    const unsigned short* __restrict__ Ah, const unsigned short* __restrict__ Al, // [8192][1024]
    const unsigned short* __restrict__ Bh, const unsigned short* __restrict__ Bl, // [1024][1024]
    const float* __restrict__ bias,           // enc_b + chunk offset
    const float* __restrict__ gains,
    float* __restrict__ C)                    // cur [8192][1024]
{
  __shared__ __align__(16) unsigned short Ahs[128*40];
  __shared__ __align__(16) unsigned short Als[128*40];
  __shared__ __align__(16) unsigned short Bhs[128*40];
  __shared__ __align__(16) unsigned short Bls[128*40];
  const int tid  = threadIdx.x;
  const int lane = tid & 63;
  const int wave = tid >> 6;
  const int wm = (wave >> 1) * 64;
  const int wn = (wave & 1) * 64;
  // XCD-aware bijective swizzle: nwg = 8*64 = 512 (%8==0)
  const int flat = blockIdx.y * 8 + blockIdx.x;
  const int swz  = (flat & 7) * 64 + (flat >> 3);
  const int bn = (swz & 7) * 128;
  const int bm = (swz >> 3) * 128;
  const int fml = lane & 15;
  const int q  = lane >> 4;
  const int r0a  = tid >> 2;
  const int sseg = tid & 3;

  f32x4 acc[4][4] = {};

  for (int k0 = 0; k0 < 1024; k0 += 32) {
    #pragma unroll
    for (int half = 0; half < 2; ++half) {
      int r = r0a + half*64;
      *(uint4*)(&Ahs[r*40 + sseg*8]) = *(const uint4*)(Ah + (size_t)(bm + r)*1024 + k0 + sseg*8);
      *(uint4*)(&Als[r*40 + sseg*8]) = *(const uint4*)(Al + (size_t)(bm + r)*1024 + k0 + sseg*8);
      *(uint4*)(&Bhs[r*40 + sseg*8]) = *(const uint4*)(Bh + (size_t)(bn + r)*1024 + k0 + sseg*8);
      *(uint4*)(&Bls[r*40 + sseg*8]) = *(const uint4*)(Bl + (size_t)(bn + r)*1024 + k0 + sseg*8);
    }
    __syncthreads();
    bf16x8 afh[4], afl[4], bfh[4], bfl[4];
    #pragma unroll
    for (int i = 0; i < 4; ++i) {
      afh[i] = *(const bf16x8*)(&Ahs[(wm + i*16 + fml)*40 + q*8]);
      afl[i] = *(const bf16x8*)(&Als[(wm + i*16 + fml)*40 + q*8]);
    }
    #pragma unroll
    for (int j = 0; j < 4; ++j) {
      bfh[j] = *(const bf16x8*)(&Bhs[(wn + j*16 + fml)*40 + q*8]);
      bfl[j] = *(const bf16x8*)(&Bls[(wn + j*16 + fml)*40 + q*8]);
    }
    #pragma unroll
    for (int i = 0; i < 4; ++i)
      #pragma unroll
      for (int j = 0; j < 4; ++j) {
        acc[i][j] = __builtin_amdgcn_mfma_f32_16x16x32_bf16(afl[i], bfh[j], acc[i][j], 0, 0, 0);
        acc[i][j] = __builtin_amdgcn_mfma_f32_16x16x32_bf16(afh[i], bfl[j], acc[i][j], 0, 0, 0);
        acc[i][j] = __builtin_amdgcn_mfma_f32_16x16x32_bf16(afh[i], bfh[j], acc[i][j], 0, 0, 0);
      }
    __syncthreads();
  }
  #pragma unroll
  for (int i = 0; i < 4; ++i) {
    #pragma unroll
    for (int j = 0; j < 4; ++j) {
      int col = bn + wn + j*16 + fml;
      float bv = bias[col];
      #pragma unroll
      for (int r = 0; r < 4; ++r) {
        int row = bm + wm + i*16 + q*4 + r;
        C[(size_t)row*D_ + col] = gains[row]*acc[i][j][r] + bv;
      }
    }
  }
}

// ---------------------------------------------------------------- GIF scan, f32 fast path (enc + dec)
__global__ __launch_bounds__(256) void k_gif_warm32(const float* __restrict__ buf,
    float* __restrict__ vinit, int Wd, int CS, int Stot)
{
  int c = blockIdx.x*256 + threadIdx.x;
  int channels = gridDim.x*256;
  int chunk = blockIdx.y;
  int b = c / Wd, h = c - b*Wd;
  int s_emit = chunk*CS;
  int s0 = s_emit - HALO; if (s0 < 0) s0 = 0;
  const float* p = buf + (size_t)b*Stot*Wd + h;
  float v = 0.f;
  for (int sg = s0; sg < s_emit; sg += 8) {
    float cv[8];
    #pragma unroll
    for (int i = 0; i < 8; ++i) cv[i] = p[(size_t)(sg+i)*Wd];
    #pragma unroll
    for (int i = 0; i < 8; ++i) {
      v = 0.9f*v + cv[i];
      float s = 1.0f/(1.0f + __expf(-4.0f*(v - 1.0f)));
      v -= s;
    }
  }
  vinit[(size_t)chunk*channels + c] = v;
}

__global__ __launch_bounds__(256) void k_gif_emit32(float* __restrict__ buf,
    const float* __restrict__ vinit, int Wd, int CS, int Stot)
{
  int c = blockIdx.x*256 + threadIdx.x;
  int channels = gridDim.x*256;
  int chunk = blockIdx.y;
  int b = c / Wd, h = c - b*Wd;
  float* p = buf + (size_t)b*Stot*Wd + h + (size_t)chunk*CS*Wd;
  float v = vinit[(size_t)chunk*channels + c];
  float cv[8], nv[8] = {0,0,0,0,0,0,0,0};
  #pragma unroll
  for (int i = 0; i < 8; ++i) cv[i] = p[(size_t)i*Wd];
  for (int sg = 0; sg < CS; sg += 8) {
    float sp[8];
    #pragma unroll
    for (int i = 0; i < 8; ++i) {
      v = 0.9f*v + cv[i];
      float s = 1.0f/(1.0f + __expf(-4.0f*(v - 1.0f)));
      v -= s; sp[i] = s;
    }
    if (sg + 8 < CS) {
      #pragma unroll
      for (int i = 0; i < 8; ++i) nv[i] = p[(size_t)(sg+8+i)*Wd];
    }
    #pragma unroll
    for (int i = 0; i < 8; ++i) p[(size_t)(sg+i)*Wd] = sp[i];
    #pragma unroll
    for (int i = 0; i < 8; ++i) cv[i] = nv[i];
  }
}

// ---------------------------------------------------------------- s2c partial, f32 FMA — 16 tokens/block (512 blocks)
__global__ __launch_bounds__(256) void k_s2c(const float* __restrict__ Sp, int ldS, int KH,
    const float* __restrict__ W, size_t woff, float* __restrict__ out, int accum,
    const float* __restrict__ bias2) {
  __shared__ float As_[16][17];
  __shared__ float Ws_[16][68];
  const int bm = blockIdx.x * 16;
  const int tid = threadIdx.x;
  const int rt = tid >> 4;   // row 0..15
  const int ct = tid & 15;   // col group 0..15
  float acc[4] = {};
  for (int k0 = 0; k0 < KH; k0 += 16) {
    As_[tid >> 4][tid & 15] = Sp[(size_t)(bm + (tid >> 4))*ldS + k0 + (tid & 15)];
    #pragma unroll
    for (int i = 0; i < 4; ++i) {
      int e = tid + i*256;
      Ws_[e >> 6][e & 63] = W[woff + (size_t)(k0 + (e >> 6))*64 + (e & 63)];
    }
    __syncthreads();
    #pragma unroll
    for (int kk = 0; kk < 16; ++kk) {
      float a = As_[rt][kk];
      #pragma unroll
      for (int j = 0; j < 4; ++j) acc[j] += a * Ws_[kk][ct*4+j];
    }
    __syncthreads();
  }
  #pragma unroll
  for (int j = 0; j < 4; ++j) {
    size_t idx = ((size_t)bm + rt)*64 + ct*4 + j;
    float a = acc[j];
    if (accum) {
      float v = out[idx] + a;
      if (bias2) v = v + bias2[ct*4+j]; // bias fold on final pass
      out[idx] = v;
    } else out[idx] = a;
  }
}

// ---------------------------------------------------------------- zero expert counters
__global__ void k_zero(int* p) { if (threadIdx.x < 8) p[threadIdx.x] = 0; }

// ---------------------------------------------------------------- fused router (f32): hidden in LDS, logits, top-2, block-agg append
__global__ __launch_bounds__(256) void k_router2(const float* __restrict__ cont,
    const float* __restrict__ rW1, const float* __restrict__ rb1,
    const float* __restrict__ rW2, const float* __restrict__ rb2,
    const float* __restrict__ gains,
    int* __restrict__ cnt, unsigned int* __restrict__ list, float* __restrict__ lw)
{
  __shared__ float W1s[64*64];
  __shared__ float W2s[64*8];
  __shared__ float b2s[8];
  __shared__ float cs[16][64];
  __shared__ float hs[16][65];
  __shared__ int bcnt[8];
  __shared__ int bbase[8];
  const int tid = threadIdx.x;
  const int j  = tid & 63;
  const int tg = tid >> 6;           // 0..3
  const int n0 = blockIdx.x * 16;
  for (int i = tid; i < 64*64; i += 256) W1s[i] = rW1[i];
  for (int i = tid; i < 64*8; i += 256)  W2s[i] = rW2[i];
  if (tid < 8) { b2s[tid] = rb2[tid]; bcnt[tid] = 0; }
  #pragma unroll
  for (int i = 0; i < 4; ++i) {
    int e = tid + i*256;             // 1024 = 16 tokens x 64
    cs[e >> 6][e & 63] = cont[(size_t)(n0 + (e >> 6))*64 + (e & 63)];
  }
  __syncthreads();
  {
    const float b1 = rb1[j];
    float t0 = b1, t1 = b1, t2 = b1, t3 = b1;
    #pragma unroll
    for (int m = 0; m < 64; ++m) {
      const float w = W1s[m*64 + j];
      t0 += cs[tg*4+0][m] * w;
      t1 += cs[tg*4+1][m] * w;
      t2 += cs[tg*4+2][m] * w;
      t3 += cs[tg*4+3][m] * w;
    }
    hs[tg*4+0][j] = tanhf(t0);
    hs[tg*4+1][j] = tanhf(t1);
    hs[tg*4+2][j] = tanhf(t2);
    hs[tg*4+3][j] = tanhf(t3);
  }
  __syncthreads();
  int i1 = 0, i2 = 0, p1l = 0, p2l = 0;
  float w1 = 0.f;
  if (tid < 16) {
    const int n = n0 + tid;
    float lg[8];
    #pragma unroll
    for (int e = 0; e < 8; ++e) lg[e] = b2s[e];
    #pragma unroll 8
    for (int jj = 0; jj < 64; ++jj) {
      float t = hs[tid][jj];
      #pragma unroll
      for (int e = 0; e < 8; ++e) lg[e] += t * W2s[jj*8 + e];
    }
    float g = gains[n];
    #pragma unroll
    for (int e = 0; e < 8; ++e) lg[e] *= g;
    float m1 = lg[0];
    #pragma unroll
    for (int e = 1; e < 8; ++e) if (lg[e] > m1) { m1 = lg[e]; i1 = e; }
    i2 = (i1 == 0) ? 1 : 0; float m2 = lg[i2];
    #pragma unroll
    for (int e = 0; e < 8; ++e) if (e != i1 && lg[e] > m2) { m2 = lg[e]; i2 = e; }
    w1 = 1.0f / (1.0f + __expf(m2 - m1));
    p1l = atomicAdd(&bcnt[i1], 1);
    p2l = atomicAdd(&bcnt[i2], 1);
  }
  __syncthreads();
  if (tid < 8) bbase[tid] = bcnt[tid] ? atomicAdd(&cnt[tid], bcnt[tid]) : 0;
  __syncthreads();
  if (tid < 16) {
    const int n = n0 + tid;
    const int p1 = bbase[i1] + p1l;
    list[i1*8192 + p1] = ((unsigned)n << 1);
    lw[i1*8192 + p1] = w1;
    const int p2 = bbase[i2] + p2l;
    list[i2*8192 + p2] = ((unsigned)n << 1) | 1u;
    lw[i2*8192 + p2] = 1.0f - w1;
  }
}

// ---------------------------------------------------------------- grouped experts — f32 SIMT (fallback tier only)
__global__ __launch_bounds__(256) void k_expgrp(
    const float* __restrict__ cont,
    const unsigned int* __restrict__ list, const float* __restrict__ lw,
    const int* __restrict__ cnt,
    const float* __restrict__ eW1, const float* __restrict__ eb1,
    const float* __restrict__ eW2, const float* __restrict__ eb2,
    float* __restrict__ eout)
{
  const int e = blockIdx.y;
  const int t0 = blockIdx.x * 64;
  const int ce = cnt[e];
  if (t0 >= ce) return;
  const int nt = (ce - t0 < 64) ? (ce - t0) : 64;
  __shared__ float ct[64][65];
  __shared__ float w1b[64][65];
  __shared__ float hbl[64][65];
  __shared__ float w2b[64][65];
  __shared__ unsigned int sl[64];
  __shared__ float swt[64];
  const int tid = threadIdx.x;
  if (tid < 64) {
    if (tid < nt) {
      sl[tid]  = list[e*8192 + t0 + tid];
      swt[tid] = lw[e*8192 + t0 + tid];
    } else { sl[tid] = 0; swt[tid] = 0.f; }
  }
  __syncthreads();
  for (int f = tid; f < 64*64; f += 256) {
    int r = f >> 6, m = f & 63;
    ct[r][m] = (r < nt) ? cont[(size_t)(sl[r] >> 1)*64 + m] : 0.f;
  }
  const float* W1 = eW1 + (size_t)e*64*1024;
  const float* W2 = eW2 + (size_t)e*1024*64;
  const float* B1 = eb1 + (size_t)e*1024;
  const int rt = tid >> 4, c16 = tid & 15;
  float outa[4][4] = {};
  for (int hc = 0; hc < 1024; hc += 64) {
    __syncthreads();
    for (int f = tid; f < 64*64; f += 256) {
      int m = f >> 6, j = f & 63;
      w1b[m][j] = W1[(size_t)m*1024 + hc + j];
      w2b[m][j] = W2[(size_t)(hc + m)*64 + j];
    }
    __syncthreads();
    float h4[4][4];
    #pragma unroll
    for (int i = 0; i < 4; ++i) {
      #pragma unroll
      for (int j = 0; j < 4; ++j) h4[i][j] = B1[hc + c16*4 + j];
    }
    #pragma unroll 16
    for (int m = 0; m < 64; ++m) {
      float a4[4], b4[4];
      #pragma unroll
      for (int i = 0; i < 4; ++i) a4[i] = ct[rt*4+i][m];
      #pragma unroll
      for (int j = 0; j < 4; ++j) b4[j] = w1b[m][c16*4+j];
      #pragma unroll
      for (int i = 0; i < 4; ++i)
        #pragma unroll
        for (int j = 0; j < 4; ++j) h4[i][j] += a4[i]*b4[j];
    }
    #pragma unroll
    for (int i = 0; i < 4; ++i)
      #pragma unroll
      for (int j = 0; j < 4; ++j)
        hbl[rt*4+i][c16*4+j] = fmaxf(h4[i][j], 0.f);
    __syncthreads();
    #pragma unroll 16
    for (int j = 0; j < 64; ++j) {
      float a4[4], b4[4];
      #pragma unroll
      for (int i = 0; i < 4; ++i) a4[i] = hbl[rt*4+i][j];
      #pragma unroll
      for (int nn = 0; nn < 4; ++nn) b4[nn] = w2b[j][c16*4+nn];
      #pragma unroll
      for (int i = 0; i < 4; ++i)
        #pragma unroll
        for (int nn = 0; nn < 4; ++nn) outa[i][nn] += a4[i]*b4[nn];
    }
  }
  #pragma unroll
  for (int i = 0; i < 4; ++i) {
    int r = rt*4 + i;
    if (r < nt) {
      float w = swt[r];
      #pragma unroll
      for (int nn = 0; nn < 4; ++nn) {
        int col = c16*4 + nn;
        eout[(size_t)sl[r]*64 + col] = w * (outa[i][nn] + eb2[(size_t)e*64 + col]);
      }
    }
  }
}

// ---------------------------------------------------------------- grouped experts — split-bf16 MFMA (R9 grid: e=blockIdx.y, spread all CUs)
__global__ __launch_bounds__(256) void k_expmfma(
    const float* __restrict__ cont,
    const unsigned int* __restrict__ list, const float* __restrict__ lw,
    const int* __restrict__ cnt,
    const unsigned short* __restrict__ w1h, const unsigned short* __restrict__ w1l, // [E][1024][64]
    const float* __restrict__ eb1,                                                  // [E][1024]
    const unsigned short* __restrict__ w2h, const unsigned short* __restrict__ w2l, // [E][64][1024]
    const float* __restrict__ eb2,                                                  // [E][64]
    float* __restrict__ eout)
{
  const int e  = blockIdx.y;
  const int t0 = blockIdx.x * 64;
  const int ce = cnt[e];
  if (t0 >= ce) return;
  const int nt = (ce - t0 < 64) ? (ce - t0) : 64;

  // stride 72 shorts = 144 B = 36 words (36 % 32 = 4): 16-row frag reads are <=2-way.
  __shared__ __align__(16) unsigned short cth[64*72],  ctl[64*72];
  __shared__ __align__(16) unsigned short w1sh[64*72], w1sl[64*72];
  __shared__ __align__(16) unsigned short w2sh[64*72], w2sl[64*72];
  __shared__ __align__(16) unsigned short hsh[64*72],  hsl[64*72];
  __shared__ unsigned int sl[64];
  __shared__ float swt[64];

  const int tid  = threadIdx.x;
  const int lane = tid & 63;
  const int wave = tid >> 6;
  const int wm  = (wave >> 1) * 32;   // token offset of this wave
  const int wn  = (wave & 1) * 32;    // col offset of this wave
  const int fml = lane & 15;
  const int q   = lane >> 4;          // 0..3

  if (tid < 64) {
    if (tid < nt) { sl[tid] = list[e*8192 + t0 + tid]; swt[tid] = lw[e*8192 + t0 + tid]; }
    else          { sl[tid] = 0; swt[tid] = 0.f; }
  }
  __syncthreads();

  // gather cont rows + split to hi/lo bf16 (row = token, 16 f32 per thread)
  {
    const int row = tid >> 2;
    const int m0  = (tid & 3) * 16;
    float x[16] = {0.f,0.f,0.f,0.f,0.f,0.f,0.f,0.f,0.f,0.f,0.f,0.f,0.f,0.f,0.f,0.f};
    if (row < nt) {
      const float* p = cont + (size_t)(sl[row] >> 1)*64 + m0;
      *(float4*)&x[0]  = *(const float4*)(p);
      *(float4*)&x[4]  = *(const float4*)(p + 4);
      *(float4*)&x[8]  = *(const float4*)(p + 8);
      *(float4*)&x[12] = *(const float4*)(p + 12);
    }
    unsigned int hp[8], lp[8];
    #pragma unroll
    for (int t = 0; t < 8; ++t) {
      unsigned short h0 = f2bf(x[2*t]);
      unsigned short h1 = f2bf(x[2*t+1]);
      unsigned short l0 = f2bf(x[2*t]   - bf2f(h0));
      unsigned short l1 = f2bf(x[2*t+1] - bf2f(h1));
      hp[t] = (unsigned)h0 | ((unsigned)h1 << 16);
      lp[t] = (unsigned)l0 | ((unsigned)l1 << 16);
    }
    *(uint4*)&cth[row*72 + m0]     = make_uint4(hp[0], hp[1], hp[2], hp[3]);
    *(uint4*)&cth[row*72 + m0 + 8] = make_uint4(hp[4], hp[5], hp[6], hp[7]);
    *(uint4*)&ctl[row*72 + m0]     = make_uint4(lp[0], lp[1], lp[2], lp[3]);
    *(uint4*)&ctl[row*72 + m0 + 8] = make_uint4(lp[4], lp[5], lp[6], lp[7]);
  }

  f32x4 acc2[2][2] = {};

  for (int hc = 0; hc < 1024; hc += 64) {
    // stage this chunk's weights: w1 rows = h-cols (K=m), w2 rows = out-cols (K=h)
    {
      const int row = tid >> 2;
      const int seg = (tid & 3) * 16;
      const size_t o1 = ((size_t)(e*1024 + hc + row))*64 + seg;
      *(uint4*)&w1sh[row*72 + seg]     = *(const uint4*)(w1h + o1);
      *(uint4*)&w1sh[row*72 + seg + 8] = *(const uint4*)(w1h + o1 + 8);
      *(uint4*)&w1sl[row*72 + seg]     = *(const uint4*)(w1l + o1);
      *(uint4*)&w1sl[row*72 + seg + 8] = *(const uint4*)(w1l + o1 + 8);
      const size_t o2 = ((size_t)(e*64 + row))*1024 + hc + seg;
      *(uint4*)&w2sh[row*72 + seg]     = *(const uint4*)(w2h + o2);
      *(uint4*)&w2sh[row*72 + seg + 8] = *(const uint4*)(w2h + o2 + 8);
      *(uint4*)&w2sl[row*72 + seg]     = *(const uint4*)(w2l + o2);
      *(uint4*)&w2sl[row*72 + seg + 8] = *(const uint4*)(w2l + o2 + 8);
    }
    __syncthreads();

    // GEMM1: h[t][col] = sum_m ct[t][m] * w1[col][m], K=64
    f32x4 acc1[2][2] = {};
    #pragma unroll
    for (int ks = 0; ks < 2; ++ks) {
      bf16x8 ah[2], al[2], bh[2], bl[2];
      #pragma unroll
      for (int i = 0; i < 2; ++i) {
        ah[i] = *(const bf16x8*)&cth[(wm + i*16 + fml)*72 + ks*32 + q*8];
        al[i] = *(const bf16x8*)&ctl[(wm + i*16 + fml)*72 + ks*32 + q*8];
      }
      #pragma unroll
      for (int j = 0; j < 2; ++j) {
        bh[j] = *(const bf16x8*)&w1sh[(wn + j*16 + fml)*72 + ks*32 + q*8];
        bl[j] = *(const bf16x8*)&w1sl[(wn + j*16 + fml)*72 + ks*32 + q*8];
      }
      #pragma unroll
      for (int i = 0; i < 2; ++i)
        #pragma unroll
        for (int j = 0; j < 2; ++j) {
          acc1[i][j] = __builtin_amdgcn_mfma_f32_16x16x32_bf16(al[i], bh[j], acc1[i][j], 0, 0, 0);
          acc1[i][j] = __builtin_amdgcn_mfma_f32_16x16x32_bf16(ah[i], bl[j], acc1[i][j], 0, 0, 0);
          acc1[i][j] = __builtin_amdgcn_mfma_f32_16x16x32_bf16(ah[i], bh[j], acc1[i][j], 0, 0, 0);
        }
    }

    // bias + relu + split to hi/lo, write h to LDS (C/D: col=lane&15, row=q*4+r)
    #pragma unroll
    for (int j = 0; j < 2; ++j) {
      const int col = wn + j*16 + fml;
      const float b1 = eb1[(size_t)e*1024 + hc + col];
      #pragma unroll
      for (int i = 0; i < 2; ++i) {
        #pragma unroll
        for (int r = 0; r < 4; ++r) {
          const int trow = wm + i*16 + q*4 + r;
          float v = fmaxf(acc1[i][j][r] + b1, 0.f);
          unsigned short hh = f2bf(v);
          hsh[trow*72 + col] = hh;
          hsl[trow*72 + col] = f2bf(v - bf2f(hh));
        }
      }
    }
    __syncthreads();

    // GEMM2: out[t][n] += sum_h hs[t][h] * w2[n][h], K=64
    #pragma unroll
    for (int ks = 0; ks < 2; ++ks) {
      bf16x8 ah[2], al[2], bh[2], bl[2];
      #pragma unroll
      for (int i = 0; i < 2; ++i) {
        ah[i] = *(const bf16x8*)&hsh[(wm + i*16 + fml)*72 + ks*32 + q*8];
        al[i] = *(const bf16x8*)&hsl[(wm + i*16 + fml)*72 + ks*32 + q*8];
      }
      #pragma unroll
      for (int j = 0; j < 2; ++j) {
        bh[j] = *(const bf16x8*)&w2sh[(wn + j*16 + fml)*72 + ks*32 + q*8];
        bl[j] = *(const bf16x8*)&w2sl[(wn + j*16 + fml)*72 + ks*32 + q*8];
      }
      #pragma unroll
      for (int i = 0; i < 2; ++i)
        #pragma unroll
        for (int j = 0; j < 2; ++j) {
          acc2[i][j] = __builtin_amdgcn_mfma_f32_16x16x32_bf16(al[i], bh[j], acc2[i][j], 0, 0, 0);
          acc2[i][j] = __builtin_amdgcn_mfma_f32_16x16x32_bf16(ah[i], bl[j], acc2[i][j], 0, 0, 0);
          acc2[i][j] = __builtin_amdgcn_mfma_f32_16x16x32_bf16(ah[i], bh[j], acc2[i][j], 0, 0, 0);
        }
    }
    __syncthreads();   // before next chunk overwrites w1s/w2s/hs
  }

  // epilogue: eout[slot][n] = w * (acc + b2)
  #pragma unroll
  for (int j = 0; j < 2; ++j) {
    const int col = wn + j*16 + fml;
    const float b2 = eb2[(size_t)e*64 + col];
    #pragma unroll
    for (int i = 0; i < 2; ++i) {
      #pragma unroll
      for (int r = 0; r < 4; ++r) {
        const int trow = wm + i*16 + q*4 + r;
        if (trow < nt)
          eout[(size_t)sl[trow]*64 + col] = swt[trow]*(acc2[i][j][r] + b2);
      }
    }
  }
}

// ---------------------------------------------------------------- c2s MFMA GEMM, split-bf16 (3 products)
__global__ __launch_bounds__(256) void k_c2sM(
    const float* __restrict__ eoutTok,        // [T][128]
    const unsigned short* __restrict__ WTh,   // [2048][64] bf16 hi
    const unsigned short* __restrict__ WTl,   // [2048][64] bf16 lo
    const float* __restrict__ bias,           // [2048]
    unsigned short* __restrict__ rates)       // [T][2048]
{
  __shared__ __align__(16) unsigned short Ahs[128*72], Als[128*72];
  __shared__ __align__(16) unsigned short Bhs[128*72], Bls[128*72];
  const int tid  = threadIdx.x;
  const int lane = tid & 63;
  const int wave = tid >> 6;
  const int wm = (wave >> 1) * 64;
  const int wn = (wave & 1) * 64;
  const int bm = blockIdx.y * 128;
  const int bn = blockIdx.x * 128;
  const int fml = lane & 15;
  const int q  = lane >> 4;

  {
    const int row = tid >> 1;          // 0..127
    const int m0  = (tid & 1) * 32;    // 0 or 32
    const float* p = eoutTok + (size_t)(bm + row)*128 + m0;
    float x[32];
    #pragma unroll
    for (int i = 0; i < 8; ++i) {
      float4 a = *(const float4*)(p + i*4);
      float4 b = *(const float4*)(p + 64 + i*4);
      x[i*4+0] = a.x + b.x; x[i*4+1] = a.y + b.y;
      x[i*4+2] = a.z + b.z; x[i*4+3] = a.w + b.w;
    }
    unsigned int hp[16], lp[16];
    #pragma unroll
    for (int t = 0; t < 16; ++t) {
      unsigned short h0 = f2bf(x[2*t]);
      unsigned short h1 = f2bf(x[2*t+1]);
      unsigned short l0 = f2bf(x[2*t]   - bf2f(h0));
      unsigned short l1 = f2bf(x[2*t+1] - bf2f(h1));
      hp[t] = (unsigned)h0 | ((unsigned)h1 << 16);
      lp[t] = (unsigned)l0 | ((unsigned)l1 << 16);
    }
    #pragma unroll
    for (int t = 0; t < 4; ++t) {
      *(uint4*)&Ahs[row*72 + m0 + t*8] = make_uint4(hp[t*4+0],hp[t*4+1],hp[t*4+2],hp[t*4+3]);
      *(uint4*)&Als[row*72 + m0 + t*8] = make_uint4(lp[t*4+0],lp[t*4+1],lp[t*4+2],lp[t*4+3]);
    }
    const unsigned short* ph = WTh + (size_t)(bn + row)*64 + m0;
    const unsigned short* pl = WTl + (size_t)(bn + row)*64 + m0;
    #pragma unroll
    for (int t = 0; t < 4; ++t) {
      *(uint4*)&Bhs[row*72 + m0 + t*8] = *(const uint4*)(ph + t*8);
      *(uint4*)&Bls[row*72 + m0 + t*8] = *(const uint4*)(pl + t*8);
    }
  }
  __syncthreads();

  f32x4 acc[4][4] = {};
  #pragma unroll
  for (int ks = 0; ks < 2; ++ks) {
    bf16x8 ah[4], al[4], bh[4], bl[4];
    #pragma unroll
    for (int i = 0; i < 4; ++i) {
      ah[i] = *(const bf16x8*)&Ahs[(wm + i*16 + fml)*72 + ks*32 + q*8];
      al[i] = *(const bf16x8*)&Als[(wm + i*16 + fml)*72 + ks*32 + q*8];
    }
    #pragma unroll
    for (int j = 0; j < 4; ++j) {
      bh[j] = *(const bf16x8*)&Bhs[(wn + j*16 + fml)*72 + ks*32 + q*8];
      bl[j] = *(const bf16x8*)&Bls[(wn + j*16 + fml)*72 + ks*32 + q*8];
    }
    #pragma unroll
    for (int i = 0; i < 4; ++i)
      #pragma unroll
      for (int j = 0; j < 4; ++j) {
        acc[i][j] = __builtin_amdgcn_mfma_f32_16x16x32_bf16(al[i], bh[j], acc[i][j], 0, 0, 0);
        acc[i][j] = __builtin_amdgcn_mfma_f32_16x16x32_bf16(ah[i], bl[j], acc[i][j], 0, 0, 0);
        acc[i][j] = __builtin_amdgcn_mfma_f32_16x16x32_bf16(ah[i], bh[j], acc[i][j], 0, 0, 0);
      }
  }

  #pragma unroll
  for (int j = 0; j < 4; ++j) {
    const int col = bn + wn + j*16 + fml;
    const float bv = bias[col];
    #pragma unroll
    for (int i = 0; i < 4; ++i) {
      #pragma unroll
      for (int r = 0; r < 4; ++r) {
        const int row = bm + wm + i*16 + q*4 + r;
        rates[(size_t)row*H_ + col] = f2bf(sigf(acc[i][j][r] + bv));
      }
    }
  }
}

// ---------------------------------------------------------------- c2s 256-col slice -> f32 (fallback path)
__global__ __launch_bounds__(256) void k_c2sS(const float* __restrict__ eoutTok,
    const float* __restrict__ W, int coff,
    const float* __restrict__ bias, float* __restrict__ rat)
{
  __shared__ float ml[8][64];
  const int tid = threadIdx.x;
  const int n0 = blockIdx.x * 8;
  for (int i = tid; i < 512; i += 256) {
    int t = i >> 6, m = i & 63;
    ml[t][m] = eoutTok[(size_t)(n0+t)*128 + m] + eoutTok[(size_t)(n0+t)*128 + 64 + m];
  }
  __syncthreads();
  float acc[8] = {};
  for (int m = 0; m < 64; ++m) {
    float wv = W[(size_t)m*H_ + coff + tid];
    #pragma unroll
    for (int t = 0; t < 8; ++t) acc[t] += ml[t][m] * wv;
  }
  float bv = bias[coff + tid];
  #pragma unroll
  for (int t = 0; t < 8; ++t)
    rat[(size_t)(n0+t)*256 + tid] = sigf(acc[t] + bv);
}

// ---------------------------------------------------------------- f32 -> bf16 transpose (dec_W [R][C] -> out [C][R])
__global__ __launch_bounds__(256) void k_transb(const float* __restrict__ in,
    unsigned short* __restrict__ out, int R, int C) {
  __shared__ unsigned short t[32][33];
  int c0 = blockIdx.x*32, r0 = blockIdx.y*32;
  int tx = threadIdx.x & 31, ty = threadIdx.x >> 5;
  #pragma unroll
  for (int i = 0; i < 32; i += 8)
    t[ty+i][tx] = f2bf(in[(size_t)(r0+ty+i)*C + (c0+tx)]);
  __syncthreads();
  #pragma unroll
  for (int i = 0; i < 32; i += 8)
    out[(size_t)(c0+ty+i)*R + (r0+tx)] = t[tx][ty+i];
}

// ---------------------------------------------------------------- dec MFMA GEMM + XCD bijective swizzle
__global__ __launch_bounds__(256) void k_dgemm(
    const unsigned short* __restrict__ A,
    const unsigned short* __restrict__ BT,
    const float* __restrict__ bias,
    const float* __restrict__ gains,
    float* __restrict__ C)
{
  __shared__ __align__(16) unsigned short As[128*40];
  __shared__ __align__(16) unsigned short Bs[128*40];
  const int tid  = threadIdx.x;
  const int lane = tid & 63;
  const int wave = tid >> 6;
  const int wm = (wave >> 1) * 64;
  const int wn = (wave & 1) * 64;
  // XCD-aware bijective swizzle: nwg = 8*gy (%8==0)
  const int gy   = gridDim.y;
  const int flat = blockIdx.y * 8 + blockIdx.x;
  const int swz  = (flat & 7) * gy + (flat >> 3);
  const int bn = (swz & 7) * 128;
  const int bm = (swz >> 3) * 128;
  const int fml = lane & 15;
  const int q  = lane >> 4;
  const int r0a  = tid >> 2;
  const int sseg = tid & 3;

  f32x4 acc[4][4] = {};

  for (int k0 = 0; k0 < H_; k0 += 32) {
    #pragma unroll
    for (int half = 0; half < 2; ++half) {
      int r = r0a + half*64;
      *(uint4*)(&As[r*40 + sseg*8]) = *(const uint4*)(A + (size_t)(bm + r)*H_ + k0 + sseg*8);
      *(uint4*)(&Bs[r*40 + sseg*8]) = *(const uint4*)(BT + (size_t)(bn + r)*H_ + k0 + sseg*8);
    }
    __syncthreads();
    bf16x8 af[4], bfr[4];
    #pragma unroll
    for (int i = 0; i < 4; ++i)
      af[i] = *(const bf16x8*)(&As[(wm + i*16 + fml)*40 + q*8]);
    #pragma unroll
    for (int j = 0; j < 4; ++j)
      bfr[j] = *(const bf16x8*)(&Bs[(wn + j*16 + fml)*40 + q*8]);
    #pragma unroll
    for (int i = 0; i < 4; ++i)
      #pragma unroll
      for (int j = 0; j < 4; ++j)
        acc[i][j] = __builtin_amdgcn_mfma_f32_16x16x32_bf16(af[i], bfr[j], acc[i][j], 0, 0, 0);
    __syncthreads();
  }
  #pragma unroll
  for (int i = 0; i < 4; ++i) {
    #pragma unroll
    for (int j = 0; j < 4; ++j) {
      int col = bn + wn + j*16 + fml;
      float bv = bias[col];
      #pragma unroll
      for (int r = 0; r < 4; ++r) {
        int row = bm + wm + i*16 + q*4 + r;
        C[(size_t)row*D_ + col] = gains[row]*acc[i][j][r] + bv;
      }
    }
  }
}

// ---------------------------------------------------------------- layernorm D=1024 in-place
__global__ __launch_bounds__(256) void k_ln(float* __restrict__ X,
    const float* __restrict__ g, const float* __restrict__ b)
{
  const int n = blockIdx.x, tid = threadIdx.x;
  float4* row = (float4*)(X + (size_t)n*D_);
  const float4 xv = row[tid];
  float xa[4] = {xv.x, xv.y, xv.z, xv.w};
  float s = xa[0]+xa[1]+xa[2]+xa[3];
  float ss = xa[0]*xa[0]+xa[1]*xa[1]+xa[2]*xa[2]+xa[3]*xa[3];
  #pragma unroll
  for (int off = 32; off >= 1; off >>= 1) {
    s  += __shfl_down(s, off);
    ss += __shfl_down(ss, off);
  }
  __shared__ float rs[4], rss[4];
  const int lane = tid & 63, wv = tid >> 6;
  if (lane == 0) { rs[wv] = s; rss[wv] = ss; }
  __syncthreads();
  float S0 = rs[0]+rs[1]+rs[2]+rs[3];
  float SS = rss[0]+rss[1]+rss[2]+rss[3];
  float mu = S0 * (1.f/(float)D_);
  float var = SS * (1.f/(float)D_) - mu*mu;
  float inv = rsqrtf(var + 1e-5f);
  int idx = tid*4;
  float4 o;
  o.x = (xa[0]-mu)*inv*g[idx+0] + b[idx+0];
  o.y = (xa[1]-mu)*inv*g[idx+1] + b[idx+1];
  o.z = (xa[2]-mu)*inv*g[idx+2] + b[idx+2];
  o.w = (xa[3]-mu)*inv*g[idx+3] + b[idx+3];
  row[tid] = o;
}

// ----------------------------------------------------------------
// ws layout:
//   [0x000000,0x200000) cont f32[8192][64]
//   [0x200000,0x300000) c2s_WT hi/lo bf16 [2048][64] (path A only)
//   [0x400000,0x800000) eout f32[16384][64]
//   0x800000 gains | 0x808000 cnt | 0x809000 list | 0x849000 lw
//   [0x890000,0x8D0000) vinitF float[16*4096] (enc GIF CS=128 + dec GIF)
//   0x900000 (4 MiB): WhT (enc) -> expert weights w1th/w1tl/w2th/w2tl -> decWT (dec)
//   0xD00000 (4 MiB): WlT (enc)  -> rates (dec path A, T*4 KiB from 0xD00000)
//   [0x1100000,0x3100000) encAh/encAl bf16 [8192][1024] each (enc pre-split, needs ws>=50 MiB)
// Enc scratch cur f32[8192][1024] = 32 MiB per H-chunk lives in d_out.
extern "C" void kernel_launch(void* const* d_in, const int* in_sizes, int n_in,
                              void* d_out, int out_size, void* d_ws, size_t ws_size,
                              hipStream_t stream) {
  (void)in_sizes; (void)n_in; (void)out_size;
  const float* embeds = (const float*)d_in[0];
  const int*   ids    = (const int*)d_in[1];
  const float* pros   = (const float*)d_in[2];
  const float* enc_W  = (const float*)d_in[3];
  const float* enc_b  = (const float*)d_in[4];
  const float* s2c_W  = (const float*)d_in[5];
  const float* s2c_b  = (const float*)d_in[6];
  const float* r_W1   = (const float*)d_in[7];
  const float* r_b1   = (const float*)d_in[8];
  const float* r_W2   = (const float*)d_in[9];
  const float* r_b2   = (const float*)d_in[10];
  const float* e_W1   = (const float*)d_in[11];
  const float* e_b1   = (const float*)d_in[12];
  const float* e_W2   = (const float*)d_in[13];
  const float* e_b2   = (const float*)d_in[14];
  const float* c2s_W  = (const float*)d_in[15];
  const float* c2s_b  = (const float*)d_in[16];
  const float* dec_W  = (const float*)d_in[17];
  const float* dec_b  = (const float*)d_in[18];
  const float* ln_g   = (const float*)d_in[19];
  const float* ln_b   = (const float*)d_in[20];

  char* ws = (char*)d_ws;
  float*          contp = (float*)ws;
  unsigned short* c2sWTh= (unsigned short*)(ws + (size_t)0x200000); // 256 KiB
  unsigned short* c2sWTl= (unsigned short*)(ws + (size_t)0x280000); // 256 KiB
  float*          eout  = (float*)(ws + (size_t)0x400000);
  float*          gains = (float*)(ws + (size_t)0x800000);
  int*            cnt   = (int*)(ws + (size_t)0x808000);
  unsigned int*   list  = (unsigned int*)(ws + (size_t)0x809000);
  float*          lw    = (float*)(ws + (size_t)0x849000);
  float*          vinitF= (float*)(ws + (size_t)0x890000);          // GIF f32 (256 KiB)
  unsigned short* WhT   = (unsigned short*)(ws + (size_t)0x900000); // -> expert w / decWT
  unsigned short* WlT   = (unsigned short*)(ws + (size_t)0xD00000); // -> rates
  unsigned short* encAh = (unsigned short*)(ws + (size_t)0x1100000); // 16 MiB (enc only)
  unsigned short* encAl = (unsigned short*)(ws + (size_t)0x2100000); // 16 MiB (enc only)
  unsigned short* decWT = WhT;
  unsigned short* rates = WlT;
  float*          ratSf = (float*)ws;              // fallback overlay of cont
  float*          cur   = (float*)d_out;           // enc scratch [8192][1024]

  // expert split-bf16 weights live in the WhT window between enc GEMM and k_transb
  unsigned short* w1th = WhT;                         // [8][1024][64] 1 MiB
  unsigned short* w1tl = w1th + (size_t)8*1024*64;    // 1 MiB
  unsigned short* w2th = w1tl + (size_t)8*1024*64;    // [8][64][1024] 1 MiB
  unsigned short* w2tl = w2th + (size_t)8*1024*64;    // 1 MiB (ends at 0xD00000)

  const int encM  = (ws_size >= (size_t)18*1024*1024) ? 1 : 0;
  const int encPA = (encM && ws_size >= (size_t)50*1024*1024) ? 1 : 0;
  const int T = (ws_size >= (size_t)46*1024*1024) ? 8192
              : (ws_size >= (size_t)30*1024*1024) ? 4096 : 0;

  k_gains<<<N_TOK/256, 256, 0, stream>>>(ids, pros, gains);
  k_zero<<<1, 64, 0, stream>>>(cnt);

  // ---- encoder: 2 H-chunks of 1024; GIF f32 at CS=128; fused s2c (KH=1024) ----
  if (encM) {
    k_splitT<<<dim3(64, 32), 256, 0, stream>>>(enc_W, WhT, WlT);
    if (encPA)
      k_asplit<<<4096, 256, 0, stream>>>(embeds, encAh, encAl);
    for (int c = 0; c < 2; ++c) {
      if (encPA) {
        k_egemm3<<<dim3(8, 64), 256, 0, stream>>>(
            encAh, encAl, WhT + (size_t)c*1024*1024, WlT + (size_t)c*1024*1024,
            enc_b + c*1024, gains, cur);
      } else {
        k_egemm<<<dim3(8, 64), 256, 0, stream>>>(
            embeds, WhT + (size_t)c*1024*1024, WlT + (size_t)c*1024*1024,
            enc_b + c*1024, gains, cur);
      }
      k_gif_warm32<<<dim3(16, 16), 256, 0, stream>>>(cur, vinitF, 1024, 128, S_);
      k_gif_emit32<<<dim3(16, 16), 256, 0, stream>>>(cur, vinitF, 1024, 128, S_);
      k_s2c<<<N_TOK/16, 256, 0, stream>>>(cur, 1024, 1024,
          s2c_W, (size_t)c*1024*64, contp, (c > 0),
          (c == 1) ? s2c_b : (const float*)nullptr);
    }
    // enc done reading WhT/WlT -> build expert split-bf16 weights in that window
    k_tsplit<<<dim3(32, 2, 8), 256, 0, stream>>>(e_W1, w1th, w1tl, 64, 1024);
    k_tsplit<<<dim3(2, 32, 8), 256, 0, stream>>>(e_W2, w2th, w2tl, 1024, 64);
  } else {
    for (int c = 0; c < 2; ++c) {
      k_genc<<<dim3(8, 64), 256, 0, stream>>>(
          embeds, D_, enc_W, H_, c*1024, enc_b, gains, cur, 1024, D_, 3);
      k_gif_warm32<<<dim3(16, 16), 256, 0, stream>>>(cur, vinitF, 1024, 128, S_);
      k_gif_emit32<<<dim3(16, 16), 256, 0, stream>>>(cur, vinitF, 1024, 128, S_);
      k_s2c<<<N_TOK/16, 256, 0, stream>>>(cur, 1024, 1024,
          s2c_W, (size_t)c*1024*64, contp, (c > 0),
          (c == 1) ? s2c_b : (const float*)nullptr);
    }
  }

  // ---- router: fused hidden + top-2 (f32) ----
  k_router2<<<N_TOK/16, 256, 0, stream>>>(contp, r_W1, r_b1, r_W2, r_b2,
                                          gains, cnt, list, lw);

  if (encM) {
    k_expmfma<<<dim3(128, 8), 256, 0, stream>>>(contp, list, lw, cnt,
        w1th, w1tl, e_b1, w2th, w2tl, e_b2, eout);
  } else {
    k_expgrp<<<dim3(128, 8), 256, 0, stream>>>(contp, list, lw, cnt,
        e_W1, e_b1, e_W2, e_b2, eout);
  }

  if (T > 0) {
    // ---- decoder path A: bf16 MFMA; GIF f32 ----
    k_transb<<<dim3(32, 64), 256, 0, stream>>>(dec_W, decWT, H_, D_);
    k_tsplit<<<dim3(64, 2, 1), 256, 0, stream>>>(c2s_W, c2sWTh, c2sWTl, 64, H_);
    for (int tok0 = 0; tok0 < N_TOK; tok0 += T) {
      k_c2sM<<<dim3(H_/128, T/128), 256, 0, stream>>>(eout + (size_t)tok0*128,
          c2sWTh, c2sWTl, c2s_b, rates);
      float* cur2 = (float*)d_out + (size_t)tok0*D_;
      k_dgemm<<<dim3(D_/128, T/128), 256, 0, stream>>>(
          rates, decWT, dec_b, gains + tok0, cur2);
      int channels = (T/2048)*1024;
      k_gif_warm32<<<dim3(channels/256, 8), 256, 0, stream>>>(cur2, vinitF, D_, 256, S_);
      k_gif_emit32<<<dim3(channels/256, 8), 256, 0, stream>>>(cur2, vinitF, D_, 256, S_);
      k_ln<<<T, 256, 0, stream>>>(cur2, ln_g, ln_b);
    }
  } else {
    // ---- decoder fallback: f32 SIMT, 2 halves x 8 K-slices ----
    for (int hb = 0; hb < 2; ++hb) {
      float* cur2 = (float*)d_out + (size_t)hb*4096*D_;
      for (int kh = 0; kh < 8; ++kh) {
        k_c2sS<<<4096/8, 256, 0, stream>>>(eout + (size_t)hb*4096*128,
            c2s_W, kh*256, c2s_b, ratSf);
        int mode = (kh == 0) ? 0 : ((kh < 7) ? 1 : 2);
        k_genc<<<dim3(8, 32), 256, 0, stream>>>(
            ratSf, 256, dec_W + (size_t)kh*256*D_, D_, 0, dec_b,
            gains + hb*4096, cur2, D_, 256, mode);
      }
      k_gif_warm32<<<dim3(8, 8), 256, 0, stream>>>(cur2, vinitF, D_, 256, S_);
      k_gif_emit32<<<dim3(8, 8), 256, 0, stream>>>(cur2, vinitF, D_, 256, S_);
      k_ln<<<4096, 256, 0, stream>>>(cur2, ln_g, ln_b);
    }
  }
}

// Round 13
// 602.017 us; speedup vs baseline: 1.1249x; 1.0929x over previous
//
#include <hip/hip_runtime.h>
#include <math.h>

#define B_ 4
#define S_ 2048
#define D_ 1024
#define H_ 2048
#define N_TOK 8192
#define HALO 256
#define VOCAB_ 32000

typedef short bf16x8 __attribute__((ext_vector_type(8)));
typedef float f32x4 __attribute__((ext_vector_type(4)));

__device__ __forceinline__ float sigf(float x) {
  return 1.0f / (1.0f + __expf(-x));
}
__device__ __forceinline__ float bf2f(unsigned short u) {
  union { unsigned int i; float f; } x; x.i = ((unsigned int)u) << 16; return x.f;
}
__device__ __forceinline__ unsigned short f2bf(float f) {
  union { float f; unsigned int i; } x; x.f = f;
  unsigned int r = x.i + 0x7fffu + ((x.i >> 16) & 1u);
  return (unsigned short)(r >> 16);
}

// ---------------------------------------------------------------- gains (f32 tanh)
__global__ __launch_bounds__(256) void k_gains(const int* __restrict__ ids,
    const float* __restrict__ table, float* __restrict__ gains) {
  int i = blockIdx.x*256 + threadIdx.x;
  int id = ids[i];
  id = id < 0 ? 0 : (id >= VOCAB_ ? VOCAB_-1 : id);
  gains[i] = 1.0f + tanhf(table[id]);
}

// ---------------------------------------------------------------- f32 SIMT GEMM (fallback enc/dec)
__global__ __launch_bounds__(256) void k_genc(
    const float* __restrict__ A, int lda,
    const float* __restrict__ W, int ldw, int c0,
    const float* __restrict__ bias,
    const float* __restrict__ gains,
    float* __restrict__ C, int ldc,
    int K, int mode)
{
  __shared__ float As2[16][132];
  __shared__ float Bs[16][128];
  const int tid = threadIdx.x;
  const int tx = tid & 15;
  const int ty = tid >> 4;
  const int bm = blockIdx.y * 128;
  const int bn = blockIdx.x * 128;

  double acc[8][8];
  float part[8][8];
  #pragma unroll
  for (int i = 0; i < 8; ++i)
    #pragma unroll
    for (int j = 0; j < 8; ++j) { acc[i][j] = 0.0; part[i][j] = 0.f; }

  const int e = tid * 8;
  const int ar = e >> 4, ak = e & 15;
  const int bk = e >> 7, bc = e & 127;

  for (int k0 = 0; k0 < K; k0 += 16) {
    {
      const float* pa = A + (size_t)(bm + ar)*lda + k0 + ak;
      float4 v0 = *(const float4*)pa;
      float4 v1 = *(const float4*)(pa + 4);
      As2[ak+0][ar] = v0.x; As2[ak+1][ar] = v0.y;
      As2[ak+2][ar] = v0.z; As2[ak+3][ar] = v0.w;
      As2[ak+4][ar] = v1.x; As2[ak+5][ar] = v1.y;
      As2[ak+6][ar] = v1.z; As2[ak+7][ar] = v1.w;
    }
    {
      const float* pw = W + (size_t)(k0 + bk)*ldw + c0 + bn + bc;
      *(float4*)&Bs[bk][bc]   = *(const float4*)pw;
      *(float4*)&Bs[bk][bc+4] = *(const float4*)(pw + 4);
    }
    __syncthreads();
    #pragma unroll
    for (int kk = 0; kk < 16; ++kk) {
      float a8[8], b8[8];
      *(float4*)&a8[0] = *(const float4*)&As2[kk][ty*8];
      *(float4*)&a8[4] = *(const float4*)&As2[kk][ty*8+4];
      *(float4*)&b8[0] = *(const float4*)&Bs[kk][tx*8];
      *(float4*)&b8[4] = *(const float4*)&Bs[kk][tx*8+4];
      #pragma unroll
      for (int i = 0; i < 8; ++i)
        #pragma unroll
        for (int j = 0; j < 8; ++j)
          part[i][j] += a8[i]*b8[j];
    }
    __syncthreads();
    #pragma unroll
    for (int i = 0; i < 8; ++i)
      #pragma unroll
      for (int j = 0; j < 8; ++j) { acc[i][j] += (double)part[i][j]; part[i][j] = 0.f; }
  }

  #pragma unroll
  for (int i = 0; i < 8; ++i) {
    const int row = bm + ty*8 + i;
    const double g = (mode >= 2) ? (double)gains[row] : 0.0;
    #pragma unroll
    for (int j = 0; j < 8; ++j) {
      const int col = bn + tx*8 + j;
      const size_t idx = (size_t)row*ldc + col;
      if (mode == 0)      C[idx] = (float)acc[i][j];
      else if (mode == 1) C[idx] += (float)acc[i][j];
      else if (mode == 2) C[idx] = (float)(g*((double)C[idx] + acc[i][j]) + (double)bias[c0+col]);
      else                C[idx] = (float)(g*acc[i][j] + (double)bias[c0+col]);
    }
  }
}

// ---------------------------------------------------------------- transpose+split enc_W [1024][2048] f32 -> WhT/WlT [2048][1024] bf16
__global__ __launch_bounds__(256) void k_splitT(const float* __restrict__ in,
    unsigned short* __restrict__ outh, unsigned short* __restrict__ outl) {
  __shared__ unsigned short th[32][33];
  __shared__ unsigned short tl[32][33];
  int c0 = blockIdx.x*32, r0 = blockIdx.y*32;
  int tx = threadIdx.x & 31, ty = threadIdx.x >> 5;
  #pragma unroll
  for (int i = 0; i < 32; i += 8) {
    float x = in[(size_t)(r0+ty+i)*H_ + (c0+tx)];
    unsigned short h = f2bf(x);
    th[ty+i][tx] = h;
    tl[ty+i][tx] = f2bf(x - bf2f(h));
  }
  __syncthreads();
  #pragma unroll
  for (int i = 0; i < 32; i += 8) {
    outh[(size_t)(c0+ty+i)*D_ + (r0+tx)] = th[tx][ty+i];
    outl[(size_t)(c0+ty+i)*D_ + (r0+tx)] = tl[tx][ty+i];
  }
}

// ---------------------------------------------------------------- generic batched transpose+split: in [Z][R][C] f32 -> oh/ol [Z][C][R] bf16
__global__ __launch_bounds__(256) void k_tsplit(const float* __restrict__ in,
    unsigned short* __restrict__ oh, unsigned short* __restrict__ ol,
    int R, int C) {
  __shared__ unsigned short th[32][33];
  __shared__ unsigned short tl[32][33];
  const size_t mat = (size_t)R*C;
  in += (size_t)blockIdx.z * mat;
  oh += (size_t)blockIdx.z * mat;
  ol += (size_t)blockIdx.z * mat;
  int c0 = blockIdx.x*32, r0 = blockIdx.y*32;
  int tx = threadIdx.x & 31, ty = threadIdx.x >> 5;
  #pragma unroll
  for (int i = 0; i < 32; i += 8) {
    float x = in[(size_t)(r0+ty+i)*C + (c0+tx)];
    unsigned short h = f2bf(x);
    th[ty+i][tx] = h;
    tl[ty+i][tx] = f2bf(x - bf2f(h));
  }
  __syncthreads();
  #pragma unroll
  for (int i = 0; i < 32; i += 8) {
    oh[(size_t)(c0+ty+i)*R + (r0+tx)] = th[tx][ty+i];
    ol[(size_t)(c0+ty+i)*R + (r0+tx)] = tl[tx][ty+i];
  }
}

// ---------------------------------------------------------------- row-major f32 -> bf16 hi/lo split (no transpose), 8 elems/thread
__global__ __launch_bounds__(256) void k_asplit(const float* __restrict__ in,
    unsigned short* __restrict__ oh, unsigned short* __restrict__ ol) {
  const size_t i = ((size_t)blockIdx.x*256 + threadIdx.x) * 8;
  float4 v0 = *(const float4*)(in + i);
  float4 v1 = *(const float4*)(in + i + 4);
  float xs[8] = {v0.x, v0.y, v0.z, v0.w, v1.x, v1.y, v1.z, v1.w};
  unsigned int hp[4], lp[4];
  #pragma unroll
  for (int t = 0; t < 4; ++t) {
    unsigned short h0 = f2bf(xs[2*t]);
    unsigned short h1 = f2bf(xs[2*t+1]);
    unsigned short l0 = f2bf(xs[2*t]   - bf2f(h0));
    unsigned short l1 = f2bf(xs[2*t+1] - bf2f(h1));
    hp[t] = (unsigned)h0 | ((unsigned)h1 << 16);
    lp[t] = (unsigned)l0 | ((unsigned)l1 << 16);
  }
  *(uint4*)(oh + i) = make_uint4(hp[0], hp[1], hp[2], hp[3]);
  *(uint4*)(ol + i) = make_uint4(lp[0], lp[1], lp[2], lp[3]);
}

// ---------------------------------------------------------------- enc MFMA GEMM (legacy, in-kernel A split) — fallback tier
__global__ __launch_bounds__(256) void k_egemm(
    const float* __restrict__ A,              // embeds f32 [8192][1024]
    const unsigned short* __restrict__ Bh,    // WhT + chunk offset, [1024][1024] bf16
    const unsigned short* __restrict__ Bl,
    const float* __restrict__ bias,           // enc_b + chunk offset
    const float* __restrict__ gains,
    float* __restrict__ C)                    // cur [8192][1024]
{
  __shared__ __align__(16) unsigned short Ahs[128*40];
  __shared__ __align__(16) unsigned short Als[128*40];
  __shared__ __align__(16) unsigned short Bhs[128*40];
  __shared__ __align__(16) unsigned short Bls[128*40];
  const int tid  = threadIdx.x;
  const int lane = tid & 63;
  const int wave = tid >> 6;
  const int wm = (wave >> 1) * 64;
  const int wn = (wave & 1) * 64;
  const int bm = blockIdx.y * 128;
  const int bn = blockIdx.x * 128;
  const int fml = lane & 15;
  const int q  = lane >> 4;
  const int r0a  = tid >> 2;
  const int sseg = tid & 3;

  f32x4 acc[4][4] = {};

  for (int k0 = 0; k0 < 1024; k0 += 32) {
    #pragma unroll
    for (int half = 0; half < 2; ++half) {
      int r = r0a + half*64;
      const float* pa = A + (size_t)(bm + r)*1024 + k0 + sseg*8;
      float4 v0 = *(const float4*)pa;
      float4 v1 = *(const float4*)(pa + 4);
      float xs[8] = {v0.x, v0.y, v0.z, v0.w, v1.x, v1.y, v1.z, v1.w};
      unsigned int hp[4], lp[4];
      #pragma unroll
      for (int t = 0; t < 4; ++t) {
        unsigned short h0 = f2bf(xs[2*t]);
        unsigned short h1 = f2bf(xs[2*t+1]);
        unsigned short l0 = f2bf(xs[2*t]   - bf2f(h0));
        unsigned short l1 = f2bf(xs[2*t+1] - bf2f(h1));
        hp[t] = (unsigned)h0 | ((unsigned)h1 << 16);
        lp[t] = (unsigned)l0 | ((unsigned)l1 << 16);
      }
      *(uint4*)(&Ahs[r*40 + sseg*8]) = make_uint4(hp[0], hp[1], hp[2], hp[3]);
      *(uint4*)(&Als[r*40 + sseg*8]) = make_uint4(lp[0], lp[1], lp[2], lp[3]);
      *(uint4*)(&Bhs[r*40 + sseg*8]) = *(const uint4*)(Bh + (size_t)(bn + r)*1024 + k0 + sseg*8);
      *(uint4*)(&Bls[r*40 + sseg*8]) = *(const uint4*)(Bl + (size_t)(bn + r)*1024 + k0 + sseg*8);
    }
    __syncthreads();
    bf16x8 afh[4], afl[4], bfh[4], bfl[4];
    #pragma unroll
    for (int i = 0; i < 4; ++i) {
      afh[i] = *(const bf16x8*)(&Ahs[(wm + i*16 + fml)*40 + q*8]);
      afl[i] = *(const bf16x8*)(&Als[(wm + i*16 + fml)*40 + q*8]);
    }
    #pragma unroll
    for (int j = 0; j < 4; ++j) {
      bfh[j] = *(const bf16x8*)(&Bhs[(wn + j*16 + fml)*40 + q*8]);
      bfl[j] = *(const bf16x8*)(&Bls[(wn + j*16 + fml)*40 + q*8]);
    }
    #pragma unroll
    for (int i = 0; i < 4; ++i)
      #pragma unroll
      for (int j = 0; j < 4; ++j) {
        acc[i][j] = __builtin_amdgcn_mfma_f32_16x16x32_bf16(afl[i], bfh[j], acc[i][j], 0, 0, 0);
        acc[i][j] = __builtin_amdgcn_mfma_f32_16x16x32_bf16(afh[i], bfl[j], acc[i][j], 0, 0, 0);
        acc[i][j] = __builtin_amdgcn_mfma_f32_16x16x32_bf16(afh[i], bfh[j], acc[i][j], 0, 0, 0);
      }
    __syncthreads();
  }
  #pragma unroll
  for (int i = 0; i < 4; ++i) {
    #pragma unroll
    for (int j = 0; j < 4; ++j) {
      int col = bn + wn + j*16 + fml;
      float bv = bias[col];
      #pragma unroll
      for (int r = 0; r < 4; ++r) {
        int row = bm + wm + i*16 + q*4 + r;   // C/D: col=lane&15, row=quad*4+reg
        C[(size_t)row*D_ + col] = gains[row]*acc[i][j][r] + bv;
      }
    }
  }
}

// ---------------------------------------------------------------- enc MFMA GEMM v3: pre-split A, B chunk [1024][1024], C ld=1024, XCD swizzle
__global__ __launch_bounds__(256) void k_egemm3(
    const unsigned short* __restrict__ Ah, const unsigned short* __restrict__ Al, // [8192][1024]
    const unsigned short* __restrict__ Bh, const unsigned short* __restrict__ Bl, // [1024][1024]
    const float* __restrict__ bias,           // enc_b + chunk offset
    const float* __restrict__ gains,
    float* __restrict__ C)                    // cur [8192][1024]
{
  __shared__ __align__(16) unsigned short Ahs[128*40];
  __shared__ __align__(16) unsigned short Als[128*40];
  __shared__ __align__(16) unsigned short Bhs[128*40];
  __shared__ __align__(16) unsigned short Bls[128*40];
  const int tid  = threadIdx.x;
  const int lane = tid & 63;
  const int wave = tid >> 6;
  const int wm = (wave >> 1) * 64;
  const int wn = (wave & 1) * 64;
  // XCD-aware bijective swizzle: nwg = 8*64 = 512 (%8==0)
  const int flat = blockIdx.y * 8 + blockIdx.x;
  const int swz  = (flat & 7) * 64 + (flat >> 3);
  const int bn = (swz & 7) * 128;
  const int bm = (swz >> 3) * 128;
  const int fml = lane & 15;
  const int q  = lane >> 4;
  const int r0a  = tid >> 2;
  const int sseg = tid & 3;

  f32x4 acc[4][4] = {};

  for (int k0 = 0; k0 < 1024; k0 += 32) {
    #pragma unroll
    for (int half = 0; half < 2; ++half) {
      int r = r0a + half*64;
      *(uint4*)(&Ahs[r*40 + sseg*8]) = *(const uint4*)(Ah + (size_t)(bm + r)*1024 + k0 + sseg*8);
      *(uint4*)(&Als[r*40 + sseg*8]) = *(const uint4*)(Al + (size_t)(bm + r)*1024 + k0 + sseg*8);
      *(uint4*)(&Bhs[r*40 + sseg*8]) = *(const uint4*)(Bh + (size_t)(bn + r)*1024 + k0 + sseg*8);
      *(uint4*)(&Bls[r*40 + sseg*8]) = *(const uint4*)(Bl + (size_t)(bn + r)*1024 + k0 + sseg*8);
    }
    __syncthreads();
    bf16x8 afh[4], afl[4], bfh[4], bfl[4];
    #pragma unroll
    for (int i = 0; i < 4; ++i) {
      afh[i] = *(const bf16x8*)(&Ahs[(wm + i*16 + fml)*40 + q*8]);
      afl[i] = *(const bf16x8*)(&Als[(wm + i*16 + fml)*40 + q*8]);
    }
    #pragma unroll
    for (int j = 0; j < 4; ++j) {
      bfh[j] = *(const bf16x8*)(&Bhs[(wn + j*16 + fml)*40 + q*8]);
      bfl[j] = *(const bf16x8*)(&Bls[(wn + j*16 + fml)*40 + q*8]);
    }
    #pragma unroll
    for (int i = 0; i < 4; ++i)
      #pragma unroll
      for (int j = 0; j < 4; ++j) {
        acc[i][j] = __builtin_amdgcn_mfma_f32_16x16x32_bf16(afl[i], bfh[j], acc[i][j], 0, 0, 0);
        acc[i][j] = __builtin_amdgcn_mfma_f32_16x16x32_bf16(afh[i], bfl[j], acc[i][j], 0, 0, 0);
        acc[i][j] = __builtin_amdgcn_mfma_f32_16x16x32_bf16(afh[i], bfh[j], acc[i][j], 0, 0, 0);
      }
    __syncthreads();
  }
  #pragma unroll
  for (int i = 0; i < 4; ++i) {
    #pragma unroll
    for (int j = 0; j < 4; ++j) {
      int col = bn + wn + j*16 + fml;
      float bv = bias[col];
      #pragma unroll
      for (int r = 0; r < 4; ++r) {
        int row = bm + wm + i*16 + q*4 + r;
        C[(size_t)row*D_ + col] = gains[row]*acc[i][j][r] + bv;
      }
    }
  }
}

// ---------------------------------------------------------------- GIF scan, f32 fast path (enc + dec)
__global__ __launch_bounds__(256) void k_gif_warm32(const float* __restrict__ buf,
    float* __restrict__ vinit, int Wd, int CS, int Stot)
{
  int c = blockIdx.x*256 + threadIdx.x;
  int channels = gridDim.x*256;
  int chunk = blockIdx.y;
  int b = c / Wd, h = c - b*Wd;
  int s_emit = chunk*CS;
  int s0 = s_emit - HALO; if (s0 < 0) s0 = 0;
  const float* p = buf + (size_t)b*Stot*Wd + h;
  float v = 0.f;
  for (int sg = s0; sg < s_emit; sg += 8) {
    float cv[8];
    #pragma unroll
    for (int i = 0; i < 8; ++i) cv[i] = p[(size_t)(sg+i)*Wd];
    #pragma unroll
    for (int i = 0; i < 8; ++i) {
      v = 0.9f*v + cv[i];
      float s = 1.0f/(1.0f + __expf(-4.0f*(v - 1.0f)));
      v -= s;
    }
  }
  vinit[(size_t)chunk*channels + c] = v;
}

__global__ __launch_bounds__(256) void k_gif_emit32(float* __restrict__ buf,
    const float* __restrict__ vinit, int Wd, int CS, int Stot)
{
  int c = blockIdx.x*256 + threadIdx.x;
  int channels = gridDim.x*256;
  int chunk = blockIdx.y;
  int b = c / Wd, h = c - b*Wd;
  float* p = buf + (size_t)b*Stot*Wd + h + (size_t)chunk*CS*Wd;
  float v = vinit[(size_t)chunk*channels + c];
  float cv[8], nv[8] = {0,0,0,0,0,0,0,0};
  #pragma unroll
  for (int i = 0; i < 8; ++i) cv[i] = p[(size_t)i*Wd];
  for (int sg = 0; sg < CS; sg += 8) {
    float sp[8];
    #pragma unroll
    for (int i = 0; i < 8; ++i) {
      v = 0.9f*v + cv[i];
      float s = 1.0f/(1.0f + __expf(-4.0f*(v - 1.0f)));
      v -= s; sp[i] = s;
    }
    if (sg + 8 < CS) {
      #pragma unroll
      for (int i = 0; i < 8; ++i) nv[i] = p[(size_t)(sg+8+i)*Wd];
    }
    #pragma unroll
    for (int i = 0; i < 8; ++i) p[(size_t)(sg+i)*Wd] = sp[i];
    #pragma unroll
    for (int i = 0; i < 8; ++i) cv[i] = nv[i];
  }
}

// ---------------------------------------------------------------- s2c split-bf16 MFMA: cont[8192][64] (+)= cur[8192][1024] @ s2c_W chunk
// A split in-kernel; WT pre-split [64][2048]. M-tile 64, K-step 32, 4 waves 2x2.
__global__ __launch_bounds__(256) void k_s2cM(
    const float* __restrict__ A,                // cur f32 [8192][1024]
    const unsigned short* __restrict__ WTh,     // [64][2048] bf16 hi
    const unsigned short* __restrict__ WTl,     // [64][2048] bf16 lo
    size_t woff,                                // chunk col offset (c*1024)
    float* __restrict__ out,                    // cont [8192][64]
    int accum, const float* __restrict__ bias2)
{
  __shared__ __align__(16) unsigned short Ahs[64*40], Als[64*40];
  __shared__ __align__(16) unsigned short Bhs[64*40], Bls[64*40];
  const int tid  = threadIdx.x;
  const int lane = tid & 63;
  const int wave = tid >> 6;
  const int wm = (wave >> 1) * 32;
  const int wn = (wave & 1) * 32;
  const int bm = blockIdx.x * 64;
  const int fml = lane & 15;
  const int q  = lane >> 4;
  const int r0a  = tid >> 2;   // 0..63
  const int sseg = tid & 3;

  f32x4 acc[2][2] = {};

  for (int k0 = 0; k0 < 1024; k0 += 32) {
    {
      const float* pa = A + (size_t)(bm + r0a)*1024 + k0 + sseg*8;
      float4 v0 = *(const float4*)pa;
      float4 v1 = *(const float4*)(pa + 4);
      float xs[8] = {v0.x, v0.y, v0.z, v0.w, v1.x, v1.y, v1.z, v1.w};
      unsigned int hp[4], lp[4];
      #pragma unroll
      for (int t = 0; t < 4; ++t) {
        unsigned short h0 = f2bf(xs[2*t]);
        unsigned short h1 = f2bf(xs[2*t+1]);
        unsigned short l0 = f2bf(xs[2*t]   - bf2f(h0));
        unsigned short l1 = f2bf(xs[2*t+1] - bf2f(h1));
        hp[t] = (unsigned)h0 | ((unsigned)h1 << 16);
        lp[t] = (unsigned)l0 | ((unsigned)l1 << 16);
      }
      *(uint4*)(&Ahs[r0a*40 + sseg*8]) = make_uint4(hp[0], hp[1], hp[2], hp[3]);
      *(uint4*)(&Als[r0a*40 + sseg*8]) = make_uint4(lp[0], lp[1], lp[2], lp[3]);
      *(uint4*)(&Bhs[r0a*40 + sseg*8]) = *(const uint4*)(WTh + (size_t)r0a*2048 + woff + k0 + sseg*8);
      *(uint4*)(&Bls[r0a*40 + sseg*8]) = *(const uint4*)(WTl + (size_t)r0a*2048 + woff + k0 + sseg*8);
    }
    __syncthreads();
    bf16x8 afh[2], afl[2], bfh[2], bfl[2];
    #pragma unroll
    for (int i = 0; i < 2; ++i) {
      afh[i] = *(const bf16x8*)(&Ahs[(wm + i*16 + fml)*40 + q*8]);
      afl[i] = *(const bf16x8*)(&Als[(wm + i*16 + fml)*40 + q*8]);
    }
    #pragma unroll
    for (int j = 0; j < 2; ++j) {
      bfh[j] = *(const bf16x8*)(&Bhs[(wn + j*16 + fml)*40 + q*8]);
      bfl[j] = *(const bf16x8*)(&Bls[(wn + j*16 + fml)*40 + q*8]);
    }
    #pragma unroll
    for (int i = 0; i < 2; ++i)
      #pragma unroll
      for (int j = 0; j < 2; ++j) {
        acc[i][j] = __builtin_amdgcn_mfma_f32_16x16x32_bf16(afl[i], bfh[j], acc[i][j], 0, 0, 0);
        acc[i][j] = __builtin_amdgcn_mfma_f32_16x16x32_bf16(afh[i], bfl[j], acc[i][j], 0, 0, 0);
        acc[i][j] = __builtin_amdgcn_mfma_f32_16x16x32_bf16(afh[i], bfh[j], acc[i][j], 0, 0, 0);
      }
    __syncthreads();
  }
  #pragma unroll
  for (int j = 0; j < 2; ++j) {
    const int col = wn + j*16 + fml;   // 0..63
    #pragma unroll
    for (int i = 0; i < 2; ++i) {
      #pragma unroll
      for (int r = 0; r < 4; ++r) {
        const int row = bm + wm + i*16 + q*4 + r;
        const size_t idx = (size_t)row*64 + col;
        float a = acc[i][j][r];
        if (accum) {
          float v = out[idx] + a;
          if (bias2) v = v + bias2[col];
          out[idx] = v;
        } else out[idx] = a;
      }
    }
  }
}

// ---------------------------------------------------------------- s2c partial, f32 FMA — fallback tier only
__global__ __launch_bounds__(256) void k_s2c(const float* __restrict__ Sp, int ldS, int KH,
    const float* __restrict__ W, size_t woff, float* __restrict__ out, int accum,
    const float* __restrict__ bias2) {
  __shared__ float As_[16][17];
  __shared__ float Ws_[16][68];
  const int bm = blockIdx.x * 16;
  const int tid = threadIdx.x;
  const int rt = tid >> 4;   // row 0..15
  const int ct = tid & 15;   // col group 0..15
  float acc[4] = {};
  for (int k0 = 0; k0 < KH; k0 += 16) {
    As_[tid >> 4][tid & 15] = Sp[(size_t)(bm + (tid >> 4))*ldS + k0 + (tid & 15)];
    #pragma unroll
    for (int i = 0; i < 4; ++i) {
      int e = tid + i*256;
      Ws_[e >> 6][e & 63] = W[woff + (size_t)(k0 + (e >> 6))*64 + (e & 63)];
    }
    __syncthreads();
    #pragma unroll
    for (int kk = 0; kk < 16; ++kk) {
      float a = As_[rt][kk];
      #pragma unroll
      for (int j = 0; j < 4; ++j) acc[j] += a * Ws_[kk][ct*4+j];
    }
    __syncthreads();
  }
  #pragma unroll
  for (int j = 0; j < 4; ++j) {
    size_t idx = ((size_t)bm + rt)*64 + ct*4 + j;
    float a = acc[j];
    if (accum) {
      float v = out[idx] + a;
      if (bias2) v = v + bias2[ct*4+j]; // bias fold on final pass
      out[idx] = v;
    } else out[idx] = a;
  }
}

// ---------------------------------------------------------------- zero expert counters
__global__ void k_zero(int* p) { if (threadIdx.x < 8) p[threadIdx.x] = 0; }

// ---------------------------------------------------------------- fused router (f32): hidden in LDS, logits, top-2, block-agg append
__global__ __launch_bounds__(256) void k_router2(const float* __restrict__ cont,
    const float* __restrict__ rW1, const float* __restrict__ rb1,
    const float* __restrict__ rW2, const float* __restrict__ rb2,
    const float* __restrict__ gains,
    int* __restrict__ cnt, unsigned int* __restrict__ list, float* __restrict__ lw)
{
  __shared__ float W1s[64*64];
  __shared__ float W2s[64*8];
  __shared__ float b2s[8];
  __shared__ float cs[16][64];
  __shared__ float hs[16][65];
  __shared__ int bcnt[8];
  __shared__ int bbase[8];
  const int tid = threadIdx.x;
  const int j  = tid & 63;
  const int tg = tid >> 6;           // 0..3
  const int n0 = blockIdx.x * 16;
  for (int i = tid; i < 64*64; i += 256) W1s[i] = rW1[i];
  for (int i = tid; i < 64*8; i += 256)  W2s[i] = rW2[i];
  if (tid < 8) { b2s[tid] = rb2[tid]; bcnt[tid] = 0; }
  #pragma unroll
  for (int i = 0; i < 4; ++i) {
    int e = tid + i*256;             // 1024 = 16 tokens x 64
    cs[e >> 6][e & 63] = cont[(size_t)(n0 + (e >> 6))*64 + (e & 63)];
  }
  __syncthreads();
  {
    const float b1 = rb1[j];
    float t0 = b1, t1 = b1, t2 = b1, t3 = b1;
    #pragma unroll
    for (int m = 0; m < 64; ++m) {
      const float w = W1s[m*64 + j];
      t0 += cs[tg*4+0][m] * w;
      t1 += cs[tg*4+1][m] * w;
      t2 += cs[tg*4+2][m] * w;
      t3 += cs[tg*4+3][m] * w;
    }
    hs[tg*4+0][j] = tanhf(t0);
    hs[tg*4+1][j] = tanhf(t1);
    hs[tg*4+2][j] = tanhf(t2);
    hs[tg*4+3][j] = tanhf(t3);
  }
  __syncthreads();
  int i1 = 0, i2 = 0, p1l = 0, p2l = 0;
  float w1 = 0.f;
  if (tid < 16) {
    const int n = n0 + tid;
    float lg[8];
    #pragma unroll
    for (int e = 0; e < 8; ++e) lg[e] = b2s[e];
    #pragma unroll 8
    for (int jj = 0; jj < 64; ++jj) {
      float t = hs[tid][jj];
      #pragma unroll
      for (int e = 0; e < 8; ++e) lg[e] += t * W2s[jj*8 + e];
    }
    float g = gains[n];
    #pragma unroll
    for (int e = 0; e < 8; ++e) lg[e] *= g;
    float m1 = lg[0];
    #pragma unroll
    for (int e = 1; e < 8; ++e) if (lg[e] > m1) { m1 = lg[e]; i1 = e; }
    i2 = (i1 == 0) ? 1 : 0; float m2 = lg[i2];
    #pragma unroll
    for (int e = 0; e < 8; ++e) if (e != i1 && lg[e] > m2) { m2 = lg[e]; i2 = e; }
    w1 = 1.0f / (1.0f + __expf(m2 - m1));
    p1l = atomicAdd(&bcnt[i1], 1);
    p2l = atomicAdd(&bcnt[i2], 1);
  }
  __syncthreads();
  if (tid < 8) bbase[tid] = bcnt[tid] ? atomicAdd(&cnt[tid], bcnt[tid]) : 0;
  __syncthreads();
  if (tid < 16) {
    const int n = n0 + tid;
    const int p1 = bbase[i1] + p1l;
    list[i1*8192 + p1] = ((unsigned)n << 1);
    lw[i1*8192 + p1] = w1;
    const int p2 = bbase[i2] + p2l;
    list[i2*8192 + p2] = ((unsigned)n << 1) | 1u;
    lw[i2*8192 + p2] = 1.0f - w1;
  }
}

// ---------------------------------------------------------------- grouped experts — f32 SIMT (fallback tier only)
__global__ __launch_bounds__(256) void k_expgrp(
    const float* __restrict__ cont,
    const unsigned int* __restrict__ list, const float* __restrict__ lw,
    const int* __restrict__ cnt,
    const float* __restrict__ eW1, const float* __restrict__ eb1,
    const float* __restrict__ eW2, const float* __restrict__ eb2,
    float* __restrict__ eout)
{
  const int e = blockIdx.y;
  const int t0 = blockIdx.x * 64;
  const int ce = cnt[e];
  if (t0 >= ce) return;
  const int nt = (ce - t0 < 64) ? (ce - t0) : 64;
  __shared__ float ct[64][65];
  __shared__ float w1b[64][65];
  __shared__ float hbl[64][65];
  __shared__ float w2b[64][65];
  __shared__ unsigned int sl[64];
  __shared__ float swt[64];
  const int tid = threadIdx.x;
  if (tid < 64) {
    if (tid < nt) {
      sl[tid]  = list[e*8192 + t0 + tid];
      swt[tid] = lw[e*8192 + t0 + tid];
    } else { sl[tid] = 0; swt[tid] = 0.f; }
  }
  __syncthreads();
  for (int f = tid; f < 64*64; f += 256) {
    int r = f >> 6, m = f & 63;
    ct[r][m] = (r < nt) ? cont[(size_t)(sl[r] >> 1)*64 + m] : 0.f;
  }
  const float* W1 = eW1 + (size_t)e*64*1024;
  const float* W2 = eW2 + (size_t)e*1024*64;
  const float* B1 = eb1 + (size_t)e*1024;
  const int rt = tid >> 4, c16 = tid & 15;
  float outa[4][4] = {};
  for (int hc = 0; hc < 1024; hc += 64) {
    __syncthreads();
    for (int f = tid; f < 64*64; f += 256) {
      int m = f >> 6, j = f & 63;
      w1b[m][j] = W1[(size_t)m*1024 + hc + j];
      w2b[m][j] = W2[(size_t)(hc + m)*64 + j];
    }
    __syncthreads();
    float h4[4][4];
    #pragma unroll
    for (int i = 0; i < 4; ++i) {
      #pragma unroll
      for (int j = 0; j < 4; ++j) h4[i][j] = B1[hc + c16*4 + j];
    }
    #pragma unroll 16
    for (int m = 0; m < 64; ++m) {
      float a4[4], b4[4];
      #pragma unroll
      for (int i = 0; i < 4; ++i) a4[i] = ct[rt*4+i][m];
      #pragma unroll
      for (int j = 0; j < 4; ++j) b4[j] = w1b[m][c16*4+j];
      #pragma unroll
      for (int i = 0; i < 4; ++i)
        #pragma unroll
        for (int j = 0; j < 4; ++j) h4[i][j] += a4[i]*b4[j];
    }
    #pragma unroll
    for (int i = 0; i < 4; ++i)
      #pragma unroll
      for (int j = 0; j < 4; ++j)
        hbl[rt*4+i][c16*4+j] = fmaxf(h4[i][j], 0.f);
    __syncthreads();
    #pragma unroll 16
    for (int j = 0; j < 64; ++j) {
      float a4[4], b4[4];
      #pragma unroll
      for (int i = 0; i < 4; ++i) a4[i] = hbl[rt*4+i][j];
      #pragma unroll
      for (int nn = 0; nn < 4; ++nn) b4[nn] = w2b[j][c16*4+nn];
      #pragma unroll
      for (int i = 0; i < 4; ++i)
        #pragma unroll
        for (int nn = 0; nn < 4; ++nn) outa[i][nn] += a4[i]*b4[nn];
    }
  }
  #pragma unroll
  for (int i = 0; i < 4; ++i) {
    int r = rt*4 + i;
    if (r < nt) {
      float w = swt[r];
      #pragma unroll
      for (int nn = 0; nn < 4; ++nn) {
        int col = c16*4 + nn;
        eout[(size_t)sl[r]*64 + col] = w * (outa[i][nn] + eb2[(size_t)e*64 + col]);
      }
    }
  }
}

// ---------------------------------------------------------------- grouped experts — split-bf16 MFMA (e=blockIdx.y, spread all CUs)
__global__ __launch_bounds__(256) void k_expmfma(
    const float* __restrict__ cont,
    const unsigned int* __restrict__ list, const float* __restrict__ lw,
    const int* __restrict__ cnt,
    const unsigned short* __restrict__ w1h, const unsigned short* __restrict__ w1l, // [E][1024][64]
    const float* __restrict__ eb1,                                                  // [E][1024]
    const unsigned short* __restrict__ w2h, const unsigned short* __restrict__ w2l, // [E][64][1024]
    const float* __restrict__ eb2,                                                  // [E][64]
    float* __restrict__ eout)
{
  const int e  = blockIdx.y;
  const int t0 = blockIdx.x * 64;
  const int ce = cnt[e];
  if (t0 >= ce) return;
  const int nt = (ce - t0 < 64) ? (ce - t0) : 64;

  // stride 72 shorts = 144 B = 36 words (36 % 32 = 4): 16-row frag reads are <=2-way.
  __shared__ __align__(16) unsigned short cth[64*72],  ctl[64*72];
  __shared__ __align__(16) unsigned short w1sh[64*72], w1sl[64*72];
  __shared__ __align__(16) unsigned short w2sh[64*72], w2sl[64*72];
  __shared__ __align__(16) unsigned short hsh[64*72],  hsl[64*72];
  __shared__ unsigned int sl[64];
  __shared__ float swt[64];

  const int tid  = threadIdx.x;
  const int lane = tid & 63;
  const int wave = tid >> 6;
  const int wm  = (wave >> 1) * 32;   // token offset of this wave
  const int wn  = (wave & 1) * 32;    // col offset of this wave
  const int fml = lane & 15;
  const int q   = lane >> 4;          // 0..3

  if (tid < 64) {
    if (tid < nt) { sl[tid] = list[e*8192 + t0 + tid]; swt[tid] = lw[e*8192 + t0 + tid]; }
    else          { sl[tid] = 0; swt[tid] = 0.f; }
  }
  __syncthreads();

  // gather cont rows + split to hi/lo bf16 (row = token, 16 f32 per thread)
  {
    const int row = tid >> 2;
    const int m0  = (tid & 3) * 16;
    float x[16] = {0.f,0.f,0.f,0.f,0.f,0.f,0.f,0.f,0.f,0.f,0.f,0.f,0.f,0.f,0.f,0.f};
    if (row < nt) {
      const float* p = cont + (size_t)(sl[row] >> 1)*64 + m0;
      *(float4*)&x[0]  = *(const float4*)(p);
      *(float4*)&x[4]  = *(const float4*)(p + 4);
      *(float4*)&x[8]  = *(const float4*)(p + 8);
      *(float4*)&x[12] = *(const float4*)(p + 12);
    }
    unsigned int hp[8], lp[8];
    #pragma unroll
    for (int t = 0; t < 8; ++t) {
      unsigned short h0 = f2bf(x[2*t]);
      unsigned short h1 = f2bf(x[2*t+1]);
      unsigned short l0 = f2bf(x[2*t]   - bf2f(h0));
      unsigned short l1 = f2bf(x[2*t+1] - bf2f(h1));
      hp[t] = (unsigned)h0 | ((unsigned)h1 << 16);
      lp[t] = (unsigned)l0 | ((unsigned)l1 << 16);
    }
    *(uint4*)&cth[row*72 + m0]     = make_uint4(hp[0], hp[1], hp[2], hp[3]);
    *(uint4*)&cth[row*72 + m0 + 8] = make_uint4(hp[4], hp[5], hp[6], hp[7]);
    *(uint4*)&ctl[row*72 + m0]     = make_uint4(lp[0], lp[1], lp[2], lp[3]);
    *(uint4*)&ctl[row*72 + m0 + 8] = make_uint4(lp[4], lp[5], lp[6], lp[7]);
  }

  f32x4 acc2[2][2] = {};

  for (int hc = 0; hc < 1024; hc += 64) {
    // stage this chunk's weights: w1 rows = h-cols (K=m), w2 rows = out-cols (K=h)
    {
      const int row = tid >> 2;
      const int seg = (tid & 3) * 16;
      const size_t o1 = ((size_t)(e*1024 + hc + row))*64 + seg;
      *(uint4*)&w1sh[row*72 + seg]     = *(const uint4*)(w1h + o1);
      *(uint4*)&w1sh[row*72 + seg + 8] = *(const uint4*)(w1h + o1 + 8);
      *(uint4*)&w1sl[row*72 + seg]     = *(const uint4*)(w1l + o1);
      *(uint4*)&w1sl[row*72 + seg + 8] = *(const uint4*)(w1l + o1 + 8);
      const size_t o2 = ((size_t)(e*64 + row))*1024 + hc + seg;
      *(uint4*)&w2sh[row*72 + seg]     = *(const uint4*)(w2h + o2);
      *(uint4*)&w2sh[row*72 + seg + 8] = *(const uint4*)(w2h + o2 + 8);
      *(uint4*)&w2sl[row*72 + seg]     = *(const uint4*)(w2l + o2);
      *(uint4*)&w2sl[row*72 + seg + 8] = *(const uint4*)(w2l + o2 + 8);
    }
    __syncthreads();

    // GEMM1: h[t][col] = sum_m ct[t][m] * w1[col][m], K=64
    f32x4 acc1[2][2] = {};
    #pragma unroll
    for (int ks = 0; ks < 2; ++ks) {
      bf16x8 ah[2], al[2], bh[2], bl[2];
      #pragma unroll
      for (int i = 0; i < 2; ++i) {
        ah[i] = *(const bf16x8*)&cth[(wm + i*16 + fml)*72 + ks*32 + q*8];
        al[i] = *(const bf16x8*)&ctl[(wm + i*16 + fml)*72 + ks*32 + q*8];
      }
      #pragma unroll
      for (int j = 0; j < 2; ++j) {
        bh[j] = *(const bf16x8*)&w1sh[(wn + j*16 + fml)*72 + ks*32 + q*8];
        bl[j] = *(const bf16x8*)&w1sl[(wn + j*16 + fml)*72 + ks*32 + q*8];
      }
      #pragma unroll
      for (int i = 0; i < 2; ++i)
        #pragma unroll
        for (int j = 0; j < 2; ++j) {
          acc1[i][j] = __builtin_amdgcn_mfma_f32_16x16x32_bf16(al[i], bh[j], acc1[i][j], 0, 0, 0);
          acc1[i][j] = __builtin_amdgcn_mfma_f32_16x16x32_bf16(ah[i], bl[j], acc1[i][j], 0, 0, 0);
          acc1[i][j] = __builtin_amdgcn_mfma_f32_16x16x32_bf16(ah[i], bh[j], acc1[i][j], 0, 0, 0);
        }
    }

    // bias + relu + split to hi/lo, write h to LDS (C/D: col=lane&15, row=q*4+r)
    #pragma unroll
    for (int j = 0; j < 2; ++j) {
      const int col = wn + j*16 + fml;
      const float b1 = eb1[(size_t)e*1024 + hc + col];
      #pragma unroll
      for (int i = 0; i < 2; ++i) {
        #pragma unroll
        for (int r = 0; r < 4; ++r) {
          const int trow = wm + i*16 + q*4 + r;
          float v = fmaxf(acc1[i][j][r] + b1, 0.f);
          unsigned short hh = f2bf(v);
          hsh[trow*72 + col] = hh;
          hsl[trow*72 + col] = f2bf(v - bf2f(hh));
        }
      }
    }
    __syncthreads();

    // GEMM2: out[t][n] += sum_h hs[t][h] * w2[n][h], K=64
    #pragma unroll
    for (int ks = 0; ks < 2; ++ks) {
      bf16x8 ah[2], al[2], bh[2], bl[2];
      #pragma unroll
      for (int i = 0; i < 2; ++i) {
        ah[i] = *(const bf16x8*)&hsh[(wm + i*16 + fml)*72 + ks*32 + q*8];
        al[i] = *(const bf16x8*)&hsl[(wm + i*16 + fml)*72 + ks*32 + q*8];
      }
      #pragma unroll
      for (int j = 0; j < 2; ++j) {
        bh[j] = *(const bf16x8*)&w2sh[(wn + j*16 + fml)*72 + ks*32 + q*8];
        bl[j] = *(const bf16x8*)&w2sl[(wn + j*16 + fml)*72 + ks*32 + q*8];
      }
      #pragma unroll
      for (int i = 0; i < 2; ++i)
        #pragma unroll
        for (int j = 0; j < 2; ++j) {
          acc2[i][j] = __builtin_amdgcn_mfma_f32_16x16x32_bf16(al[i], bh[j], acc2[i][j], 0, 0, 0);
          acc2[i][j] = __builtin_amdgcn_mfma_f32_16x16x32_bf16(ah[i], bl[j], acc2[i][j], 0, 0, 0);
          acc2[i][j] = __builtin_amdgcn_mfma_f32_16x16x32_bf16(ah[i], bh[j], acc2[i][j], 0, 0, 0);
        }
    }
    __syncthreads();   // before next chunk overwrites w1s/w2s/hs
  }

  // epilogue: eout[slot][n] = w * (acc + b2)
  #pragma unroll
  for (int j = 0; j < 2; ++j) {
    const int col = wn + j*16 + fml;
    const float b2 = eb2[(size_t)e*64 + col];
    #pragma unroll
    for (int i = 0; i < 2; ++i) {
      #pragma unroll
      for (int r = 0; r < 4; ++r) {
        const int trow = wm + i*16 + q*4 + r;
        if (trow < nt)
          eout[(size_t)sl[trow]*64 + col] = swt[trow]*(acc2[i][j][r] + b2);
      }
    }
  }
}

// ---------------------------------------------------------------- c2s MFMA GEMM, split-bf16 (3 products)
__global__ __launch_bounds__(256) void k_c2sM(
    const float* __restrict__ eoutTok,        // [T][128]
    const unsigned short* __restrict__ WTh,   // [2048][64] bf16 hi
    const unsigned short* __restrict__ WTl,   // [2048][64] bf16 lo
    const float* __restrict__ bias,           // [2048]
    unsigned short* __restrict__ rates)       // [T][2048]
{
  __shared__ __align__(16) unsigned short Ahs[128*72], Als[128*72];
  __shared__ __align__(16) unsigned short Bhs[128*72], Bls[128*72];
  const int tid  = threadIdx.x;
  const int lane = tid & 63;
  const int wave = tid >> 6;
  const int wm = (wave >> 1) * 64;
  const int wn = (wave & 1) * 64;
  const int bm = blockIdx.y * 128;
  const int bn = blockIdx.x * 128;
  const int fml = lane & 15;
  const int q  = lane >> 4;

  {
    const int row = tid >> 1;          // 0..127
    const int m0  = (tid & 1) * 32;    // 0 or 32
    const float* p = eoutTok + (size_t)(bm + row)*128 + m0;
    float x[32];
    #pragma unroll
    for (int i = 0; i < 8; ++i) {
      float4 a = *(const float4*)(p + i*4);
      float4 b = *(const float4*)(p + 64 + i*4);
      x[i*4+0] = a.x + b.x; x[i*4+1] = a.y + b.y;
      x[i*4+2] = a.z + b.z; x[i*4+3] = a.w + b.w;
    }
    unsigned int hp[16], lp[16];
    #pragma unroll
    for (int t = 0; t < 16; ++t) {
      unsigned short h0 = f2bf(x[2*t]);
      unsigned short h1 = f2bf(x[2*t+1]);
      unsigned short l0 = f2bf(x[2*t]   - bf2f(h0));
      unsigned short l1 = f2bf(x[2*t+1] - bf2f(h1));
      hp[t] = (unsigned)h0 | ((unsigned)h1 << 16);
      lp[t] = (unsigned)l0 | ((unsigned)l1 << 16);
    }
    #pragma unroll
    for (int t = 0; t < 4; ++t) {
      *(uint4*)&Ahs[row*72 + m0 + t*8] = make_uint4(hp[t*4+0],hp[t*4+1],hp[t*4+2],hp[t*4+3]);
      *(uint4*)&Als[row*72 + m0 + t*8] = make_uint4(lp[t*4+0],lp[t*4+1],lp[t*4+2],lp[t*4+3]);
    }
    const unsigned short* ph = WTh + (size_t)(bn + row)*64 + m0;
    const unsigned short* pl = WTl + (size_t)(bn + row)*64 + m0;
    #pragma unroll
    for (int t = 0; t < 4; ++t) {
      *(uint4*)&Bhs[row*72 + m0 + t*8] = *(const uint4*)(ph + t*8);
      *(uint4*)&Bls[row*72 + m0 + t*8] = *(const uint4*)(pl + t*8);
    }
  }
  __syncthreads();

  f32x4 acc[4][4] = {};
  #pragma unroll
  for (int ks = 0; ks < 2; ++ks) {
    bf16x8 ah[4], al[4], bh[4], bl[4];
    #pragma unroll
    for (int i = 0; i < 4; ++i) {
      ah[i] = *(const bf16x8*)&Ahs[(wm + i*16 + fml)*72 + ks*32 + q*8];
      al[i] = *(const bf16x8*)&Als[(wm + i*16 + fml)*72 + ks*32 + q*8];
    }
    #pragma unroll
    for (int j = 0; j < 4; ++j) {
      bh[j] = *(const bf16x8*)&Bhs[(wn + j*16 + fml)*72 + ks*32 + q*8];
      bl[j] = *(const bf16x8*)&Bls[(wn + j*16 + fml)*72 + ks*32 + q*8];
    }
    #pragma unroll
    for (int i = 0; i < 4; ++i)
      #pragma unroll
      for (int j = 0; j < 4; ++j) {
        acc[i][j] = __builtin_amdgcn_mfma_f32_16x16x32_bf16(al[i], bh[j], acc[i][j], 0, 0, 0);
        acc[i][j] = __builtin_amdgcn_mfma_f32_16x16x32_bf16(ah[i], bl[j], acc[i][j], 0, 0, 0);
        acc[i][j] = __builtin_amdgcn_mfma_f32_16x16x32_bf16(ah[i], bh[j], acc[i][j], 0, 0, 0);
      }
  }

  #pragma unroll
  for (int j = 0; j < 4; ++j) {
    const int col = bn + wn + j*16 + fml;
    const float bv = bias[col];
    #pragma unroll
    for (int i = 0; i < 4; ++i) {
      #pragma unroll
      for (int r = 0; r < 4; ++r) {
        const int row = bm + wm + i*16 + q*4 + r;
        rates[(size_t)row*H_ + col] = f2bf(sigf(acc[i][j][r] + bv));
      }
    }
  }
}

// ---------------------------------------------------------------- c2s 256-col slice -> f32 (fallback path)
__global__ __launch_bounds__(256) void k_c2sS(const float* __restrict__ eoutTok,
    const float* __restrict__ W, int coff,
    const float* __restrict__ bias, float* __restrict__ rat)
{
  __shared__ float ml[8][64];
  const int tid = threadIdx.x;
  const int n0 = blockIdx.x * 8;
  for (int i = tid; i < 512; i += 256) {
    int t = i >> 6, m = i & 63;
    ml[t][m] = eoutTok[(size_t)(n0+t)*128 + m] + eoutTok[(size_t)(n0+t)*128 + 64 + m];
  }
  __syncthreads();
  float acc[8] = {};
  for (int m = 0; m < 64; ++m) {
    float wv = W[(size_t)m*H_ + coff + tid];
    #pragma unroll
    for (int t = 0; t < 8; ++t) acc[t] += ml[t][m] * wv;
  }
  float bv = bias[coff + tid];
  #pragma unroll
  for (int t = 0; t < 8; ++t)
    rat[(size_t)(n0+t)*256 + tid] = sigf(acc[t] + bv);
}

// ---------------------------------------------------------------- f32 -> bf16 transpose (dec_W [R][C] -> out [C][R])
__global__ __launch_bounds__(256) void k_transb(const float* __restrict__ in,
    unsigned short* __restrict__ out, int R, int C) {
  __shared__ unsigned short t[32][33];
  int c0 = blockIdx.x*32, r0 = blockIdx.y*32;
  int tx = threadIdx.x & 31, ty = threadIdx.x >> 5;
  #pragma unroll
  for (int i = 0; i < 32; i += 8)
    t[ty+i][tx] = f2bf(in[(size_t)(r0+ty+i)*C + (c0+tx)]);
  __syncthreads();
  #pragma unroll
  for (int i = 0; i < 32; i += 8)
    out[(size_t)(c0+ty+i)*R + (r0+tx)] = t[tx][ty+i];
}

// ---------------------------------------------------------------- dec MFMA GEMM + XCD bijective swizzle
__global__ __launch_bounds__(256) void k_dgemm(
    const unsigned short* __restrict__ A,
    const unsigned short* __restrict__ BT,
    const float* __restrict__ bias,
    const float* __restrict__ gains,
    float* __restrict__ C)
{
  __shared__ __align__(16) unsigned short As[128*40];
  __shared__ __align__(16) unsigned short Bs[128*40];
  const int tid  = threadIdx.x;
  const int lane = tid & 63;
  const int wave = tid >> 6;
  const int wm = (wave >> 1) * 64;
  const int wn = (wave & 1) * 64;
  // XCD-aware bijective swizzle: nwg = 8*gy (%8==0)
  const int gy   = gridDim.y;
  const int flat = blockIdx.y * 8 + blockIdx.x;
  const int swz  = (flat & 7) * gy + (flat >> 3);
  const int bn = (swz & 7) * 128;
  const int bm = (swz >> 3) * 128;
  const int fml = lane & 15;
  const int q  = lane >> 4;
  const int r0a  = tid >> 2;
  const int sseg = tid & 3;

  f32x4 acc[4][4] = {};

  for (int k0 = 0; k0 < H_; k0 += 32) {
    #pragma unroll
    for (int half = 0; half < 2; ++half) {
      int r = r0a + half*64;
      *(uint4*)(&As[r*40 + sseg*8]) = *(const uint4*)(A + (size_t)(bm + r)*H_ + k0 + sseg*8);
      *(uint4*)(&Bs[r*40 + sseg*8]) = *(const uint4*)(BT + (size_t)(bn + r)*H_ + k0 + sseg*8);
    }
    __syncthreads();
    bf16x8 af[4], bfr[4];
    #pragma unroll
    for (int i = 0; i < 4; ++i)
      af[i] = *(const bf16x8*)(&As[(wm + i*16 + fml)*40 + q*8]);
    #pragma unroll
    for (int j = 0; j < 4; ++j)
      bfr[j] = *(const bf16x8*)(&Bs[(wn + j*16 + fml)*40 + q*8]);
    #pragma unroll
    for (int i = 0; i < 4; ++i)
      #pragma unroll
      for (int j = 0; j < 4; ++j)
        acc[i][j] = __builtin_amdgcn_mfma_f32_16x16x32_bf16(af[i], bfr[j], acc[i][j], 0, 0, 0);
    __syncthreads();
  }
  #pragma unroll
  for (int i = 0; i < 4; ++i) {
    #pragma unroll
    for (int j = 0; j < 4; ++j) {
      int col = bn + wn + j*16 + fml;
      float bv = bias[col];
      #pragma unroll
      for (int r = 0; r < 4; ++r) {
        int row = bm + wm + i*16 + q*4 + r;
        C[(size_t)row*D_ + col] = gains[row]*acc[i][j][r] + bv;
      }
    }
  }
}

// ---------------------------------------------------------------- layernorm D=1024 in-place
__global__ __launch_bounds__(256) void k_ln(float* __restrict__ X,
    const float* __restrict__ g, const float* __restrict__ b)
{
  const int n = blockIdx.x, tid = threadIdx.x;
  float4* row = (float4*)(X + (size_t)n*D_);
  const float4 xv = row[tid];
  float xa[4] = {xv.x, xv.y, xv.z, xv.w};
  float s = xa[0]+xa[1]+xa[2]+xa[3];
  float ss = xa[0]*xa[0]+xa[1]*xa[1]+xa[2]*xa[2]+xa[3]*xa[3];
  #pragma unroll
  for (int off = 32; off >= 1; off >>= 1) {
    s  += __shfl_down(s, off);
    ss += __shfl_down(ss, off);
  }
  __shared__ float rs[4], rss[4];
  const int lane = tid & 63, wv = tid >> 6;
  if (lane == 0) { rs[wv] = s; rss[wv] = ss; }
  __syncthreads();
  float S0 = rs[0]+rs[1]+rs[2]+rs[3];
  float SS = rss[0]+rss[1]+rss[2]+rss[3];
  float mu = S0 * (1.f/(float)D_);
  float var = SS * (1.f/(float)D_) - mu*mu;
  float inv = rsqrtf(var + 1e-5f);
  int idx = tid*4;
  float4 o;
  o.x = (xa[0]-mu)*inv*g[idx+0] + b[idx+0];
  o.y = (xa[1]-mu)*inv*g[idx+1] + b[idx+1];
  o.z = (xa[2]-mu)*inv*g[idx+2] + b[idx+2];
  o.w = (xa[3]-mu)*inv*g[idx+3] + b[idx+3];
  row[tid] = o;
}

// ----------------------------------------------------------------
// ws layout:
//   [0x000000,0x200000) cont f32[8192][64]
//   [0x200000,0x300000) c2s_WT hi/lo bf16 [2048][64] (path A only)
//   [0x300000,0x380000) s2c_WT hi/lo bf16 [64][2048] (encM only)
//   [0x400000,0x800000) eout f32[16384][64]
//   0x800000 gains | 0x808000 cnt | 0x809000 list | 0x849000 lw
//   [0x890000,0x8D0000) vinitF float[16*4096] (enc GIF CS=128 + dec GIF)
//   0x900000 (4 MiB): WhT (enc) -> expert weights w1th/w1tl/w2th/w2tl -> decWT (dec)
//   0xD00000 (4 MiB): WlT (enc)  -> rates (dec path A, T*4 KiB from 0xD00000)
//   [0x1100000,0x3100000) encAh/encAl bf16 [8192][1024] each (enc pre-split, needs ws>=50 MiB)
// Enc scratch cur f32[8192][1024] = 32 MiB per H-chunk lives in d_out.
extern "C" void kernel_launch(void* const* d_in, const int* in_sizes, int n_in,
                              void* d_out, int out_size, void* d_ws, size_t ws_size,
                              hipStream_t stream) {
  (void)in_sizes; (void)n_in; (void)out_size;
  const float* embeds = (const float*)d_in[0];
  const int*   ids    = (const int*)d_in[1];
  const float* pros   = (const float*)d_in[2];
  const float* enc_W  = (const float*)d_in[3];
  const float* enc_b  = (const float*)d_in[4];
  const float* s2c_W  = (const float*)d_in[5];
  const float* s2c_b  = (const float*)d_in[6];
  const float* r_W1   = (const float*)d_in[7];
  const float* r_b1   = (const float*)d_in[8];
  const float* r_W2   = (const float*)d_in[9];
  const float* r_b2   = (const float*)d_in[10];
  const float* e_W1   = (const float*)d_in[11];
  const float* e_b1   = (const float*)d_in[12];
  const float* e_W2   = (const float*)d_in[13];
  const float* e_b2   = (const float*)d_in[14];
  const float* c2s_W  = (const float*)d_in[15];
  const float* c2s_b  = (const float*)d_in[16];
  const float* dec_W  = (const float*)d_in[17];
  const float* dec_b  = (const float*)d_in[18];
  const float* ln_g   = (const float*)d_in[19];
  const float* ln_b   = (const float*)d_in[20];

  char* ws = (char*)d_ws;
  float*          contp = (float*)ws;
  unsigned short* c2sWTh= (unsigned short*)(ws + (size_t)0x200000); // 256 KiB
  unsigned short* c2sWTl= (unsigned short*)(ws + (size_t)0x280000); // 256 KiB
  unsigned short* s2cWTh= (unsigned short*)(ws + (size_t)0x300000); // 256 KiB
  unsigned short* s2cWTl= (unsigned short*)(ws + (size_t)0x340000); // 256 KiB
  float*          eout  = (float*)(ws + (size_t)0x400000);
  float*          gains = (float*)(ws + (size_t)0x800000);
  int*            cnt   = (int*)(ws + (size_t)0x808000);
  unsigned int*   list  = (unsigned int*)(ws + (size_t)0x809000);
  float*          lw    = (float*)(ws + (size_t)0x849000);
  float*          vinitF= (float*)(ws + (size_t)0x890000);          // GIF f32 (256 KiB)
  unsigned short* WhT   = (unsigned short*)(ws + (size_t)0x900000); // -> expert w / decWT
  unsigned short* WlT   = (unsigned short*)(ws + (size_t)0xD00000); // -> rates
  unsigned short* encAh = (unsigned short*)(ws + (size_t)0x1100000); // 16 MiB (enc only)
  unsigned short* encAl = (unsigned short*)(ws + (size_t)0x2100000); // 16 MiB (enc only)
  unsigned short* decWT = WhT;
  unsigned short* rates = WlT;
  float*          ratSf = (float*)ws;              // fallback overlay of cont
  float*          cur   = (float*)d_out;           // enc scratch [8192][1024]

  // expert split-bf16 weights live in the WhT window between enc GEMM and k_transb
  unsigned short* w1th = WhT;                         // [8][1024][64] 1 MiB
  unsigned short* w1tl = w1th + (size_t)8*1024*64;    // 1 MiB
  unsigned short* w2th = w1tl + (size_t)8*1024*64;    // [8][64][1024] 1 MiB
  unsigned short* w2tl = w2th + (size_t)8*1024*64;    // 1 MiB (ends at 0xD00000)

  const int encM  = (ws_size >= (size_t)18*1024*1024) ? 1 : 0;
  const int encPA = (encM && ws_size >= (size_t)50*1024*1024) ? 1 : 0;
  const int T = (ws_size >= (size_t)46*1024*1024) ? 8192
              : (ws_size >= (size_t)30*1024*1024) ? 4096 : 0;

  k_gains<<<N_TOK/256, 256, 0, stream>>>(ids, pros, gains);
  k_zero<<<1, 64, 0, stream>>>(cnt);

  // ---- encoder: 2 H-chunks of 1024; GIF f32 at CS=128; MFMA s2c ----
  if (encM) {
    k_splitT<<<dim3(64, 32), 256, 0, stream>>>(enc_W, WhT, WlT);
    k_tsplit<<<dim3(2, 64, 1), 256, 0, stream>>>(s2c_W, s2cWTh, s2cWTl, 2048, 64);
    if (encPA)
      k_asplit<<<4096, 256, 0, stream>>>(embeds, encAh, encAl);
    for (int c = 0; c < 2; ++c) {
      if (encPA) {
        k_egemm3<<<dim3(8, 64), 256, 0, stream>>>(
            encAh, encAl, WhT + (size_t)c*1024*1024, WlT + (size_t)c*1024*1024,
            enc_b + c*1024, gains, cur);
      } else {
        k_egemm<<<dim3(8, 64), 256, 0, stream>>>(
            embeds, WhT + (size_t)c*1024*1024, WlT + (size_t)c*1024*1024,
            enc_b + c*1024, gains, cur);
      }
      k_gif_warm32<<<dim3(16, 16), 256, 0, stream>>>(cur, vinitF, 1024, 128, S_);
      k_gif_emit32<<<dim3(16, 16), 256, 0, stream>>>(cur, vinitF, 1024, 128, S_);
      k_s2cM<<<N_TOK/64, 256, 0, stream>>>(cur, s2cWTh, s2cWTl, (size_t)c*1024,
          contp, (c > 0), (c == 1) ? s2c_b : (const float*)nullptr);
    }
    // enc done reading WhT/WlT -> build expert split-bf16 weights in that window
    k_tsplit<<<dim3(32, 2, 8), 256, 0, stream>>>(e_W1, w1th, w1tl, 64, 1024);
    k_tsplit<<<dim3(2, 32, 8), 256, 0, stream>>>(e_W2, w2th, w2tl, 1024, 64);
  } else {
    for (int c = 0; c < 2; ++c) {
      k_genc<<<dim3(8, 64), 256, 0, stream>>>(
          embeds, D_, enc_W, H_, c*1024, enc_b, gains, cur, 1024, D_, 3);
      k_gif_warm32<<<dim3(16, 16), 256, 0, stream>>>(cur, vinitF, 1024, 128, S_);
      k_gif_emit32<<<dim3(16, 16), 256, 0, stream>>>(cur, vinitF, 1024, 128, S_);
      k_s2c<<<N_TOK/16, 256, 0, stream>>>(cur, 1024, 1024,
          s2c_W, (size_t)c*1024*64, contp, (c > 0),
          (c == 1) ? s2c_b : (const float*)nullptr);
    }
  }

  // ---- router: fused hidden + top-2 (f32) ----
  k_router2<<<N_TOK/16, 256, 0, stream>>>(contp, r_W1, r_b1, r_W2, r_b2,
                                          gains, cnt, list, lw);

  if (encM) {
    k_expmfma<<<dim3(128, 8), 256, 0, stream>>>(contp, list, lw, cnt,
        w1th, w1tl, e_b1, w2th, w2tl, e_b2, eout);
  } else {
    k_expgrp<<<dim3(128, 8), 256, 0, stream>>>(contp, list, lw, cnt,
        e_W1, e_b1, e_W2, e_b2, eout);
  }

  if (T > 0) {
    // ---- decoder path A: bf16 MFMA; GIF f32 ----
    k_transb<<<dim3(32, 64), 256, 0, stream>>>(dec_W, decWT, H_, D_);
    k_tsplit<<<dim3(64, 2, 1), 256, 0, stream>>>(c2s_W, c2sWTh, c2sWTl, 64, H_);
    for (int tok0 = 0; tok0 < N_TOK; tok0 += T) {
      k_c2sM<<<dim3(H_/128, T/128), 256, 0, stream>>>(eout + (size_t)tok0*128,
          c2sWTh, c2sWTl, c2s_b, rates);
      float* cur2 = (float*)d_out + (size_t)tok0*D_;
      k_dgemm<<<dim3(D_/128, T/128), 256, 0, stream>>>(
          rates, decWT, dec_b, gains + tok0, cur2);
      int channels = (T/2048)*1024;
      k_gif_warm32<<<dim3(channels/256, 8), 256, 0, stream>>>(cur2, vinitF, D_, 256, S_);
      k_gif_emit32<<<dim3(channels/256, 8), 256, 0, stream>>>(cur2, vinitF, D_, 256, S_);
      k_ln<<<T, 256, 0, stream>>>(cur2, ln_g, ln_b);
    }
  } else {
    // ---- decoder fallback: f32 SIMT, 2 halves x 8 K-slices ----
    for (int hb = 0; hb < 2; ++hb) {
      float* cur2 = (float*)d_out + (size_t)hb*4096*D_;
      for (int kh = 0; kh < 8; ++kh) {
        k_c2sS<<<4096/8, 256, 0, stream>>>(eout + (size_t)hb*4096*128,
            c2s_W, kh*256, c2s_b, ratSf);
        int mode = (kh == 0) ? 0 : ((kh < 7) ? 1 : 2);
        k_genc<<<dim3(8, 32), 256, 0, stream>>>(
            ratSf, 256, dec_W + (size_t)kh*256*D_, D_, 0, dec_b,
            gains + hb*4096, cur2, D_, 256, mode);
      }
      k_gif_warm32<<<dim3(8, 8), 256, 0, stream>>>(cur2, vinitF, D_, 256, S_);
      k_gif_emit32<<<dim3(8, 8), 256, 0, stream>>>(cur2, vinitF, D_, 256, S_);
      k_ln<<<4096, 256, 0, stream>>>(cur2, ln_g, ln_b);
    }
  }
}

// Round 14
// 574.813 us; speedup vs baseline: 1.1781x; 1.0473x over previous
//
#include <hip/hip_runtime.h>
#include <math.h>

#define B_ 4
#define S_ 2048
#define D_ 1024
#define H_ 2048
#define N_TOK 8192
#define HALO 160
#define VOCAB_ 32000

typedef short bf16x8 __attribute__((ext_vector_type(8)));
typedef float f32x4 __attribute__((ext_vector_type(4)));

__device__ __forceinline__ float sigf(float x) {
  return 1.0f / (1.0f + __expf(-x));
}
__device__ __forceinline__ float bf2f(unsigned short u) {
  union { unsigned int i; float f; } x; x.i = ((unsigned int)u) << 16; return x.f;
}
__device__ __forceinline__ unsigned short f2bf(float f) {
  union { float f; unsigned int i; } x; x.f = f;
  unsigned int r = x.i + 0x7fffu + ((x.i >> 16) & 1u);
  return (unsigned short)(r >> 16);
}

// ---------------------------------------------------------------- gains (f32 tanh)
__global__ __launch_bounds__(256) void k_gains(const int* __restrict__ ids,
    const float* __restrict__ table, float* __restrict__ gains) {
  int i = blockIdx.x*256 + threadIdx.x;
  int id = ids[i];
  id = id < 0 ? 0 : (id >= VOCAB_ ? VOCAB_-1 : id);
  gains[i] = 1.0f + tanhf(table[id]);
}

// ---------------------------------------------------------------- f32 SIMT GEMM (fallback enc/dec)
__global__ __launch_bounds__(256) void k_genc(
    const float* __restrict__ A, int lda,
    const float* __restrict__ W, int ldw, int c0,
    const float* __restrict__ bias,
    const float* __restrict__ gains,
    float* __restrict__ C, int ldc,
    int K, int mode)
{
  __shared__ float As2[16][132];
  __shared__ float Bs[16][128];
  const int tid = threadIdx.x;
  const int tx = tid & 15;
  const int ty = tid >> 4;
  const int bm = blockIdx.y * 128;
  const int bn = blockIdx.x * 128;

  double acc[8][8];
  float part[8][8];
  #pragma unroll
  for (int i = 0; i < 8; ++i)
    #pragma unroll
    for (int j = 0; j < 8; ++j) { acc[i][j] = 0.0; part[i][j] = 0.f; }

  const int e = tid * 8;
  const int ar = e >> 4, ak = e & 15;
  const int bk = e >> 7, bc = e & 127;

  for (int k0 = 0; k0 < K; k0 += 16) {
    {
      const float* pa = A + (size_t)(bm + ar)*lda + k0 + ak;
      float4 v0 = *(const float4*)pa;
      float4 v1 = *(const float4*)(pa + 4);
      As2[ak+0][ar] = v0.x; As2[ak+1][ar] = v0.y;
      As2[ak+2][ar] = v0.z; As2[ak+3][ar] = v0.w;
      As2[ak+4][ar] = v1.x; As2[ak+5][ar] = v1.y;
      As2[ak+6][ar] = v1.z; As2[ak+7][ar] = v1.w;
    }
    {
      const float* pw = W + (size_t)(k0 + bk)*ldw + c0 + bn + bc;
      *(float4*)&Bs[bk][bc]   = *(const float4*)pw;
      *(float4*)&Bs[bk][bc+4] = *(const float4*)(pw + 4);
    }
    __syncthreads();
    #pragma unroll
    for (int kk = 0; kk < 16; ++kk) {
      float a8[8], b8[8];
      *(float4*)&a8[0] = *(const float4*)&As2[kk][ty*8];
      *(float4*)&a8[4] = *(const float4*)&As2[kk][ty*8+4];
      *(float4*)&b8[0] = *(const float4*)&Bs[kk][tx*8];
      *(float4*)&b8[4] = *(const float4*)&Bs[kk][tx*8+4];
      #pragma unroll
      for (int i = 0; i < 8; ++i)
        #pragma unroll
        for (int j = 0; j < 8; ++j)
          part[i][j] += a8[i]*b8[j];
    }
    __syncthreads();
    #pragma unroll
    for (int i = 0; i < 8; ++i)
      #pragma unroll
      for (int j = 0; j < 8; ++j) { acc[i][j] += (double)part[i][j]; part[i][j] = 0.f; }
  }

  #pragma unroll
  for (int i = 0; i < 8; ++i) {
    const int row = bm + ty*8 + i;
    const double g = (mode >= 2) ? (double)gains[row] : 0.0;
    #pragma unroll
    for (int j = 0; j < 8; ++j) {
      const int col = bn + tx*8 + j;
      const size_t idx = (size_t)row*ldc + col;
      if (mode == 0)      C[idx] = (float)acc[i][j];
      else if (mode == 1) C[idx] += (float)acc[i][j];
      else if (mode == 2) C[idx] = (float)(g*((double)C[idx] + acc[i][j]) + (double)bias[c0+col]);
      else                C[idx] = (float)(g*acc[i][j] + (double)bias[c0+col]);
    }
  }
}

// ---------------------------------------------------------------- transpose+split enc_W [1024][2048] f32 -> WhT/WlT [2048][1024] bf16
__global__ __launch_bounds__(256) void k_splitT(const float* __restrict__ in,
    unsigned short* __restrict__ outh, unsigned short* __restrict__ outl) {
  __shared__ unsigned short th[32][33];
  __shared__ unsigned short tl[32][33];
  int c0 = blockIdx.x*32, r0 = blockIdx.y*32;
  int tx = threadIdx.x & 31, ty = threadIdx.x >> 5;
  #pragma unroll
  for (int i = 0; i < 32; i += 8) {
    float x = in[(size_t)(r0+ty+i)*H_ + (c0+tx)];
    unsigned short h = f2bf(x);
    th[ty+i][tx] = h;
    tl[ty+i][tx] = f2bf(x - bf2f(h));
  }
  __syncthreads();
  #pragma unroll
  for (int i = 0; i < 32; i += 8) {
    outh[(size_t)(c0+ty+i)*D_ + (r0+tx)] = th[tx][ty+i];
    outl[(size_t)(c0+ty+i)*D_ + (r0+tx)] = tl[tx][ty+i];
  }
}

// ---------------------------------------------------------------- generic batched transpose+split: in [Z][R][C] f32 -> oh/ol [Z][C][R] bf16
__global__ __launch_bounds__(256) void k_tsplit(const float* __restrict__ in,
    unsigned short* __restrict__ oh, unsigned short* __restrict__ ol,
    int R, int C) {
  __shared__ unsigned short th[32][33];
  __shared__ unsigned short tl[32][33];
  const size_t mat = (size_t)R*C;
  in += (size_t)blockIdx.z * mat;
  oh += (size_t)blockIdx.z * mat;
  ol += (size_t)blockIdx.z * mat;
  int c0 = blockIdx.x*32, r0 = blockIdx.y*32;
  int tx = threadIdx.x & 31, ty = threadIdx.x >> 5;
  #pragma unroll
  for (int i = 0; i < 32; i += 8) {
    float x = in[(size_t)(r0+ty+i)*C + (c0+tx)];
    unsigned short h = f2bf(x);
    th[ty+i][tx] = h;
    tl[ty+i][tx] = f2bf(x - bf2f(h));
  }
  __syncthreads();
  #pragma unroll
  for (int i = 0; i < 32; i += 8) {
    oh[(size_t)(c0+ty+i)*R + (r0+tx)] = th[tx][ty+i];
    ol[(size_t)(c0+ty+i)*R + (r0+tx)] = tl[tx][ty+i];
  }
}

// ---------------------------------------------------------------- row-major f32 -> bf16 hi/lo split (no transpose), 8 elems/thread
__global__ __launch_bounds__(256) void k_asplit(const float* __restrict__ in,
    unsigned short* __restrict__ oh, unsigned short* __restrict__ ol) {
  const size_t i = ((size_t)blockIdx.x*256 + threadIdx.x) * 8;
  float4 v0 = *(const float4*)(in + i);
  float4 v1 = *(const float4*)(in + i + 4);
  float xs[8] = {v0.x, v0.y, v0.z, v0.w, v1.x, v1.y, v1.z, v1.w};
  unsigned int hp[4], lp[4];
  #pragma unroll
  for (int t = 0; t < 4; ++t) {
    unsigned short h0 = f2bf(xs[2*t]);
    unsigned short h1 = f2bf(xs[2*t+1]);
    unsigned short l0 = f2bf(xs[2*t]   - bf2f(h0));
    unsigned short l1 = f2bf(xs[2*t+1] - bf2f(h1));
    hp[t] = (unsigned)h0 | ((unsigned)h1 << 16);
    lp[t] = (unsigned)l0 | ((unsigned)l1 << 16);
  }
  *(uint4*)(oh + i) = make_uint4(hp[0], hp[1], hp[2], hp[3]);
  *(uint4*)(ol + i) = make_uint4(lp[0], lp[1], lp[2], lp[3]);
}

// ---------------------------------------------------------------- enc MFMA GEMM (legacy, in-kernel A split) — fallback tier
__global__ __launch_bounds__(256) void k_egemm(
    const float* __restrict__ A,              // embeds f32 [8192][1024]
    const unsigned short* __restrict__ Bh,    // WhT + chunk offset, [1024][1024] bf16
    const unsigned short* __restrict__ Bl,
    const float* __restrict__ bias,           // enc_b + chunk offset
    const float* __restrict__ gains,
    float* __restrict__ C)                    // cur [8192][1024]
{
  __shared__ __align__(16) unsigned short Ahs[128*40];
  __shared__ __align__(16) unsigned short Als[128*40];
  __shared__ __align__(16) unsigned short Bhs[128*40];
  __shared__ __align__(16) unsigned short Bls[128*40];
  const int tid  = threadIdx.x;
  const int lane = tid & 63;
  const int wave = tid >> 6;
  const int wm = (wave >> 1) * 64;
  const int wn = (wave & 1) * 64;
  const int bm = blockIdx.y * 128;
  const int bn = blockIdx.x * 128;
  const int fml = lane & 15;
  const int q  = lane >> 4;
  const int r0a  = tid >> 2;
  const int sseg = tid & 3;

  f32x4 acc[4][4] = {};

  for (int k0 = 0; k0 < 1024; k0 += 32) {
    #pragma unroll
    for (int half = 0; half < 2; ++half) {
      int r = r0a + half*64;
      const float* pa = A + (size_t)(bm + r)*1024 + k0 + sseg*8;
      float4 v0 = *(const float4*)pa;
      float4 v1 = *(const float4*)(pa + 4);
      float xs[8] = {v0.x, v0.y, v0.z, v0.w, v1.x, v1.y, v1.z, v1.w};
      unsigned int hp[4], lp[4];
      #pragma unroll
      for (int t = 0; t < 4; ++t) {
        unsigned short h0 = f2bf(xs[2*t]);
        unsigned short h1 = f2bf(xs[2*t+1]);
        unsigned short l0 = f2bf(xs[2*t]   - bf2f(h0));
        unsigned short l1 = f2bf(xs[2*t+1] - bf2f(h1));
        hp[t] = (unsigned)h0 | ((unsigned)h1 << 16);
        lp[t] = (unsigned)l0 | ((unsigned)l1 << 16);
      }
      *(uint4*)(&Ahs[r*40 + sseg*8]) = make_uint4(hp[0], hp[1], hp[2], hp[3]);
      *(uint4*)(&Als[r*40 + sseg*8]) = make_uint4(lp[0], lp[1], lp[2], lp[3]);
      *(uint4*)(&Bhs[r*40 + sseg*8]) = *(const uint4*)(Bh + (size_t)(bn + r)*1024 + k0 + sseg*8);
      *(uint4*)(&Bls[r*40 + sseg*8]) = *(const uint4*)(Bl + (size_t)(bn + r)*1024 + k0 + sseg*8);
    }
    __syncthreads();
    bf16x8 afh[4], afl[4], bfh[4], bfl[4];
    #pragma unroll
    for (int i = 0; i < 4; ++i) {
      afh[i] = *(const bf16x8*)(&Ahs[(wm + i*16 + fml)*40 + q*8]);
      afl[i] = *(const bf16x8*)(&Als[(wm + i*16 + fml)*40 + q*8]);
    }
    #pragma unroll
    for (int j = 0; j < 4; ++j) {
      bfh[j] = *(const bf16x8*)(&Bhs[(wn + j*16 + fml)*40 + q*8]);
      bfl[j] = *(const bf16x8*)(&Bls[(wn + j*16 + fml)*40 + q*8]);
    }
    #pragma unroll
    for (int i = 0; i < 4; ++i)
      #pragma unroll
      for (int j = 0; j < 4; ++j) {
        acc[i][j] = __builtin_amdgcn_mfma_f32_16x16x32_bf16(afl[i], bfh[j], acc[i][j], 0, 0, 0);
        acc[i][j] = __builtin_amdgcn_mfma_f32_16x16x32_bf16(afh[i], bfl[j], acc[i][j], 0, 0, 0);
        acc[i][j] = __builtin_amdgcn_mfma_f32_16x16x32_bf16(afh[i], bfh[j], acc[i][j], 0, 0, 0);
      }
    __syncthreads();
  }
  #pragma unroll
  for (int i = 0; i < 4; ++i) {
    #pragma unroll
    for (int j = 0; j < 4; ++j) {
      int col = bn + wn + j*16 + fml;
      float bv = bias[col];
      #pragma unroll
      for (int r = 0; r < 4; ++r) {
        int row = bm + wm + i*16 + q*4 + r;   // C/D: col=lane&15, row=quad*4+reg
        C[(size_t)row*D_ + col] = gains[row]*acc[i][j][r] + bv;
      }
    }
  }
}

// ---------------------------------------------------------------- enc MFMA GEMM v3: pre-split A, B chunk [1024][1024], C ld=1024, XCD swizzle
__global__ __launch_bounds__(256) void k_egemm3(
    const unsigned short* __restrict__ Ah, const unsigned short* __restrict__ Al, // [8192][1024]
    const unsigned short* __restrict__ Bh, const unsigned short* __restrict__ Bl, // [1024][1024]
    const float* __restrict__ bias,           // enc_b + chunk offset
    const float* __restrict__ gains,
    float* __restrict__ C)                    // cur [8192][1024]
{
  __shared__ __align__(16) unsigned short Ahs[128*40];
  __shared__ __align__(16) unsigned short Als[128*40];
  __shared__ __align__(16) unsigned short Bhs[128*40];
  __shared__ __align__(16) unsigned short Bls[128*40];
  const int tid  = threadIdx.x;
  const int lane = tid & 63;
  const int wave = tid >> 6;
  const int wm = (wave >> 1) * 64;
  const int wn = (wave & 1) * 64;
  // XCD-aware bijective swizzle: nwg = 8*64 = 512 (%8==0)
  const int flat = blockIdx.y * 8 + blockIdx.x;
  const int swz  = (flat & 7) * 64 + (flat >> 3);
  const int bn = (swz & 7) * 128;
  const int bm = (swz >> 3) * 128;
  const int fml = lane & 15;
  const int q  = lane >> 4;
  const int r0a  = tid >> 2;
  const int sseg = tid & 3;

  f32x4 acc[4][4] = {};

  for (int k0 = 0; k0 < 1024; k0 += 32) {
    #pragma unroll
    for (int half = 0; half < 2; ++half) {
      int r = r0a + half*64;
      *(uint4*)(&Ahs[r*40 + sseg*8]) = *(const uint4*)(Ah + (size_t)(bm + r)*1024 + k0 + sseg*8);
      *(uint4*)(&Als[r*40 + sseg*8]) = *(const uint4*)(Al + (size_t)(bm + r)*1024 + k0 + sseg*8);
      *(uint4*)(&Bhs[r*40 + sseg*8]) = *(const uint4*)(Bh + (size_t)(bn + r)*1024 + k0 + sseg*8);
      *(uint4*)(&Bls[r*40 + sseg*8]) = *(const uint4*)(Bl + (size_t)(bn + r)*1024 + k0 + sseg*8);
    }
    __syncthreads();
    bf16x8 afh[4], afl[4], bfh[4], bfl[4];
    #pragma unroll
    for (int i = 0; i < 4; ++i) {
      afh[i] = *(const bf16x8*)(&Ahs[(wm + i*16 + fml)*40 + q*8]);
      afl[i] = *(const bf16x8*)(&Als[(wm + i*16 + fml)*40 + q*8]);
    }
    #pragma unroll
    for (int j = 0; j < 4; ++j) {
      bfh[j] = *(const bf16x8*)(&Bhs[(wn + j*16 + fml)*40 + q*8]);
      bfl[j] = *(const bf16x8*)(&Bls[(wn + j*16 + fml)*40 + q*8]);
    }
    #pragma unroll
    for (int i = 0; i < 4; ++i)
      #pragma unroll
      for (int j = 0; j < 4; ++j) {
        acc[i][j] = __builtin_amdgcn_mfma_f32_16x16x32_bf16(afl[i], bfh[j], acc[i][j], 0, 0, 0);
        acc[i][j] = __builtin_amdgcn_mfma_f32_16x16x32_bf16(afh[i], bfl[j], acc[i][j], 0, 0, 0);
        acc[i][j] = __builtin_amdgcn_mfma_f32_16x16x32_bf16(afh[i], bfh[j], acc[i][j], 0, 0, 0);
      }
    __syncthreads();
  }
  #pragma unroll
  for (int i = 0; i < 4; ++i) {
    #pragma unroll
    for (int j = 0; j < 4; ++j) {
      int col = bn + wn + j*16 + fml;
      float bv = bias[col];
      #pragma unroll
      for (int r = 0; r < 4; ++r) {
        int row = bm + wm + i*16 + q*4 + r;
        C[(size_t)row*D_ + col] = gains[row]*acc[i][j][r] + bv;
      }
    }
  }
}

// ---------------------------------------------------------------- GIF scan, f32 fast path (enc + dec)
__global__ __launch_bounds__(256) void k_gif_warm32(const float* __restrict__ buf,
    float* __restrict__ vinit, int Wd, int CS, int Stot)
{
  int c = blockIdx.x*256 + threadIdx.x;
  int channels = gridDim.x*256;
  int chunk = blockIdx.y;
  int b = c / Wd, h = c - b*Wd;
  int s_emit = chunk*CS;
  int s0 = s_emit - HALO; if (s0 < 0) s0 = 0;
  const float* p = buf + (size_t)b*Stot*Wd + h;
  float v = 0.f;
  for (int sg = s0; sg < s_emit; sg += 8) {
    float cv[8];
    #pragma unroll
    for (int i = 0; i < 8; ++i) cv[i] = p[(size_t)(sg+i)*Wd];
    #pragma unroll
    for (int i = 0; i < 8; ++i) {
      v = 0.9f*v + cv[i];
      float s = 1.0f/(1.0f + __expf(-4.0f*(v - 1.0f)));
      v -= s;
    }
  }
  vinit[(size_t)chunk*channels + c] = v;
}

__global__ __launch_bounds__(256) void k_gif_emit32(float* __restrict__ buf,
    const float* __restrict__ vinit, int Wd, int CS, int Stot)
{
  int c = blockIdx.x*256 + threadIdx.x;
  int channels = gridDim.x*256;
  int chunk = blockIdx.y;
  int b = c / Wd, h = c - b*Wd;
  float* p = buf + (size_t)b*Stot*Wd + h + (size_t)chunk*CS*Wd;
  float v = vinit[(size_t)chunk*channels + c];
  float cv[8], nv[8] = {0,0,0,0,0,0,0,0};
  #pragma unroll
  for (int i = 0; i < 8; ++i) cv[i] = p[(size_t)i*Wd];
  for (int sg = 0; sg < CS; sg += 8) {
    float sp[8];
    #pragma unroll
    for (int i = 0; i < 8; ++i) {
      v = 0.9f*v + cv[i];
      float s = 1.0f/(1.0f + __expf(-4.0f*(v - 1.0f)));
      v -= s; sp[i] = s;
    }
    if (sg + 8 < CS) {
      #pragma unroll
      for (int i = 0; i < 8; ++i) nv[i] = p[(size_t)(sg+8+i)*Wd];
    }
    #pragma unroll
    for (int i = 0; i < 8; ++i) p[(size_t)(sg+i)*Wd] = sp[i];
    #pragma unroll
    for (int i = 0; i < 8; ++i) cv[i] = nv[i];
  }
}

// ---------------------------------------------------------------- s2c split-bf16 MFMA: cont[8192][64] (+)= cur[8192][1024] @ s2c_W chunk
__global__ __launch_bounds__(256) void k_s2cM(
    const float* __restrict__ A,                // cur f32 [8192][1024]
    const unsigned short* __restrict__ WTh,     // [64][2048] bf16 hi
    const unsigned short* __restrict__ WTl,     // [64][2048] bf16 lo
    size_t woff,                                // chunk col offset (c*1024)
    float* __restrict__ out,                    // cont [8192][64]
    int accum, const float* __restrict__ bias2)
{
  __shared__ __align__(16) unsigned short Ahs[64*40], Als[64*40];
  __shared__ __align__(16) unsigned short Bhs[64*40], Bls[64*40];
  const int tid  = threadIdx.x;
  const int lane = tid & 63;
  const int wave = tid >> 6;
  const int wm = (wave >> 1) * 32;
  const int wn = (wave & 1) * 32;
  const int bm = blockIdx.x * 64;
  const int fml = lane & 15;
  const int q  = lane >> 4;
  const int r0a  = tid >> 2;   // 0..63
  const int sseg = tid & 3;

  f32x4 acc[2][2] = {};

  for (int k0 = 0; k0 < 1024; k0 += 32) {
    {
      const float* pa = A + (size_t)(bm + r0a)*1024 + k0 + sseg*8;
      float4 v0 = *(const float4*)pa;
      float4 v1 = *(const float4*)(pa + 4);
      float xs[8] = {v0.x, v0.y, v0.z, v0.w, v1.x, v1.y, v1.z, v1.w};
      unsigned int hp[4], lp[4];
      #pragma unroll
      for (int t = 0; t < 4; ++t) {
        unsigned short h0 = f2bf(xs[2*t]);
        unsigned short h1 = f2bf(xs[2*t+1]);
        unsigned short l0 = f2bf(xs[2*t]   - bf2f(h0));
        unsigned short l1 = f2bf(xs[2*t+1] - bf2f(h1));
        hp[t] = (unsigned)h0 | ((unsigned)h1 << 16);
        lp[t] = (unsigned)l0 | ((unsigned)l1 << 16);
      }
      *(uint4*)(&Ahs[r0a*40 + sseg*8]) = make_uint4(hp[0], hp[1], hp[2], hp[3]);
      *(uint4*)(&Als[r0a*40 + sseg*8]) = make_uint4(lp[0], lp[1], lp[2], lp[3]);
      *(uint4*)(&Bhs[r0a*40 + sseg*8]) = *(const uint4*)(WTh + (size_t)r0a*2048 + woff + k0 + sseg*8);
      *(uint4*)(&Bls[r0a*40 + sseg*8]) = *(const uint4*)(WTl + (size_t)r0a*2048 + woff + k0 + sseg*8);
    }
    __syncthreads();
    bf16x8 afh[2], afl[2], bfh[2], bfl[2];
    #pragma unroll
    for (int i = 0; i < 2; ++i) {
      afh[i] = *(const bf16x8*)(&Ahs[(wm + i*16 + fml)*40 + q*8]);
      afl[i] = *(const bf16x8*)(&Als[(wm + i*16 + fml)*40 + q*8]);
    }
    #pragma unroll
    for (int j = 0; j < 2; ++j) {
      bfh[j] = *(const bf16x8*)(&Bhs[(wn + j*16 + fml)*40 + q*8]);
      bfl[j] = *(const bf16x8*)(&Bls[(wn + j*16 + fml)*40 + q*8]);
    }
    #pragma unroll
    for (int i = 0; i < 2; ++i)
      #pragma unroll
      for (int j = 0; j < 2; ++j) {
        acc[i][j] = __builtin_amdgcn_mfma_f32_16x16x32_bf16(afl[i], bfh[j], acc[i][j], 0, 0, 0);
        acc[i][j] = __builtin_amdgcn_mfma_f32_16x16x32_bf16(afh[i], bfl[j], acc[i][j], 0, 0, 0);
        acc[i][j] = __builtin_amdgcn_mfma_f32_16x16x32_bf16(afh[i], bfh[j], acc[i][j], 0, 0, 0);
      }
    __syncthreads();
  }
  #pragma unroll
  for (int j = 0; j < 2; ++j) {
    const int col = wn + j*16 + fml;   // 0..63
    #pragma unroll
    for (int i = 0; i < 2; ++i) {
      #pragma unroll
      for (int r = 0; r < 4; ++r) {
        const int row = bm + wm + i*16 + q*4 + r;
        const size_t idx = (size_t)row*64 + col;
        float a = acc[i][j][r];
        if (accum) {
          float v = out[idx] + a;
          if (bias2) v = v + bias2[col];
          out[idx] = v;
        } else out[idx] = a;
      }
    }
  }
}

// ---------------------------------------------------------------- s2c partial, f32 FMA — fallback tier only
__global__ __launch_bounds__(256) void k_s2c(const float* __restrict__ Sp, int ldS, int KH,
    const float* __restrict__ W, size_t woff, float* __restrict__ out, int accum,
    const float* __restrict__ bias2) {
  __shared__ float As_[16][17];
  __shared__ float Ws_[16][68];
  const int bm = blockIdx.x * 16;
  const int tid = threadIdx.x;
  const int rt = tid >> 4;   // row 0..15
  const int ct = tid & 15;   // col group 0..15
  float acc[4] = {};
  for (int k0 = 0; k0 < KH; k0 += 16) {
    As_[tid >> 4][tid & 15] = Sp[(size_t)(bm + (tid >> 4))*ldS + k0 + (tid & 15)];
    #pragma unroll
    for (int i = 0; i < 4; ++i) {
      int e = tid + i*256;
      Ws_[e >> 6][e & 63] = W[woff + (size_t)(k0 + (e >> 6))*64 + (e & 63)];
    }
    __syncthreads();
    #pragma unroll
    for (int kk = 0; kk < 16; ++kk) {
      float a = As_[rt][kk];
      #pragma unroll
      for (int j = 0; j < 4; ++j) acc[j] += a * Ws_[kk][ct*4+j];
    }
    __syncthreads();
  }
  #pragma unroll
  for (int j = 0; j < 4; ++j) {
    size_t idx = ((size_t)bm + rt)*64 + ct*4 + j;
    float a = acc[j];
    if (accum) {
      float v = out[idx] + a;
      if (bias2) v = v + bias2[ct*4+j]; // bias fold on final pass
      out[idx] = v;
    } else out[idx] = a;
  }
}

// ---------------------------------------------------------------- zero expert counters
__global__ void k_zero(int* p) { if (threadIdx.x < 8) p[threadIdx.x] = 0; }

// ---------------------------------------------------------------- fused router (f32): hidden in LDS, logits, top-2, block-agg append
__global__ __launch_bounds__(256) void k_router2(const float* __restrict__ cont,
    const float* __restrict__ rW1, const float* __restrict__ rb1,
    const float* __restrict__ rW2, const float* __restrict__ rb2,
    const float* __restrict__ gains,
    int* __restrict__ cnt, unsigned int* __restrict__ list, float* __restrict__ lw)
{
  __shared__ float W1s[64*64];
  __shared__ float W2s[64*8];
  __shared__ float b2s[8];
  __shared__ float cs[16][64];
  __shared__ float hs[16][65];
  __shared__ int bcnt[8];
  __shared__ int bbase[8];
  const int tid = threadIdx.x;
  const int j  = tid & 63;
  const int tg = tid >> 6;           // 0..3
  const int n0 = blockIdx.x * 16;
  for (int i = tid; i < 64*64; i += 256) W1s[i] = rW1[i];
  for (int i = tid; i < 64*8; i += 256)  W2s[i] = rW2[i];
  if (tid < 8) { b2s[tid] = rb2[tid]; bcnt[tid] = 0; }
  #pragma unroll
  for (int i = 0; i < 4; ++i) {
    int e = tid + i*256;             // 1024 = 16 tokens x 64
    cs[e >> 6][e & 63] = cont[(size_t)(n0 + (e >> 6))*64 + (e & 63)];
  }
  __syncthreads();
  {
    const float b1 = rb1[j];
    float t0 = b1, t1 = b1, t2 = b1, t3 = b1;
    #pragma unroll
    for (int m = 0; m < 64; ++m) {
      const float w = W1s[m*64 + j];
      t0 += cs[tg*4+0][m] * w;
      t1 += cs[tg*4+1][m] * w;
      t2 += cs[tg*4+2][m] * w;
      t3 += cs[tg*4+3][m] * w;
    }
    hs[tg*4+0][j] = tanhf(t0);
    hs[tg*4+1][j] = tanhf(t1);
    hs[tg*4+2][j] = tanhf(t2);
    hs[tg*4+3][j] = tanhf(t3);
  }
  __syncthreads();
  int i1 = 0, i2 = 0, p1l = 0, p2l = 0;
  float w1 = 0.f;
  if (tid < 16) {
    const int n = n0 + tid;
    float lg[8];
    #pragma unroll
    for (int e = 0; e < 8; ++e) lg[e] = b2s[e];
    #pragma unroll 8
    for (int jj = 0; jj < 64; ++jj) {
      float t = hs[tid][jj];
      #pragma unroll
      for (int e = 0; e < 8; ++e) lg[e] += t * W2s[jj*8 + e];
    }
    float g = gains[n];
    #pragma unroll
    for (int e = 0; e < 8; ++e) lg[e] *= g;
    float m1 = lg[0];
    #pragma unroll
    for (int e = 1; e < 8; ++e) if (lg[e] > m1) { m1 = lg[e]; i1 = e; }
    i2 = (i1 == 0) ? 1 : 0; float m2 = lg[i2];
    #pragma unroll
    for (int e = 0; e < 8; ++e) if (e != i1 && lg[e] > m2) { m2 = lg[e]; i2 = e; }
    w1 = 1.0f / (1.0f + __expf(m2 - m1));
    p1l = atomicAdd(&bcnt[i1], 1);
    p2l = atomicAdd(&bcnt[i2], 1);
  }
  __syncthreads();
  if (tid < 8) bbase[tid] = bcnt[tid] ? atomicAdd(&cnt[tid], bcnt[tid]) : 0;
  __syncthreads();
  if (tid < 16) {
    const int n = n0 + tid;
    const int p1 = bbase[i1] + p1l;
    list[i1*8192 + p1] = ((unsigned)n << 1);
    lw[i1*8192 + p1] = w1;
    const int p2 = bbase[i2] + p2l;
    list[i2*8192 + p2] = ((unsigned)n << 1) | 1u;
    lw[i2*8192 + p2] = 1.0f - w1;
  }
}

// ---------------------------------------------------------------- grouped experts — f32 SIMT (fallback tier only)
__global__ __launch_bounds__(256) void k_expgrp(
    const float* __restrict__ cont,
    const unsigned int* __restrict__ list, const float* __restrict__ lw,
    const int* __restrict__ cnt,
    const float* __restrict__ eW1, const float* __restrict__ eb1,
    const float* __restrict__ eW2, const float* __restrict__ eb2,
    float* __restrict__ eout)
{
  const int e = blockIdx.y;
  const int t0 = blockIdx.x * 64;
  const int ce = cnt[e];
  if (t0 >= ce) return;
  const int nt = (ce - t0 < 64) ? (ce - t0) : 64;
  __shared__ float ct[64][65];
  __shared__ float w1b[64][65];
  __shared__ float hbl[64][65];
  __shared__ float w2b[64][65];
  __shared__ unsigned int sl[64];
  __shared__ float swt[64];
  const int tid = threadIdx.x;
  if (tid < 64) {
    if (tid < nt) {
      sl[tid]  = list[e*8192 + t0 + tid];
      swt[tid] = lw[e*8192 + t0 + tid];
    } else { sl[tid] = 0; swt[tid] = 0.f; }
  }
  __syncthreads();
  for (int f = tid; f < 64*64; f += 256) {
    int r = f >> 6, m = f & 63;
    ct[r][m] = (r < nt) ? cont[(size_t)(sl[r] >> 1)*64 + m] : 0.f;
  }
  const float* W1 = eW1 + (size_t)e*64*1024;
  const float* W2 = eW2 + (size_t)e*1024*64;
  const float* B1 = eb1 + (size_t)e*1024;
  const int rt = tid >> 4, c16 = tid & 15;
  float outa[4][4] = {};
  for (int hc = 0; hc < 1024; hc += 64) {
    __syncthreads();
    for (int f = tid; f < 64*64; f += 256) {
      int m = f >> 6, j = f & 63;
      w1b[m][j] = W1[(size_t)m*1024 + hc + j];
      w2b[m][j] = W2[(size_t)(hc + m)*64 + j];
    }
    __syncthreads();
    float h4[4][4];
    #pragma unroll
    for (int i = 0; i < 4; ++i) {
      #pragma unroll
      for (int j = 0; j < 4; ++j) h4[i][j] = B1[hc + c16*4 + j];
    }
    #pragma unroll 16
    for (int m = 0; m < 64; ++m) {
      float a4[4], b4[4];
      #pragma unroll
      for (int i = 0; i < 4; ++i) a4[i] = ct[rt*4+i][m];
      #pragma unroll
      for (int j = 0; j < 4; ++j) b4[j] = w1b[m][c16*4+j];
      #pragma unroll
      for (int i = 0; i < 4; ++i)
        #pragma unroll
        for (int j = 0; j < 4; ++j) h4[i][j] += a4[i]*b4[j];
    }
    #pragma unroll
    for (int i = 0; i < 4; ++i)
      #pragma unroll
      for (int j = 0; j < 4; ++j)
        hbl[rt*4+i][c16*4+j] = fmaxf(h4[i][j], 0.f);
    __syncthreads();
    #pragma unroll 16
    for (int j = 0; j < 64; ++j) {
      float a4[4], b4[4];
      #pragma unroll
      for (int i = 0; i < 4; ++i) a4[i] = hbl[rt*4+i][j];
      #pragma unroll
      for (int nn = 0; nn < 4; ++nn) b4[nn] = w2b[j][c16*4+nn];
      #pragma unroll
      for (int i = 0; i < 4; ++i)
        #pragma unroll
        for (int nn = 0; nn < 4; ++nn) outa[i][nn] += a4[i]*b4[nn];
    }
  }
  #pragma unroll
  for (int i = 0; i < 4; ++i) {
    int r = rt*4 + i;
    if (r < nt) {
      float w = swt[r];
      #pragma unroll
      for (int nn = 0; nn < 4; ++nn) {
        int col = c16*4 + nn;
        eout[(size_t)sl[r]*64 + col] = w * (outa[i][nn] + eb2[(size_t)e*64 + col]);
      }
    }
  }
}

// ---------------------------------------------------------------- grouped experts — split-bf16 MFMA (e=blockIdx.y, spread all CUs)
__global__ __launch_bounds__(256) void k_expmfma(
    const float* __restrict__ cont,
    const unsigned int* __restrict__ list, const float* __restrict__ lw,
    const int* __restrict__ cnt,
    const unsigned short* __restrict__ w1h, const unsigned short* __restrict__ w1l, // [E][1024][64]
    const float* __restrict__ eb1,                                                  // [E][1024]
    const unsigned short* __restrict__ w2h, const unsigned short* __restrict__ w2l, // [E][64][1024]
    const float* __restrict__ eb2,                                                  // [E][64]
    float* __restrict__ eout)
{
  const int e  = blockIdx.y;
  const int t0 = blockIdx.x * 64;
  const int ce = cnt[e];
  if (t0 >= ce) return;
  const int nt = (ce - t0 < 64) ? (ce - t0) : 64;

  // stride 72 shorts = 144 B = 36 words (36 % 32 = 4): 16-row frag reads are <=2-way.
  __shared__ __align__(16) unsigned short cth[64*72],  ctl[64*72];
  __shared__ __align__(16) unsigned short w1sh[64*72], w1sl[64*72];
  __shared__ __align__(16) unsigned short w2sh[64*72], w2sl[64*72];
  __shared__ __align__(16) unsigned short hsh[64*72],  hsl[64*72];
  __shared__ unsigned int sl[64];
  __shared__ float swt[64];

  const int tid  = threadIdx.x;
  const int lane = tid & 63;
  const int wave = tid >> 6;
  const int wm  = (wave >> 1) * 32;   // token offset of this wave
  const int wn  = (wave & 1) * 32;    // col offset of this wave
  const int fml = lane & 15;
  const int q   = lane >> 4;          // 0..3

  if (tid < 64) {
    if (tid < nt) { sl[tid] = list[e*8192 + t0 + tid]; swt[tid] = lw[e*8192 + t0 + tid]; }
    else          { sl[tid] = 0; swt[tid] = 0.f; }
  }
  __syncthreads();

  // gather cont rows + split to hi/lo bf16 (row = token, 16 f32 per thread)
  {
    const int row = tid >> 2;
    const int m0  = (tid & 3) * 16;
    float x[16] = {0.f,0.f,0.f,0.f,0.f,0.f,0.f,0.f,0.f,0.f,0.f,0.f,0.f,0.f,0.f,0.f};
    if (row < nt) {
      const float* p = cont + (size_t)(sl[row] >> 1)*64 + m0;
      *(float4*)&x[0]  = *(const float4*)(p);
      *(float4*)&x[4]  = *(const float4*)(p + 4);
      *(float4*)&x[8]  = *(const float4*)(p + 8);
      *(float4*)&x[12] = *(const float4*)(p + 12);
    }
    unsigned int hp[8], lp[8];
    #pragma unroll
    for (int t = 0; t < 8; ++t) {
      unsigned short h0 = f2bf(x[2*t]);
      unsigned short h1 = f2bf(x[2*t+1]);
      unsigned short l0 = f2bf(x[2*t]   - bf2f(h0));
      unsigned short l1 = f2bf(x[2*t+1] - bf2f(h1));
      hp[t] = (unsigned)h0 | ((unsigned)h1 << 16);
      lp[t] = (unsigned)l0 | ((unsigned)l1 << 16);
    }
    *(uint4*)&cth[row*72 + m0]     = make_uint4(hp[0], hp[1], hp[2], hp[3]);
    *(uint4*)&cth[row*72 + m0 + 8] = make_uint4(hp[4], hp[5], hp[6], hp[7]);
    *(uint4*)&ctl[row*72 + m0]     = make_uint4(lp[0], lp[1], lp[2], lp[3]);
    *(uint4*)&ctl[row*72 + m0 + 8] = make_uint4(lp[4], lp[5], lp[6], lp[7]);
  }

  f32x4 acc2[2][2] = {};

  for (int hc = 0; hc < 1024; hc += 64) {
    // stage this chunk's weights: w1 rows = h-cols (K=m), w2 rows = out-cols (K=h)
    {
      const int row = tid >> 2;
      const int seg = (tid & 3) * 16;
      const size_t o1 = ((size_t)(e*1024 + hc + row))*64 + seg;
      *(uint4*)&w1sh[row*72 + seg]     = *(const uint4*)(w1h + o1);
      *(uint4*)&w1sh[row*72 + seg + 8] = *(const uint4*)(w1h + o1 + 8);
      *(uint4*)&w1sl[row*72 + seg]     = *(const uint4*)(w1l + o1);
      *(uint4*)&w1sl[row*72 + seg + 8] = *(const uint4*)(w1l + o1 + 8);
      const size_t o2 = ((size_t)(e*64 + row))*1024 + hc + seg;
      *(uint4*)&w2sh[row*72 + seg]     = *(const uint4*)(w2h + o2);
      *(uint4*)&w2sh[row*72 + seg + 8] = *(const uint4*)(w2h + o2 + 8);
      *(uint4*)&w2sl[row*72 + seg]     = *(const uint4*)(w2l + o2);
      *(uint4*)&w2sl[row*72 + seg + 8] = *(const uint4*)(w2l + o2 + 8);
    }
    __syncthreads();

    // GEMM1: h[t][col] = sum_m ct[t][m] * w1[col][m], K=64
    f32x4 acc1[2][2] = {};
    #pragma unroll
    for (int ks = 0; ks < 2; ++ks) {
      bf16x8 ah[2], al[2], bh[2], bl[2];
      #pragma unroll
      for (int i = 0; i < 2; ++i) {
        ah[i] = *(const bf16x8*)&cth[(wm + i*16 + fml)*72 + ks*32 + q*8];
        al[i] = *(const bf16x8*)&ctl[(wm + i*16 + fml)*72 + ks*32 + q*8];
      }
      #pragma unroll
      for (int j = 0; j < 2; ++j) {
        bh[j] = *(const bf16x8*)&w1sh[(wn + j*16 + fml)*72 + ks*32 + q*8];
        bl[j] = *(const bf16x8*)&w1sl[(wn + j*16 + fml)*72 + ks*32 + q*8];
      }
      #pragma unroll
      for (int i = 0; i < 2; ++i)
        #pragma unroll
        for (int j = 0; j < 2; ++j) {
          acc1[i][j] = __builtin_amdgcn_mfma_f32_16x16x32_bf16(al[i], bh[j], acc1[i][j], 0, 0, 0);
          acc1[i][j] = __builtin_amdgcn_mfma_f32_16x16x32_bf16(ah[i], bl[j], acc1[i][j], 0, 0, 0);
          acc1[i][j] = __builtin_amdgcn_mfma_f32_16x16x32_bf16(ah[i], bh[j], acc1[i][j], 0, 0, 0);
        }
    }

    // bias + relu + split to hi/lo, write h to LDS (C/D: col=lane&15, row=q*4+r)
    #pragma unroll
    for (int j = 0; j < 2; ++j) {
      const int col = wn + j*16 + fml;
      const float b1 = eb1[(size_t)e*1024 + hc + col];
      #pragma unroll
      for (int i = 0; i < 2; ++i) {
        #pragma unroll
        for (int r = 0; r < 4; ++r) {
          const int trow = wm + i*16 + q*4 + r;
          float v = fmaxf(acc1[i][j][r] + b1, 0.f);
          unsigned short hh = f2bf(v);
          hsh[trow*72 + col] = hh;
          hsl[trow*72 + col] = f2bf(v - bf2f(hh));
        }
      }
    }
    __syncthreads();

    // GEMM2: out[t][n] += sum_h hs[t][h] * w2[n][h], K=64
    #pragma unroll
    for (int ks = 0; ks < 2; ++ks) {
      bf16x8 ah[2], al[2], bh[2], bl[2];
      #pragma unroll
      for (int i = 0; i < 2; ++i) {
        ah[i] = *(const bf16x8*)&hsh[(wm + i*16 + fml)*72 + ks*32 + q*8];
        al[i] = *(const bf16x8*)&hsl[(wm + i*16 + fml)*72 + ks*32 + q*8];
      }
      #pragma unroll
      for (int j = 0; j < 2; ++j) {
        bh[j] = *(const bf16x8*)&w2sh[(wn + j*16 + fml)*72 + ks*32 + q*8];
        bl[j] = *(const bf16x8*)&w2sl[(wn + j*16 + fml)*72 + ks*32 + q*8];
      }
      #pragma unroll
      for (int i = 0; i < 2; ++i)
        #pragma unroll
        for (int j = 0; j < 2; ++j) {
          acc2[i][j] = __builtin_amdgcn_mfma_f32_16x16x32_bf16(al[i], bh[j], acc2[i][j], 0, 0, 0);
          acc2[i][j] = __builtin_amdgcn_mfma_f32_16x16x32_bf16(ah[i], bl[j], acc2[i][j], 0, 0, 0);
          acc2[i][j] = __builtin_amdgcn_mfma_f32_16x16x32_bf16(ah[i], bh[j], acc2[i][j], 0, 0, 0);
        }
    }
    __syncthreads();   // before next chunk overwrites w1s/w2s/hs
  }

  // epilogue: eout[slot][n] = w * (acc + b2)
  #pragma unroll
  for (int j = 0; j < 2; ++j) {
    const int col = wn + j*16 + fml;
    const float b2 = eb2[(size_t)e*64 + col];
    #pragma unroll
    for (int i = 0; i < 2; ++i) {
      #pragma unroll
      for (int r = 0; r < 4; ++r) {
        const int trow = wm + i*16 + q*4 + r;
        if (trow < nt)
          eout[(size_t)sl[trow]*64 + col] = swt[trow]*(acc2[i][j][r] + b2);
      }
    }
  }
}

// ---------------------------------------------------------------- c2s MFMA GEMM, split-bf16 (3 products)
__global__ __launch_bounds__(256) void k_c2sM(
    const float* __restrict__ eoutTok,        // [T][128]
    const unsigned short* __restrict__ WTh,   // [2048][64] bf16 hi
    const unsigned short* __restrict__ WTl,   // [2048][64] bf16 lo
    const float* __restrict__ bias,           // [2048]
    unsigned short* __restrict__ rates)       // [T][2048]
{
  __shared__ __align__(16) unsigned short Ahs[128*72], Als[128*72];
  __shared__ __align__(16) unsigned short Bhs[128*72], Bls[128*72];
  const int tid  = threadIdx.x;
  const int lane = tid & 63;
  const int wave = tid >> 6;
  const int wm = (wave >> 1) * 64;
  const int wn = (wave & 1) * 64;
  const int bm = blockIdx.y * 128;
  const int bn = blockIdx.x * 128;
  const int fml = lane & 15;
  const int q  = lane >> 4;

  {
    const int row = tid >> 1;          // 0..127
    const int m0  = (tid & 1) * 32;    // 0 or 32
    const float* p = eoutTok + (size_t)(bm + row)*128 + m0;
    float x[32];
    #pragma unroll
    for (int i = 0; i < 8; ++i) {
      float4 a = *(const float4*)(p + i*4);
      float4 b = *(const float4*)(p + 64 + i*4);
      x[i*4+0] = a.x + b.x; x[i*4+1] = a.y + b.y;
      x[i*4+2] = a.z + b.z; x[i*4+3] = a.w + b.w;
    }
    unsigned int hp[16], lp[16];
    #pragma unroll
    for (int t = 0; t < 16; ++t) {
      unsigned short h0 = f2bf(x[2*t]);
      unsigned short h1 = f2bf(x[2*t+1]);
      unsigned short l0 = f2bf(x[2*t]   - bf2f(h0));
      unsigned short l1 = f2bf(x[2*t+1] - bf2f(h1));
      hp[t] = (unsigned)h0 | ((unsigned)h1 << 16);
      lp[t] = (unsigned)l0 | ((unsigned)l1 << 16);
    }
    #pragma unroll
    for (int t = 0; t < 4; ++t) {
      *(uint4*)&Ahs[row*72 + m0 + t*8] = make_uint4(hp[t*4+0],hp[t*4+1],hp[t*4+2],hp[t*4+3]);
      *(uint4*)&Als[row*72 + m0 + t*8] = make_uint4(lp[t*4+0],lp[t*4+1],lp[t*4+2],lp[t*4+3]);
    }
    const unsigned short* ph = WTh + (size_t)(bn + row)*64 + m0;
    const unsigned short* pl = WTl + (size_t)(bn + row)*64 + m0;
    #pragma unroll
    for (int t = 0; t < 4; ++t) {
      *(uint4*)&Bhs[row*72 + m0 + t*8] = *(const uint4*)(ph + t*8);
      *(uint4*)&Bls[row*72 + m0 + t*8] = *(const uint4*)(pl + t*8);
    }
  }
  __syncthreads();

  f32x4 acc[4][4] = {};
  #pragma unroll
  for (int ks = 0; ks < 2; ++ks) {
    bf16x8 ah[4], al[4], bh[4], bl[4];
    #pragma unroll
    for (int i = 0; i < 4; ++i) {
      ah[i] = *(const bf16x8*)&Ahs[(wm + i*16 + fml)*72 + ks*32 + q*8];
      al[i] = *(const bf16x8*)&Als[(wm + i*16 + fml)*72 + ks*32 + q*8];
    }
    #pragma unroll
    for (int j = 0; j < 4; ++j) {
      bh[j] = *(const bf16x8*)&Bhs[(wn + j*16 + fml)*72 + ks*32 + q*8];
      bl[j] = *(const bf16x8*)&Bls[(wn + j*16 + fml)*72 + ks*32 + q*8];
    }
    #pragma unroll
    for (int i = 0; i < 4; ++i)
      #pragma unroll
      for (int j = 0; j < 4; ++j) {
        acc[i][j] = __builtin_amdgcn_mfma_f32_16x16x32_bf16(al[i], bh[j], acc[i][j], 0, 0, 0);
        acc[i][j] = __builtin_amdgcn_mfma_f32_16x16x32_bf16(ah[i], bl[j], acc[i][j], 0, 0, 0);
        acc[i][j] = __builtin_amdgcn_mfma_f32_16x16x32_bf16(ah[i], bh[j], acc[i][j], 0, 0, 0);
      }
  }

  #pragma unroll
  for (int j = 0; j < 4; ++j) {
    const int col = bn + wn + j*16 + fml;
    const float bv = bias[col];
    #pragma unroll
    for (int i = 0; i < 4; ++i) {
      #pragma unroll
      for (int r = 0; r < 4; ++r) {
        const int row = bm + wm + i*16 + q*4 + r;
        rates[(size_t)row*H_ + col] = f2bf(sigf(acc[i][j][r] + bv));
      }
    }
  }
}

// ---------------------------------------------------------------- c2s 256-col slice -> f32 (fallback path)
__global__ __launch_bounds__(256) void k_c2sS(const float* __restrict__ eoutTok,
    const float* __restrict__ W, int coff,
    const float* __restrict__ bias, float* __restrict__ rat)
{
  __shared__ float ml[8][64];
  const int tid = threadIdx.x;
  const int n0 = blockIdx.x * 8;
  for (int i = tid; i < 512; i += 256) {
    int t = i >> 6, m = i & 63;
    ml[t][m] = eoutTok[(size_t)(n0+t)*128 + m] + eoutTok[(size_t)(n0+t)*128 + 64 + m];
  }
  __syncthreads();
  float acc[8] = {};
  for (int m = 0; m < 64; ++m) {
    float wv = W[(size_t)m*H_ + coff + tid];
    #pragma unroll
    for (int t = 0; t < 8; ++t) acc[t] += ml[t][m] * wv;
  }
  float bv = bias[coff + tid];
  #pragma unroll
  for (int t = 0; t < 8; ++t)
    rat[(size_t)(n0+t)*256 + tid] = sigf(acc[t] + bv);
}

// ---------------------------------------------------------------- f32 -> bf16 transpose (dec_W [R][C] -> out [C][R])
__global__ __launch_bounds__(256) void k_transb(const float* __restrict__ in,
    unsigned short* __restrict__ out, int R, int C) {
  __shared__ unsigned short t[32][33];
  int c0 = blockIdx.x*32, r0 = blockIdx.y*32;
  int tx = threadIdx.x & 31, ty = threadIdx.x >> 5;
  #pragma unroll
  for (int i = 0; i < 32; i += 8)
    t[ty+i][tx] = f2bf(in[(size_t)(r0+ty+i)*C + (c0+tx)]);
  __syncthreads();
  #pragma unroll
  for (int i = 0; i < 32; i += 8)
    out[(size_t)(c0+ty+i)*R + (r0+tx)] = t[tx][ty+i];
}

// ---------------------------------------------------------------- dec MFMA GEMM + XCD bijective swizzle
__global__ __launch_bounds__(256) void k_dgemm(
    const unsigned short* __restrict__ A,
    const unsigned short* __restrict__ BT,
    const float* __restrict__ bias,
    const float* __restrict__ gains,
    float* __restrict__ C)
{
  __shared__ __align__(16) unsigned short As[128*40];
  __shared__ __align__(16) unsigned short Bs[128*40];
  const int tid  = threadIdx.x;
  const int lane = tid & 63;
  const int wave = tid >> 6;
  const int wm = (wave >> 1) * 64;
  const int wn = (wave & 1) * 64;
  // XCD-aware bijective swizzle: nwg = 8*gy (%8==0)
  const int gy   = gridDim.y;
  const int flat = blockIdx.y * 8 + blockIdx.x;
  const int swz  = (flat & 7) * gy + (flat >> 3);
  const int bn = (swz & 7) * 128;
  const int bm = (swz >> 3) * 128;
  const int fml = lane & 15;
  const int q  = lane >> 4;
  const int r0a  = tid >> 2;
  const int sseg = tid & 3;

  f32x4 acc[4][4] = {};

  for (int k0 = 0; k0 < H_; k0 += 32) {
    #pragma unroll
    for (int half = 0; half < 2; ++half) {
      int r = r0a + half*64;
      *(uint4*)(&As[r*40 + sseg*8]) = *(const uint4*)(A + (size_t)(bm + r)*H_ + k0 + sseg*8);
      *(uint4*)(&Bs[r*40 + sseg*8]) = *(const uint4*)(BT + (size_t)(bn + r)*H_ + k0 + sseg*8);
    }
    __syncthreads();
    bf16x8 af[4], bfr[4];
    #pragma unroll
    for (int i = 0; i < 4; ++i)
      af[i] = *(const bf16x8*)(&As[(wm + i*16 + fml)*40 + q*8]);
    #pragma unroll
    for (int j = 0; j < 4; ++j)
      bfr[j] = *(const bf16x8*)(&Bs[(wn + j*16 + fml)*40 + q*8]);
    #pragma unroll
    for (int i = 0; i < 4; ++i)
      #pragma unroll
      for (int j = 0; j < 4; ++j)
        acc[i][j] = __builtin_amdgcn_mfma_f32_16x16x32_bf16(af[i], bfr[j], acc[i][j], 0, 0, 0);
    __syncthreads();
  }
  #pragma unroll
  for (int i = 0; i < 4; ++i) {
    #pragma unroll
    for (int j = 0; j < 4; ++j) {
      int col = bn + wn + j*16 + fml;
      float bv = bias[col];
      #pragma unroll
      for (int r = 0; r < 4; ++r) {
        int row = bm + wm + i*16 + q*4 + r;
        C[(size_t)row*D_ + col] = gains[row]*acc[i][j][r] + bv;
      }
    }
  }
}

// ---------------------------------------------------------------- layernorm D=1024 in-place
__global__ __launch_bounds__(256) void k_ln(float* __restrict__ X,
    const float* __restrict__ g, const float* __restrict__ b)
{
  const int n = blockIdx.x, tid = threadIdx.x;
  float4* row = (float4*)(X + (size_t)n*D_);
  const float4 xv = row[tid];
  float xa[4] = {xv.x, xv.y, xv.z, xv.w};
  float s = xa[0]+xa[1]+xa[2]+xa[3];
  float ss = xa[0]*xa[0]+xa[1]*xa[1]+xa[2]*xa[2]+xa[3]*xa[3];
  #pragma unroll
  for (int off = 32; off >= 1; off >>= 1) {
    s  += __shfl_down(s, off);
    ss += __shfl_down(ss, off);
  }
  __shared__ float rs[4], rss[4];
  const int lane = tid & 63, wv = tid >> 6;
  if (lane == 0) { rs[wv] = s; rss[wv] = ss; }
  __syncthreads();
  float S0 = rs[0]+rs[1]+rs[2]+rs[3];
  float SS = rss[0]+rss[1]+rss[2]+rss[3];
  float mu = S0 * (1.f/(float)D_);
  float var = SS * (1.f/(float)D_) - mu*mu;
  float inv = rsqrtf(var + 1e-5f);
  int idx = tid*4;
  float4 o;
  o.x = (xa[0]-mu)*inv*g[idx+0] + b[idx+0];
  o.y = (xa[1]-mu)*inv*g[idx+1] + b[idx+1];
  o.z = (xa[2]-mu)*inv*g[idx+2] + b[idx+2];
  o.w = (xa[3]-mu)*inv*g[idx+3] + b[idx+3];
  row[tid] = o;
}

// ----------------------------------------------------------------
// ws layout:
//   [0x000000,0x200000) cont f32[8192][64]
//   [0x200000,0x300000) c2s_WT hi/lo bf16 [2048][64] (path A only)
//   [0x300000,0x380000) s2c_WT hi/lo bf16 [64][2048] (encM only)
//   [0x400000,0x800000) eout f32[16384][64]
//   0x800000 gains | 0x808000 cnt | 0x809000 list | 0x849000 lw
//   [0x890000,0x8D0000) vinitF float[16*4096] (enc+dec GIF, CS=128)
//   0x900000 (4 MiB): WhT (enc) -> expert weights w1th/w1tl/w2th/w2tl -> decWT (dec)
//   0xD00000 (4 MiB): WlT (enc)  -> rates (dec path A, T*4 KiB from 0xD00000)
//   [0x1100000,0x3100000) encAh/encAl bf16 [8192][1024] each (enc pre-split, needs ws>=50 MiB)
// Enc scratch cur f32[8192][1024] = 32 MiB per H-chunk lives in d_out.
extern "C" void kernel_launch(void* const* d_in, const int* in_sizes, int n_in,
                              void* d_out, int out_size, void* d_ws, size_t ws_size,
                              hipStream_t stream) {
  (void)in_sizes; (void)n_in; (void)out_size;
  const float* embeds = (const float*)d_in[0];
  const int*   ids    = (const int*)d_in[1];
  const float* pros   = (const float*)d_in[2];
  const float* enc_W  = (const float*)d_in[3];
  const float* enc_b  = (const float*)d_in[4];
  const float* s2c_W  = (const float*)d_in[5];
  const float* s2c_b  = (const float*)d_in[6];
  const float* r_W1   = (const float*)d_in[7];
  const float* r_b1   = (const float*)d_in[8];
  const float* r_W2   = (const float*)d_in[9];
  const float* r_b2   = (const float*)d_in[10];
  const float* e_W1   = (const float*)d_in[11];
  const float* e_b1   = (const float*)d_in[12];
  const float* e_W2   = (const float*)d_in[13];
  const float* e_b2   = (const float*)d_in[14];
  const float* c2s_W  = (const float*)d_in[15];
  const float* c2s_b  = (const float*)d_in[16];
  const float* dec_W  = (const float*)d_in[17];
  const float* dec_b  = (const float*)d_in[18];
  const float* ln_g   = (const float*)d_in[19];
  const float* ln_b   = (const float*)d_in[20];

  char* ws = (char*)d_ws;
  float*          contp = (float*)ws;
  unsigned short* c2sWTh= (unsigned short*)(ws + (size_t)0x200000); // 256 KiB
  unsigned short* c2sWTl= (unsigned short*)(ws + (size_t)0x280000); // 256 KiB
  unsigned short* s2cWTh= (unsigned short*)(ws + (size_t)0x300000); // 256 KiB
  unsigned short* s2cWTl= (unsigned short*)(ws + (size_t)0x340000); // 256 KiB
  float*          eout  = (float*)(ws + (size_t)0x400000);
  float*          gains = (float*)(ws + (size_t)0x800000);
  int*            cnt   = (int*)(ws + (size_t)0x808000);
  unsigned int*   list  = (unsigned int*)(ws + (size_t)0x809000);
  float*          lw    = (float*)(ws + (size_t)0x849000);
  float*          vinitF= (float*)(ws + (size_t)0x890000);          // GIF f32 (256 KiB)
  unsigned short* WhT   = (unsigned short*)(ws + (size_t)0x900000); // -> expert w / decWT
  unsigned short* WlT   = (unsigned short*)(ws + (size_t)0xD00000); // -> rates
  unsigned short* encAh = (unsigned short*)(ws + (size_t)0x1100000); // 16 MiB (enc only)
  unsigned short* encAl = (unsigned short*)(ws + (size_t)0x2100000); // 16 MiB (enc only)
  unsigned short* decWT = WhT;
  unsigned short* rates = WlT;
  float*          ratSf = (float*)ws;              // fallback overlay of cont
  float*          cur   = (float*)d_out;           // enc scratch [8192][1024]

  // expert split-bf16 weights live in the WhT window between enc GEMM and k_transb
  unsigned short* w1th = WhT;                         // [8][1024][64] 1 MiB
  unsigned short* w1tl = w1th + (size_t)8*1024*64;    // 1 MiB
  unsigned short* w2th = w1tl + (size_t)8*1024*64;    // [8][64][1024] 1 MiB
  unsigned short* w2tl = w2th + (size_t)8*1024*64;    // 1 MiB (ends at 0xD00000)

  const int encM  = (ws_size >= (size_t)18*1024*1024) ? 1 : 0;
  const int encPA = (encM && ws_size >= (size_t)50*1024*1024) ? 1 : 0;
  const int T = (ws_size >= (size_t)46*1024*1024) ? 8192
              : (ws_size >= (size_t)30*1024*1024) ? 4096 : 0;

  k_gains<<<N_TOK/256, 256, 0, stream>>>(ids, pros, gains);
  k_zero<<<1, 64, 0, stream>>>(cnt);

  // ---- encoder: 2 H-chunks of 1024; GIF f32 at CS=128; MFMA s2c ----
  if (encM) {
    k_splitT<<<dim3(64, 32), 256, 0, stream>>>(enc_W, WhT, WlT);
    k_tsplit<<<dim3(2, 64, 1), 256, 0, stream>>>(s2c_W, s2cWTh, s2cWTl, 2048, 64);
    if (encPA)
      k_asplit<<<4096, 256, 0, stream>>>(embeds, encAh, encAl);
    for (int c = 0; c < 2; ++c) {
      if (encPA) {
        k_egemm3<<<dim3(8, 64), 256, 0, stream>>>(
            encAh, encAl, WhT + (size_t)c*1024*1024, WlT + (size_t)c*1024*1024,
            enc_b + c*1024, gains, cur);
      } else {
        k_egemm<<<dim3(8, 64), 256, 0, stream>>>(
            embeds, WhT + (size_t)c*1024*1024, WlT + (size_t)c*1024*1024,
            enc_b + c*1024, gains, cur);
      }
      k_gif_warm32<<<dim3(16, 16), 256, 0, stream>>>(cur, vinitF, 1024, 128, S_);
      k_gif_emit32<<<dim3(16, 16), 256, 0, stream>>>(cur, vinitF, 1024, 128, S_);
      k_s2cM<<<N_TOK/64, 256, 0, stream>>>(cur, s2cWTh, s2cWTl, (size_t)c*1024,
          contp, (c > 0), (c == 1) ? s2c_b : (const float*)nullptr);
    }
    // enc done reading WhT/WlT -> build expert split-bf16 weights in that window
    k_tsplit<<<dim3(32, 2, 8), 256, 0, stream>>>(e_W1, w1th, w1tl, 64, 1024);
    k_tsplit<<<dim3(2, 32, 8), 256, 0, stream>>>(e_W2, w2th, w2tl, 1024, 64);
  } else {
    for (int c = 0; c < 2; ++c) {
      k_genc<<<dim3(8, 64), 256, 0, stream>>>(
          embeds, D_, enc_W, H_, c*1024, enc_b, gains, cur, 1024, D_, 3);
      k_gif_warm32<<<dim3(16, 16), 256, 0, stream>>>(cur, vinitF, 1024, 128, S_);
      k_gif_emit32<<<dim3(16, 16), 256, 0, stream>>>(cur, vinitF, 1024, 128, S_);
      k_s2c<<<N_TOK/16, 256, 0, stream>>>(cur, 1024, 1024,
          s2c_W, (size_t)c*1024*64, contp, (c > 0),
          (c == 1) ? s2c_b : (const float*)nullptr);
    }
  }

  // ---- router: fused hidden + top-2 (f32) ----
  k_router2<<<N_TOK/16, 256, 0, stream>>>(contp, r_W1, r_b1, r_W2, r_b2,
                                          gains, cnt, list, lw);

  if (encM) {
    k_expmfma<<<dim3(128, 8), 256, 0, stream>>>(contp, list, lw, cnt,
        w1th, w1tl, e_b1, w2th, w2tl, e_b2, eout);
  } else {
    k_expgrp<<<dim3(128, 8), 256, 0, stream>>>(contp, list, lw, cnt,
        e_W1, e_b1, e_W2, e_b2, eout);
  }

  if (T > 0) {
    // ---- decoder path A: bf16 MFMA; GIF f32 at CS=128 ----
    k_transb<<<dim3(32, 64), 256, 0, stream>>>(dec_W, decWT, H_, D_);
    k_tsplit<<<dim3(64, 2, 1), 256, 0, stream>>>(c2s_W, c2sWTh, c2sWTl, 64, H_);
    for (int tok0 = 0; tok0 < N_TOK; tok0 += T) {
      k_c2sM<<<dim3(H_/128, T/128), 256, 0, stream>>>(eout + (size_t)tok0*128,
          c2sWTh, c2sWTl, c2s_b, rates);
      float* cur2 = (float*)d_out + (size_t)tok0*D_;
      k_dgemm<<<dim3(D_/128, T/128), 256, 0, stream>>>(
          rates, decWT, dec_b, gains + tok0, cur2);
      int channels = (T/2048)*1024;
      k_gif_warm32<<<dim3(channels/256, 16), 256, 0, stream>>>(cur2, vinitF, D_, 128, S_);
      k_gif_emit32<<<dim3(channels/256, 16), 256, 0, stream>>>(cur2, vinitF, D_, 128, S_);
      k_ln<<<T, 256, 0, stream>>>(cur2, ln_g, ln_b);
    }
  } else {
    // ---- decoder fallback: f32 SIMT, 2 halves x 8 K-slices ----
    for (int hb = 0; hb < 2; ++hb) {
      float* cur2 = (float*)d_out + (size_t)hb*4096*D_;
      for (int kh = 0; kh < 8; ++kh) {
        k_c2sS<<<4096/8, 256, 0, stream>>>(eout + (size_t)hb*4096*128,
            c2s_W, kh*256, c2s_b, ratSf);
        int mode = (kh == 0) ? 0 : ((kh < 7) ? 1 : 2);
        k_genc<<<dim3(8, 32), 256, 0, stream>>>(
            ratSf, 256, dec_W + (size_t)kh*256*D_, D_, 0, dec_b,
            gains + hb*4096, cur2, D_, 256, mode);
      }
      k_gif_warm32<<<dim3(8, 16), 256, 0, stream>>>(cur2, vinitF, D_, 128, S_);
      k_gif_emit32<<<dim3(8, 16), 256, 0, stream>>>(cur2, vinitF, D_, 128, S_);
      k_ln<<<4096, 256, 0, stream>>>(cur2, ln_g, ln_b);
    }
  }
}

// Round 15
// 538.892 us; speedup vs baseline: 1.2567x; 1.0667x over previous
//
#include <hip/hip_runtime.h>
#include <math.h>

#define B_ 4
#define S_ 2048
#define D_ 1024
#define H_ 2048
#define N_TOK 8192
#define HALO 160
#define VOCAB_ 32000

typedef short bf16x8 __attribute__((ext_vector_type(8)));
typedef float f32x4 __attribute__((ext_vector_type(4)));

__device__ __forceinline__ float sigf(float x) {
  return 1.0f / (1.0f + __expf(-x));
}
__device__ __forceinline__ float bf2f(unsigned short u) {
  union { unsigned int i; float f; } x; x.i = ((unsigned int)u) << 16; return x.f;
}
__device__ __forceinline__ unsigned short f2bf(float f) {
  union { float f; unsigned int i; } x; x.f = f;
  unsigned int r = x.i + 0x7fffu + ((x.i >> 16) & 1u);
  return (unsigned short)(r >> 16);
}

// ---------------------------------------------------------------- gains (f32 tanh) + cnt zero (block 0)
__global__ __launch_bounds__(256) void k_gains(const int* __restrict__ ids,
    const float* __restrict__ table, float* __restrict__ gains, int* __restrict__ cnt) {
  int i = blockIdx.x*256 + threadIdx.x;
  if (blockIdx.x == 0 && threadIdx.x < 8) cnt[threadIdx.x] = 0;
  int id = ids[i];
  id = id < 0 ? 0 : (id >= VOCAB_ ? VOCAB_-1 : id);
  gains[i] = 1.0f + tanhf(table[id]);
}

// ---------------------------------------------------------------- f32 SIMT GEMM (fallback enc/dec)
__global__ __launch_bounds__(256) void k_genc(
    const float* __restrict__ A, int lda,
    const float* __restrict__ W, int ldw, int c0,
    const float* __restrict__ bias,
    const float* __restrict__ gains,
    float* __restrict__ C, int ldc,
    int K, int mode)
{
  __shared__ float As2[16][132];
  __shared__ float Bs[16][128];
  const int tid = threadIdx.x;
  const int tx = tid & 15;
  const int ty = tid >> 4;
  const int bm = blockIdx.y * 128;
  const int bn = blockIdx.x * 128;

  double acc[8][8];
  float part[8][8];
  #pragma unroll
  for (int i = 0; i < 8; ++i)
    #pragma unroll
    for (int j = 0; j < 8; ++j) { acc[i][j] = 0.0; part[i][j] = 0.f; }

  const int e = tid * 8;
  const int ar = e >> 4, ak = e & 15;
  const int bk = e >> 7, bc = e & 127;

  for (int k0 = 0; k0 < K; k0 += 16) {
    {
      const float* pa = A + (size_t)(bm + ar)*lda + k0 + ak;
      float4 v0 = *(const float4*)pa;
      float4 v1 = *(const float4*)(pa + 4);
      As2[ak+0][ar] = v0.x; As2[ak+1][ar] = v0.y;
      As2[ak+2][ar] = v0.z; As2[ak+3][ar] = v0.w;
      As2[ak+4][ar] = v1.x; As2[ak+5][ar] = v1.y;
      As2[ak+6][ar] = v1.z; As2[ak+7][ar] = v1.w;
    }
    {
      const float* pw = W + (size_t)(k0 + bk)*ldw + c0 + bn + bc;
      *(float4*)&Bs[bk][bc]   = *(const float4*)pw;
      *(float4*)&Bs[bk][bc+4] = *(const float4*)(pw + 4);
    }
    __syncthreads();
    #pragma unroll
    for (int kk = 0; kk < 16; ++kk) {
      float a8[8], b8[8];
      *(float4*)&a8[0] = *(const float4*)&As2[kk][ty*8];
      *(float4*)&a8[4] = *(const float4*)&As2[kk][ty*8+4];
      *(float4*)&b8[0] = *(const float4*)&Bs[kk][tx*8];
      *(float4*)&b8[4] = *(const float4*)&Bs[kk][tx*8+4];
      #pragma unroll
      for (int i = 0; i < 8; ++i)
        #pragma unroll
        for (int j = 0; j < 8; ++j)
          part[i][j] += a8[i]*b8[j];
    }
    __syncthreads();
    #pragma unroll
    for (int i = 0; i < 8; ++i)
      #pragma unroll
      for (int j = 0; j < 8; ++j) { acc[i][j] += (double)part[i][j]; part[i][j] = 0.f; }
  }

  #pragma unroll
  for (int i = 0; i < 8; ++i) {
    const int row = bm + ty*8 + i;
    const double g = (mode >= 2) ? (double)gains[row] : 0.0;
    #pragma unroll
    for (int j = 0; j < 8; ++j) {
      const int col = bn + tx*8 + j;
      const size_t idx = (size_t)row*ldc + col;
      if (mode == 0)      C[idx] = (float)acc[i][j];
      else if (mode == 1) C[idx] += (float)acc[i][j];
      else if (mode == 2) C[idx] = (float)(g*((double)C[idx] + acc[i][j]) + (double)bias[c0+col]);
      else                C[idx] = (float)(g*acc[i][j] + (double)bias[c0+col]);
    }
  }
}

// ---------------------------------------------------------------- transpose+split enc_W [1024][2048] f32 -> WhT/WlT [2048][1024] bf16
__global__ __launch_bounds__(256) void k_splitT(const float* __restrict__ in,
    unsigned short* __restrict__ outh, unsigned short* __restrict__ outl) {
  __shared__ unsigned short th[32][33];
  __shared__ unsigned short tl[32][33];
  int c0 = blockIdx.x*32, r0 = blockIdx.y*32;
  int tx = threadIdx.x & 31, ty = threadIdx.x >> 5;
  #pragma unroll
  for (int i = 0; i < 32; i += 8) {
    float x = in[(size_t)(r0+ty+i)*H_ + (c0+tx)];
    unsigned short h = f2bf(x);
    th[ty+i][tx] = h;
    tl[ty+i][tx] = f2bf(x - bf2f(h));
  }
  __syncthreads();
  #pragma unroll
  for (int i = 0; i < 32; i += 8) {
    outh[(size_t)(c0+ty+i)*D_ + (r0+tx)] = th[tx][ty+i];
    outl[(size_t)(c0+ty+i)*D_ + (r0+tx)] = tl[tx][ty+i];
  }
}

// ---------------------------------------------------------------- generic batched transpose+split: in [Z][R][C] f32 -> oh/ol [Z][C][R] bf16
__global__ __launch_bounds__(256) void k_tsplit(const float* __restrict__ in,
    unsigned short* __restrict__ oh, unsigned short* __restrict__ ol,
    int R, int C) {
  __shared__ unsigned short th[32][33];
  __shared__ unsigned short tl[32][33];
  const size_t mat = (size_t)R*C;
  in += (size_t)blockIdx.z * mat;
  oh += (size_t)blockIdx.z * mat;
  ol += (size_t)blockIdx.z * mat;
  int c0 = blockIdx.x*32, r0 = blockIdx.y*32;
  int tx = threadIdx.x & 31, ty = threadIdx.x >> 5;
  #pragma unroll
  for (int i = 0; i < 32; i += 8) {
    float x = in[(size_t)(r0+ty+i)*C + (c0+tx)];
    unsigned short h = f2bf(x);
    th[ty+i][tx] = h;
    tl[ty+i][tx] = f2bf(x - bf2f(h));
  }
  __syncthreads();
  #pragma unroll
  for (int i = 0; i < 32; i += 8) {
    oh[(size_t)(c0+ty+i)*R + (r0+tx)] = th[tx][ty+i];
    ol[(size_t)(c0+ty+i)*R + (r0+tx)] = tl[tx][ty+i];
  }
}

// ---------------------------------------------------------------- row-major f32 -> bf16 hi/lo split (no transpose), 8 elems/thread
__global__ __launch_bounds__(256) void k_asplit(const float* __restrict__ in,
    unsigned short* __restrict__ oh, unsigned short* __restrict__ ol) {
  const size_t i = ((size_t)blockIdx.x*256 + threadIdx.x) * 8;
  float4 v0 = *(const float4*)(in + i);
  float4 v1 = *(const float4*)(in + i + 4);
  float xs[8] = {v0.x, v0.y, v0.z, v0.w, v1.x, v1.y, v1.z, v1.w};
  unsigned int hp[4], lp[4];
  #pragma unroll
  for (int t = 0; t < 4; ++t) {
    unsigned short h0 = f2bf(xs[2*t]);
    unsigned short h1 = f2bf(xs[2*t+1]);
    unsigned short l0 = f2bf(xs[2*t]   - bf2f(h0));
    unsigned short l1 = f2bf(xs[2*t+1] - bf2f(h1));
    hp[t] = (unsigned)h0 | ((unsigned)h1 << 16);
    lp[t] = (unsigned)l0 | ((unsigned)l1 << 16);
  }
  *(uint4*)(oh + i) = make_uint4(hp[0], hp[1], hp[2], hp[3]);
  *(uint4*)(ol + i) = make_uint4(lp[0], lp[1], lp[2], lp[3]);
}

// ---------------------------------------------------------------- enc MFMA GEMM (legacy, in-kernel A split) — fallback tier
__global__ __launch_bounds__(256) void k_egemm(
    const float* __restrict__ A,              // embeds f32 [8192][1024]
    const unsigned short* __restrict__ Bh,    // WhT + chunk offset, [1024][1024] bf16
    const unsigned short* __restrict__ Bl,
    const float* __restrict__ bias,           // enc_b + chunk offset
    const float* __restrict__ gains,
    float* __restrict__ C)                    // cur [8192][1024]
{
  __shared__ __align__(16) unsigned short Ahs[128*40];
  __shared__ __align__(16) unsigned short Als[128*40];
  __shared__ __align__(16) unsigned short Bhs[128*40];
  __shared__ __align__(16) unsigned short Bls[128*40];
  const int tid  = threadIdx.x;
  const int lane = tid & 63;
  const int wave = tid >> 6;
  const int wm = (wave >> 1) * 64;
  const int wn = (wave & 1) * 64;
  const int bm = blockIdx.y * 128;
  const int bn = blockIdx.x * 128;
  const int fml = lane & 15;
  const int q  = lane >> 4;
  const int r0a  = tid >> 2;
  const int sseg = tid & 3;

  f32x4 acc[4][4] = {};

  for (int k0 = 0; k0 < 1024; k0 += 32) {
    #pragma unroll
    for (int half = 0; half < 2; ++half) {
      int r = r0a + half*64;
      const float* pa = A + (size_t)(bm + r)*1024 + k0 + sseg*8;
      float4 v0 = *(const float4*)pa;
      float4 v1 = *(const float4*)(pa + 4);
      float xs[8] = {v0.x, v0.y, v0.z, v0.w, v1.x, v1.y, v1.z, v1.w};
      unsigned int hp[4], lp[4];
      #pragma unroll
      for (int t = 0; t < 4; ++t) {
        unsigned short h0 = f2bf(xs[2*t]);
        unsigned short h1 = f2bf(xs[2*t+1]);
        unsigned short l0 = f2bf(xs[2*t]   - bf2f(h0));
        unsigned short l1 = f2bf(xs[2*t+1] - bf2f(h1));
        hp[t] = (unsigned)h0 | ((unsigned)h1 << 16);
        lp[t] = (unsigned)l0 | ((unsigned)l1 << 16);
      }
      *(uint4*)(&Ahs[r*40 + sseg*8]) = make_uint4(hp[0], hp[1], hp[2], hp[3]);
      *(uint4*)(&Als[r*40 + sseg*8]) = make_uint4(lp[0], lp[1], lp[2], lp[3]);
      *(uint4*)(&Bhs[r*40 + sseg*8]) = *(const uint4*)(Bh + (size_t)(bn + r)*1024 + k0 + sseg*8);
      *(uint4*)(&Bls[r*40 + sseg*8]) = *(const uint4*)(Bl + (size_t)(bn + r)*1024 + k0 + sseg*8);
    }
    __syncthreads();
    bf16x8 afh[4], afl[4], bfh[4], bfl[4];
    #pragma unroll
    for (int i = 0; i < 4; ++i) {
      afh[i] = *(const bf16x8*)(&Ahs[(wm + i*16 + fml)*40 + q*8]);
      afl[i] = *(const bf16x8*)(&Als[(wm + i*16 + fml)*40 + q*8]);
    }
    #pragma unroll
    for (int j = 0; j < 4; ++j) {
      bfh[j] = *(const bf16x8*)(&Bhs[(wn + j*16 + fml)*40 + q*8]);
      bfl[j] = *(const bf16x8*)(&Bls[(wn + j*16 + fml)*40 + q*8]);
    }
    #pragma unroll
    for (int i = 0; i < 4; ++i)
      #pragma unroll
      for (int j = 0; j < 4; ++j) {
        acc[i][j] = __builtin_amdgcn_mfma_f32_16x16x32_bf16(afl[i], bfh[j], acc[i][j], 0, 0, 0);
        acc[i][j] = __builtin_amdgcn_mfma_f32_16x16x32_bf16(afh[i], bfl[j], acc[i][j], 0, 0, 0);
        acc[i][j] = __builtin_amdgcn_mfma_f32_16x16x32_bf16(afh[i], bfh[j], acc[i][j], 0, 0, 0);
      }
    __syncthreads();
  }
  #pragma unroll
  for (int i = 0; i < 4; ++i) {
    #pragma unroll
    for (int j = 0; j < 4; ++j) {
      int col = bn + wn + j*16 + fml;
      float bv = bias[col];
      #pragma unroll
      for (int r = 0; r < 4; ++r) {
        int row = bm + wm + i*16 + q*4 + r;   // C/D: col=lane&15, row=quad*4+reg
        C[(size_t)row*D_ + col] = gains[row]*acc[i][j][r] + bv;
      }
    }
  }
}

// ---------------------------------------------------------------- enc MFMA GEMM v3: pre-split A, B chunk [1024][1024], C ld=1024, XCD swizzle
__global__ __launch_bounds__(256) void k_egemm3(
    const unsigned short* __restrict__ Ah, const unsigned short* __restrict__ Al, // [8192][1024]
    const unsigned short* __restrict__ Bh, const unsigned short* __restrict__ Bl, // [1024][1024]
    const float* __restrict__ bias,           // enc_b + chunk offset
    const float* __restrict__ gains,
    float* __restrict__ C)                    // cur [8192][1024]
{
  __shared__ __align__(16) unsigned short Ahs[128*40];
  __shared__ __align__(16) unsigned short Als[128*40];
  __shared__ __align__(16) unsigned short Bhs[128*40];
  __shared__ __align__(16) unsigned short Bls[128*40];
  const int tid  = threadIdx.x;
  const int lane = tid & 63;
  const int wave = tid >> 6;
  const int wm = (wave >> 1) * 64;
  const int wn = (wave & 1) * 64;
  // XCD-aware bijective swizzle: nwg = 8*64 = 512 (%8==0)
  const int flat = blockIdx.y * 8 + blockIdx.x;
  const int swz  = (flat & 7) * 64 + (flat >> 3);
  const int bn = (swz & 7) * 128;
  const int bm = (swz >> 3) * 128;
  const int fml = lane & 15;
  const int q  = lane >> 4;
  const int r0a  = tid >> 2;
  const int sseg = tid & 3;

  f32x4 acc[4][4] = {};

  for (int k0 = 0; k0 < 1024; k0 += 32) {
    #pragma unroll
    for (int half = 0; half < 2; ++half) {
      int r = r0a + half*64;
      *(uint4*)(&Ahs[r*40 + sseg*8]) = *(const uint4*)(Ah + (size_t)(bm + r)*1024 + k0 + sseg*8);
      *(uint4*)(&Als[r*40 + sseg*8]) = *(const uint4*)(Al + (size_t)(bm + r)*1024 + k0 + sseg*8);
      *(uint4*)(&Bhs[r*40 + sseg*8]) = *(const uint4*)(Bh + (size_t)(bn + r)*1024 + k0 + sseg*8);
      *(uint4*)(&Bls[r*40 + sseg*8]) = *(const uint4*)(Bl + (size_t)(bn + r)*1024 + k0 + sseg*8);
    }
    __syncthreads();
    bf16x8 afh[4], afl[4], bfh[4], bfl[4];
    #pragma unroll
    for (int i = 0; i < 4; ++i) {
      afh[i] = *(const bf16x8*)(&Ahs[(wm + i*16 + fml)*40 + q*8]);
      afl[i] = *(const bf16x8*)(&Als[(wm + i*16 + fml)*40 + q*8]);
    }
    #pragma unroll
    for (int j = 0; j < 4; ++j) {
      bfh[j] = *(const bf16x8*)(&Bhs[(wn + j*16 + fml)*40 + q*8]);
      bfl[j] = *(const bf16x8*)(&Bls[(wn + j*16 + fml)*40 + q*8]);
    }
    #pragma unroll
    for (int i = 0; i < 4; ++i)
      #pragma unroll
      for (int j = 0; j < 4; ++j) {
        acc[i][j] = __builtin_amdgcn_mfma_f32_16x16x32_bf16(afl[i], bfh[j], acc[i][j], 0, 0, 0);
        acc[i][j] = __builtin_amdgcn_mfma_f32_16x16x32_bf16(afh[i], bfl[j], acc[i][j], 0, 0, 0);
        acc[i][j] = __builtin_amdgcn_mfma_f32_16x16x32_bf16(afh[i], bfh[j], acc[i][j], 0, 0, 0);
      }
    __syncthreads();
  }
  #pragma unroll
  for (int i = 0; i < 4; ++i) {
    #pragma unroll
    for (int j = 0; j < 4; ++j) {
      int col = bn + wn + j*16 + fml;
      float bv = bias[col];
      #pragma unroll
      for (int r = 0; r < 4; ++r) {
        int row = bm + wm + i*16 + q*4 + r;
        C[(size_t)row*D_ + col] = gains[row]*acc[i][j][r] + bv;
      }
    }
  }
}

// ---------------------------------------------------------------- GIF scan, f32 fast path (enc + dec)
__global__ __launch_bounds__(256) void k_gif_warm32(const float* __restrict__ buf,
    float* __restrict__ vinit, int Wd, int CS, int Stot)
{
  int c = blockIdx.x*256 + threadIdx.x;
  int channels = gridDim.x*256;
  int chunk = blockIdx.y;
  int b = c / Wd, h = c - b*Wd;
  int s_emit = chunk*CS;
  int s0 = s_emit - HALO; if (s0 < 0) s0 = 0;
  const float* p = buf + (size_t)b*Stot*Wd + h;
  float v = 0.f;
  for (int sg = s0; sg < s_emit; sg += 8) {
    float cv[8];
    #pragma unroll
    for (int i = 0; i < 8; ++i) cv[i] = p[(size_t)(sg+i)*Wd];
    #pragma unroll
    for (int i = 0; i < 8; ++i) {
      v = 0.9f*v + cv[i];
      float s = 1.0f/(1.0f + __expf(-4.0f*(v - 1.0f)));
      v -= s;
    }
  }
  vinit[(size_t)chunk*channels + c] = v;
}

__global__ __launch_bounds__(256) void k_gif_emit32(float* __restrict__ buf,
    const float* __restrict__ vinit, int Wd, int CS, int Stot)
{
  int c = blockIdx.x*256 + threadIdx.x;
  int channels = gridDim.x*256;
  int chunk = blockIdx.y;
  int b = c / Wd, h = c - b*Wd;
  float* p = buf + (size_t)b*Stot*Wd + h + (size_t)chunk*CS*Wd;
  float v = vinit[(size_t)chunk*channels + c];
  float cv[8], nv[8] = {0,0,0,0,0,0,0,0};
  #pragma unroll
  for (int i = 0; i < 8; ++i) cv[i] = p[(size_t)i*Wd];
  for (int sg = 0; sg < CS; sg += 8) {
    float sp[8];
    #pragma unroll
    for (int i = 0; i < 8; ++i) {
      v = 0.9f*v + cv[i];
      float s = 1.0f/(1.0f + __expf(-4.0f*(v - 1.0f)));
      v -= s; sp[i] = s;
    }
    if (sg + 8 < CS) {
      #pragma unroll
      for (int i = 0; i < 8; ++i) nv[i] = p[(size_t)(sg+8+i)*Wd];
    }
    #pragma unroll
    for (int i = 0; i < 8; ++i) p[(size_t)(sg+i)*Wd] = sp[i];
    #pragma unroll
    for (int i = 0; i < 8; ++i) cv[i] = nv[i];
  }
}

// ---------------------------------------------------------------- s2c split-bf16 MFMA, K-split x4 + atomic accum
// cont[8192][64] += cur[8192][1024] @ s2c_W chunk; grid (N_TOK/64, 4)
__global__ __launch_bounds__(256) void k_s2cM(
    const float* __restrict__ A,                // cur f32 [8192][1024]
    const unsigned short* __restrict__ WTh,     // [64][2048] bf16 hi
    const unsigned short* __restrict__ WTl,     // [64][2048] bf16 lo
    size_t woff,                                // chunk col offset (c*1024)
    float* __restrict__ out,                    // cont [8192][64], pre-zeroed
    const float* __restrict__ bias2)            // added once by kh==0 blocks when non-null
{
  __shared__ __align__(16) unsigned short Ahs[64*40], Als[64*40];
  __shared__ __align__(16) unsigned short Bhs[64*40], Bls[64*40];
  const int tid  = threadIdx.x;
  const int lane = tid & 63;
  const int wave = tid >> 6;
  const int wm = (wave >> 1) * 32;
  const int wn = (wave & 1) * 32;
  const int bm = blockIdx.x * 64;
  const int kh = blockIdx.y;          // 0..3, K-range [kh*256, kh*256+256)
  const int kbeg = kh * 256;
  const int fml = lane & 15;
  const int q  = lane >> 4;
  const int r0a  = tid >> 2;   // 0..63
  const int sseg = tid & 3;

  f32x4 acc[2][2] = {};

  for (int k0 = kbeg; k0 < kbeg + 256; k0 += 32) {
    {
      const float* pa = A + (size_t)(bm + r0a)*1024 + k0 + sseg*8;
      float4 v0 = *(const float4*)pa;
      float4 v1 = *(const float4*)(pa + 4);
      float xs[8] = {v0.x, v0.y, v0.z, v0.w, v1.x, v1.y, v1.z, v1.w};
      unsigned int hp[4], lp[4];
      #pragma unroll
      for (int t = 0; t < 4; ++t) {
        unsigned short h0 = f2bf(xs[2*t]);
        unsigned short h1 = f2bf(xs[2*t+1]);
        unsigned short l0 = f2bf(xs[2*t]   - bf2f(h0));
        unsigned short l1 = f2bf(xs[2*t+1] - bf2f(h1));
        hp[t] = (unsigned)h0 | ((unsigned)h1 << 16);
        lp[t] = (unsigned)l0 | ((unsigned)l1 << 16);
      }
      *(uint4*)(&Ahs[r0a*40 + sseg*8]) = make_uint4(hp[0], hp[1], hp[2], hp[3]);
      *(uint4*)(&Als[r0a*40 + sseg*8]) = make_uint4(lp[0], lp[1], lp[2], lp[3]);
      *(uint4*)(&Bhs[r0a*40 + sseg*8]) = *(const uint4*)(WTh + (size_t)r0a*2048 + woff + k0 + sseg*8);
      *(uint4*)(&Bls[r0a*40 + sseg*8]) = *(const uint4*)(WTl + (size_t)r0a*2048 + woff + k0 + sseg*8);
    }
    __syncthreads();
    bf16x8 afh[2], afl[2], bfh[2], bfl[2];
    #pragma unroll
    for (int i = 0; i < 2; ++i) {
      afh[i] = *(const bf16x8*)(&Ahs[(wm + i*16 + fml)*40 + q*8]);
      afl[i] = *(const bf16x8*)(&Als[(wm + i*16 + fml)*40 + q*8]);
    }
    #pragma unroll
    for (int j = 0; j < 2; ++j) {
      bfh[j] = *(const bf16x8*)(&Bhs[(wn + j*16 + fml)*40 + q*8]);
      bfl[j] = *(const bf16x8*)(&Bls[(wn + j*16 + fml)*40 + q*8]);
    }
    #pragma unroll
    for (int i = 0; i < 2; ++i)
      #pragma unroll
      for (int j = 0; j < 2; ++j) {
        acc[i][j] = __builtin_amdgcn_mfma_f32_16x16x32_bf16(afl[i], bfh[j], acc[i][j], 0, 0, 0);
        acc[i][j] = __builtin_amdgcn_mfma_f32_16x16x32_bf16(afh[i], bfl[j], acc[i][j], 0, 0, 0);
        acc[i][j] = __builtin_amdgcn_mfma_f32_16x16x32_bf16(afh[i], bfh[j], acc[i][j], 0, 0, 0);
      }
    __syncthreads();
  }
  #pragma unroll
  for (int j = 0; j < 2; ++j) {
    const int col = wn + j*16 + fml;   // 0..63
    const float bv = (bias2 && kh == 0) ? bias2[col] : 0.f;
    #pragma unroll
    for (int i = 0; i < 2; ++i) {
      #pragma unroll
      for (int r = 0; r < 4; ++r) {
        const int row = bm + wm + i*16 + q*4 + r;
        atomicAdd(&out[(size_t)row*64 + col], acc[i][j][r] + bv);
      }
    }
  }
}

// ---------------------------------------------------------------- s2c partial, f32 FMA — fallback tier only
__global__ __launch_bounds__(256) void k_s2c(const float* __restrict__ Sp, int ldS, int KH,
    const float* __restrict__ W, size_t woff, float* __restrict__ out, int accum,
    const float* __restrict__ bias2) {
  __shared__ float As_[16][17];
  __shared__ float Ws_[16][68];
  const int bm = blockIdx.x * 16;
  const int tid = threadIdx.x;
  const int rt = tid >> 4;   // row 0..15
  const int ct = tid & 15;   // col group 0..15
  float acc[4] = {};
  for (int k0 = 0; k0 < KH; k0 += 16) {
    As_[tid >> 4][tid & 15] = Sp[(size_t)(bm + (tid >> 4))*ldS + k0 + (tid & 15)];
    #pragma unroll
    for (int i = 0; i < 4; ++i) {
      int e = tid + i*256;
      Ws_[e >> 6][e & 63] = W[woff + (size_t)(k0 + (e >> 6))*64 + (e & 63)];
    }
    __syncthreads();
    #pragma unroll
    for (int kk = 0; kk < 16; ++kk) {
      float a = As_[rt][kk];
      #pragma unroll
      for (int j = 0; j < 4; ++j) acc[j] += a * Ws_[kk][ct*4+j];
    }
    __syncthreads();
  }
  #pragma unroll
  for (int j = 0; j < 4; ++j) {
    size_t idx = ((size_t)bm + rt)*64 + ct*4 + j;
    float a = acc[j];
    if (accum) {
      float v = out[idx] + a;
      if (bias2) v = v + bias2[ct*4+j]; // bias fold on final pass
      out[idx] = v;
    } else out[idx] = a;
  }
}

// ---------------------------------------------------------------- fused router (f32): hidden in LDS, logits, top-2, block-agg append
__global__ __launch_bounds__(256) void k_router2(const float* __restrict__ cont,
    const float* __restrict__ rW1, const float* __restrict__ rb1,
    const float* __restrict__ rW2, const float* __restrict__ rb2,
    const float* __restrict__ gains,
    int* __restrict__ cnt, unsigned int* __restrict__ list, float* __restrict__ lw)
{
  __shared__ float W1s[64*64];
  __shared__ float W2s[64*8];
  __shared__ float b2s[8];
  __shared__ float cs[16][64];
  __shared__ float hs[16][65];
  __shared__ int bcnt[8];
  __shared__ int bbase[8];
  const int tid = threadIdx.x;
  const int j  = tid & 63;
  const int tg = tid >> 6;           // 0..3
  const int n0 = blockIdx.x * 16;
  for (int i = tid; i < 64*64; i += 256) W1s[i] = rW1[i];
  for (int i = tid; i < 64*8; i += 256)  W2s[i] = rW2[i];
  if (tid < 8) { b2s[tid] = rb2[tid]; bcnt[tid] = 0; }
  #pragma unroll
  for (int i = 0; i < 4; ++i) {
    int e = tid + i*256;             // 1024 = 16 tokens x 64
    cs[e >> 6][e & 63] = cont[(size_t)(n0 + (e >> 6))*64 + (e & 63)];
  }
  __syncthreads();
  {
    const float b1 = rb1[j];
    float t0 = b1, t1 = b1, t2 = b1, t3 = b1;
    #pragma unroll
    for (int m = 0; m < 64; ++m) {
      const float w = W1s[m*64 + j];
      t0 += cs[tg*4+0][m] * w;
      t1 += cs[tg*4+1][m] * w;
      t2 += cs[tg*4+2][m] * w;
      t3 += cs[tg*4+3][m] * w;
    }
    hs[tg*4+0][j] = tanhf(t0);
    hs[tg*4+1][j] = tanhf(t1);
    hs[tg*4+2][j] = tanhf(t2);
    hs[tg*4+3][j] = tanhf(t3);
  }
  __syncthreads();
  int i1 = 0, i2 = 0, p1l = 0, p2l = 0;
  float w1 = 0.f;
  if (tid < 16) {
    const int n = n0 + tid;
    float lg[8];
    #pragma unroll
    for (int e = 0; e < 8; ++e) lg[e] = b2s[e];
    #pragma unroll 8
    for (int jj = 0; jj < 64; ++jj) {
      float t = hs[tid][jj];
      #pragma unroll
      for (int e = 0; e < 8; ++e) lg[e] += t * W2s[jj*8 + e];
    }
    float g = gains[n];
    #pragma unroll
    for (int e = 0; e < 8; ++e) lg[e] *= g;
    float m1 = lg[0];
    #pragma unroll
    for (int e = 1; e < 8; ++e) if (lg[e] > m1) { m1 = lg[e]; i1 = e; }
    i2 = (i1 == 0) ? 1 : 0; float m2 = lg[i2];
    #pragma unroll
    for (int e = 0; e < 8; ++e) if (e != i1 && lg[e] > m2) { m2 = lg[e]; i2 = e; }
    w1 = 1.0f / (1.0f + __expf(m2 - m1));
    p1l = atomicAdd(&bcnt[i1], 1);
    p2l = atomicAdd(&bcnt[i2], 1);
  }
  __syncthreads();
  if (tid < 8) bbase[tid] = bcnt[tid] ? atomicAdd(&cnt[tid], bcnt[tid]) : 0;
  __syncthreads();
  if (tid < 16) {
    const int n = n0 + tid;
    const int p1 = bbase[i1] + p1l;
    list[i1*8192 + p1] = ((unsigned)n << 1);
    lw[i1*8192 + p1] = w1;
    const int p2 = bbase[i2] + p2l;
    list[i2*8192 + p2] = ((unsigned)n << 1) | 1u;
    lw[i2*8192 + p2] = 1.0f - w1;
  }
}

// ---------------------------------------------------------------- grouped experts — f32 SIMT (fallback tier only)
__global__ __launch_bounds__(256) void k_expgrp(
    const float* __restrict__ cont,
    const unsigned int* __restrict__ list, const float* __restrict__ lw,
    const int* __restrict__ cnt,
    const float* __restrict__ eW1, const float* __restrict__ eb1,
    const float* __restrict__ eW2, const float* __restrict__ eb2,
    float* __restrict__ eout)
{
  const int e = blockIdx.y;
  const int t0 = blockIdx.x * 64;
  const int ce = cnt[e];
  if (t0 >= ce) return;
  const int nt = (ce - t0 < 64) ? (ce - t0) : 64;
  __shared__ float ct[64][65];
  __shared__ float w1b[64][65];
  __shared__ float hbl[64][65];
  __shared__ float w2b[64][65];
  __shared__ unsigned int sl[64];
  __shared__ float swt[64];
  const int tid = threadIdx.x;
  if (tid < 64) {
    if (tid < nt) {
      sl[tid]  = list[e*8192 + t0 + tid];
      swt[tid] = lw[e*8192 + t0 + tid];
    } else { sl[tid] = 0; swt[tid] = 0.f; }
  }
  __syncthreads();
  for (int f = tid; f < 64*64; f += 256) {
    int r = f >> 6, m = f & 63;
    ct[r][m] = (r < nt) ? cont[(size_t)(sl[r] >> 1)*64 + m] : 0.f;
  }
  const float* W1 = eW1 + (size_t)e*64*1024;
  const float* W2 = eW2 + (size_t)e*1024*64;
  const float* B1 = eb1 + (size_t)e*1024;
  const int rt = tid >> 4, c16 = tid & 15;
  float outa[4][4] = {};
  for (int hc = 0; hc < 1024; hc += 64) {
    __syncthreads();
    for (int f = tid; f < 64*64; f += 256) {
      int m = f >> 6, j = f & 63;
      w1b[m][j] = W1[(size_t)m*1024 + hc + j];
      w2b[m][j] = W2[(size_t)(hc + m)*64 + j];
    }
    __syncthreads();
    float h4[4][4];
    #pragma unroll
    for (int i = 0; i < 4; ++i) {
      #pragma unroll
      for (int j = 0; j < 4; ++j) h4[i][j] = B1[hc + c16*4 + j];
    }
    #pragma unroll 16
    for (int m = 0; m < 64; ++m) {
      float a4[4], b4[4];
      #pragma unroll
      for (int i = 0; i < 4; ++i) a4[i] = ct[rt*4+i][m];
      #pragma unroll
      for (int j = 0; j < 4; ++j) b4[j] = w1b[m][c16*4+j];
      #pragma unroll
      for (int i = 0; i < 4; ++i)
        #pragma unroll
        for (int j = 0; j < 4; ++j) h4[i][j] += a4[i]*b4[j];
    }
    #pragma unroll
    for (int i = 0; i < 4; ++i)
      #pragma unroll
      for (int j = 0; j < 4; ++j)
        hbl[rt*4+i][c16*4+j] = fmaxf(h4[i][j], 0.f);
    __syncthreads();
    #pragma unroll 16
    for (int j = 0; j < 64; ++j) {
      float a4[4], b4[4];
      #pragma unroll
      for (int i = 0; i < 4; ++i) a4[i] = hbl[rt*4+i][j];
      #pragma unroll
      for (int nn = 0; nn < 4; ++nn) b4[nn] = w2b[j][c16*4+nn];
      #pragma unroll
      for (int i = 0; i < 4; ++i)
        #pragma unroll
        for (int nn = 0; nn < 4; ++nn) outa[i][nn] += a4[i]*b4[nn];
    }
  }
  #pragma unroll
  for (int i = 0; i < 4; ++i) {
    int r = rt*4 + i;
    if (r < nt) {
      float w = swt[r];
      #pragma unroll
      for (int nn = 0; nn < 4; ++nn) {
        int col = c16*4 + nn;
        eout[(size_t)sl[r]*64 + col] = w * (outa[i][nn] + eb2[(size_t)e*64 + col]);
      }
    }
  }
}

// ---------------------------------------------------------------- grouped experts — split-bf16 MFMA (e=blockIdx.y, spread all CUs)
__global__ __launch_bounds__(256) void k_expmfma(
    const float* __restrict__ cont,
    const unsigned int* __restrict__ list, const float* __restrict__ lw,
    const int* __restrict__ cnt,
    const unsigned short* __restrict__ w1h, const unsigned short* __restrict__ w1l, // [E][1024][64]
    const float* __restrict__ eb1,                                                  // [E][1024]
    const unsigned short* __restrict__ w2h, const unsigned short* __restrict__ w2l, // [E][64][1024]
    const float* __restrict__ eb2,                                                  // [E][64]
    float* __restrict__ eout)
{
  const int e  = blockIdx.y;
  const int t0 = blockIdx.x * 64;
  const int ce = cnt[e];
  if (t0 >= ce) return;
  const int nt = (ce - t0 < 64) ? (ce - t0) : 64;

  // stride 72 shorts = 144 B = 36 words (36 % 32 = 4): 16-row frag reads are <=2-way.
  __shared__ __align__(16) unsigned short cth[64*72],  ctl[64*72];
  __shared__ __align__(16) unsigned short w1sh[64*72], w1sl[64*72];
  __shared__ __align__(16) unsigned short w2sh[64*72], w2sl[64*72];
  __shared__ __align__(16) unsigned short hsh[64*72],  hsl[64*72];
  __shared__ unsigned int sl[64];
  __shared__ float swt[64];

  const int tid  = threadIdx.x;
  const int lane = tid & 63;
  const int wave = tid >> 6;
  const int wm  = (wave >> 1) * 32;   // token offset of this wave
  const int wn  = (wave & 1) * 32;    // col offset of this wave
  const int fml = lane & 15;
  const int q   = lane >> 4;          // 0..3

  if (tid < 64) {
    if (tid < nt) { sl[tid] = list[e*8192 + t0 + tid]; swt[tid] = lw[e*8192 + t0 + tid]; }
    else          { sl[tid] = 0; swt[tid] = 0.f; }
  }
  __syncthreads();

  // gather cont rows + split to hi/lo bf16 (row = token, 16 f32 per thread)
  {
    const int row = tid >> 2;
    const int m0  = (tid & 3) * 16;
    float x[16] = {0.f,0.f,0.f,0.f,0.f,0.f,0.f,0.f,0.f,0.f,0.f,0.f,0.f,0.f,0.f,0.f};
    if (row < nt) {
      const float* p = cont + (size_t)(sl[row] >> 1)*64 + m0;
      *(float4*)&x[0]  = *(const float4*)(p);
      *(float4*)&x[4]  = *(const float4*)(p + 4);
      *(float4*)&x[8]  = *(const float4*)(p + 8);
      *(float4*)&x[12] = *(const float4*)(p + 12);
    }
    unsigned int hp[8], lp[8];
    #pragma unroll
    for (int t = 0; t < 8; ++t) {
      unsigned short h0 = f2bf(x[2*t]);
      unsigned short h1 = f2bf(x[2*t+1]);
      unsigned short l0 = f2bf(x[2*t]   - bf2f(h0));
      unsigned short l1 = f2bf(x[2*t+1] - bf2f(h1));
      hp[t] = (unsigned)h0 | ((unsigned)h1 << 16);
      lp[t] = (unsigned)l0 | ((unsigned)l1 << 16);
    }
    *(uint4*)&cth[row*72 + m0]     = make_uint4(hp[0], hp[1], hp[2], hp[3]);
    *(uint4*)&cth[row*72 + m0 + 8] = make_uint4(hp[4], hp[5], hp[6], hp[7]);
    *(uint4*)&ctl[row*72 + m0]     = make_uint4(lp[0], lp[1], lp[2], lp[3]);
    *(uint4*)&ctl[row*72 + m0 + 8] = make_uint4(lp[4], lp[5], lp[6], lp[7]);
  }

  f32x4 acc2[2][2] = {};

  for (int hc = 0; hc < 1024; hc += 64) {
    // stage this chunk's weights: w1 rows = h-cols (K=m), w2 rows = out-cols (K=h)
    {
      const int row = tid >> 2;
      const int seg = (tid & 3) * 16;
      const size_t o1 = ((size_t)(e*1024 + hc + row))*64 + seg;
      *(uint4*)&w1sh[row*72 + seg]     = *(const uint4*)(w1h + o1);
      *(uint4*)&w1sh[row*72 + seg + 8] = *(const uint4*)(w1h + o1 + 8);
      *(uint4*)&w1sl[row*72 + seg]     = *(const uint4*)(w1l + o1);
      *(uint4*)&w1sl[row*72 + seg + 8] = *(const uint4*)(w1l + o1 + 8);
      const size_t o2 = ((size_t)(e*64 + row))*1024 + hc + seg;
      *(uint4*)&w2sh[row*72 + seg]     = *(const uint4*)(w2h + o2);
      *(uint4*)&w2sh[row*72 + seg + 8] = *(const uint4*)(w2h + o2 + 8);
      *(uint4*)&w2sl[row*72 + seg]     = *(const uint4*)(w2l + o2);
      *(uint4*)&w2sl[row*72 + seg + 8] = *(const uint4*)(w2l + o2 + 8);
    }
    __syncthreads();

    // GEMM1: h[t][col] = sum_m ct[t][m] * w1[col][m], K=64
    f32x4 acc1[2][2] = {};
    #pragma unroll
    for (int ks = 0; ks < 2; ++ks) {
      bf16x8 ah[2], al[2], bh[2], bl[2];
      #pragma unroll
      for (int i = 0; i < 2; ++i) {
        ah[i] = *(const bf16x8*)&cth[(wm + i*16 + fml)*72 + ks*32 + q*8];
        al[i] = *(const bf16x8*)&ctl[(wm + i*16 + fml)*72 + ks*32 + q*8];
      }
      #pragma unroll
      for (int j = 0; j < 2; ++j) {
        bh[j] = *(const bf16x8*)&w1sh[(wn + j*16 + fml)*72 + ks*32 + q*8];
        bl[j] = *(const bf16x8*)&w1sl[(wn + j*16 + fml)*72 + ks*32 + q*8];
      }
      #pragma unroll
      for (int i = 0; i < 2; ++i)
        #pragma unroll
        for (int j = 0; j < 2; ++j) {
          acc1[i][j] = __builtin_amdgcn_mfma_f32_16x16x32_bf16(al[i], bh[j], acc1[i][j], 0, 0, 0);
          acc1[i][j] = __builtin_amdgcn_mfma_f32_16x16x32_bf16(ah[i], bl[j], acc1[i][j], 0, 0, 0);
          acc1[i][j] = __builtin_amdgcn_mfma_f32_16x16x32_bf16(ah[i], bh[j], acc1[i][j], 0, 0, 0);
        }
    }

    // bias + relu + split to hi/lo, write h to LDS (C/D: col=lane&15, row=q*4+r)
    #pragma unroll
    for (int j = 0; j < 2; ++j) {
      const int col = wn + j*16 + fml;
      const float b1 = eb1[(size_t)e*1024 + hc + col];
      #pragma unroll
      for (int i = 0; i < 2; ++i) {
        #pragma unroll
        for (int r = 0; r < 4; ++r) {
          const int trow = wm + i*16 + q*4 + r;
          float v = fmaxf(acc1[i][j][r] + b1, 0.f);
          unsigned short hh = f2bf(v);
          hsh[trow*72 + col] = hh;
          hsl[trow*72 + col] = f2bf(v - bf2f(hh));
        }
      }
    }
    __syncthreads();

    // GEMM2: out[t][n] += sum_h hs[t][h] * w2[n][h], K=64
    #pragma unroll
    for (int ks = 0; ks < 2; ++ks) {
      bf16x8 ah[2], al[2], bh[2], bl[2];
      #pragma unroll
      for (int i = 0; i < 2; ++i) {
        ah[i] = *(const bf16x8*)&hsh[(wm + i*16 + fml)*72 + ks*32 + q*8];
        al[i] = *(const bf16x8*)&hsl[(wm + i*16 + fml)*72 + ks*32 + q*8];
      }
      #pragma unroll
      for (int j = 0; j < 2; ++j) {
        bh[j] = *(const bf16x8*)&w2sh[(wn + j*16 + fml)*72 + ks*32 + q*8];
        bl[j] = *(const bf16x8*)&w2sl[(wn + j*16 + fml)*72 + ks*32 + q*8];
      }
      #pragma unroll
      for (int i = 0; i < 2; ++i)
        #pragma unroll
        for (int j = 0; j < 2; ++j) {
          acc2[i][j] = __builtin_amdgcn_mfma_f32_16x16x32_bf16(al[i], bh[j], acc2[i][j], 0, 0, 0);
          acc2[i][j] = __builtin_amdgcn_mfma_f32_16x16x32_bf16(ah[i], bl[j], acc2[i][j], 0, 0, 0);
          acc2[i][j] = __builtin_amdgcn_mfma_f32_16x16x32_bf16(ah[i], bh[j], acc2[i][j], 0, 0, 0);
        }
    }
    __syncthreads();   // before next chunk overwrites w1s/w2s/hs
  }

  // epilogue: eout[slot][n] = w * (acc + b2)
  #pragma unroll
  for (int j = 0; j < 2; ++j) {
    const int col = wn + j*16 + fml;
    const float b2 = eb2[(size_t)e*64 + col];
    #pragma unroll
    for (int i = 0; i < 2; ++i) {
      #pragma unroll
      for (int r = 0; r < 4; ++r) {
        const int trow = wm + i*16 + q*4 + r;
        if (trow < nt)
          eout[(size_t)sl[trow]*64 + col] = swt[trow]*(acc2[i][j][r] + b2);
      }
    }
  }
}

// ---------------------------------------------------------------- c2s MFMA GEMM, split-bf16 (3 products)
__global__ __launch_bounds__(256) void k_c2sM(
    const float* __restrict__ eoutTok,        // [T][128]
    const unsigned short* __restrict__ WTh,   // [2048][64] bf16 hi
    const unsigned short* __restrict__ WTl,   // [2048][64] bf16 lo
    const float* __restrict__ bias,           // [2048]
    unsigned short* __restrict__ rates)       // [T][2048]
{
  __shared__ __align__(16) unsigned short Ahs[128*72], Als[128*72];
  __shared__ __align__(16) unsigned short Bhs[128*72], Bls[128*72];
  const int tid  = threadIdx.x;
  const int lane = tid & 63;
  const int wave = tid >> 6;
  const int wm = (wave >> 1) * 64;
  const int wn = (wave & 1) * 64;
  const int bm = blockIdx.y * 128;
  const int bn = blockIdx.x * 128;
  const int fml = lane & 15;
  const int q  = lane >> 4;

  {
    const int row = tid >> 1;          // 0..127
    const int m0  = (tid & 1) * 32;    // 0 or 32
    const float* p = eoutTok + (size_t)(bm + row)*128 + m0;
    float x[32];
    #pragma unroll
    for (int i = 0; i < 8; ++i) {
      float4 a = *(const float4*)(p + i*4);
      float4 b = *(const float4*)(p + 64 + i*4);
      x[i*4+0] = a.x + b.x; x[i*4+1] = a.y + b.y;
      x[i*4+2] = a.z + b.z; x[i*4+3] = a.w + b.w;
    }
    unsigned int hp[16], lp[16];
    #pragma unroll
    for (int t = 0; t < 16; ++t) {
      unsigned short h0 = f2bf(x[2*t]);
      unsigned short h1 = f2bf(x[2*t+1]);
      unsigned short l0 = f2bf(x[2*t]   - bf2f(h0));
      unsigned short l1 = f2bf(x[2*t+1] - bf2f(h1));
      hp[t] = (unsigned)h0 | ((unsigned)h1 << 16);
      lp[t] = (unsigned)l0 | ((unsigned)l1 << 16);
    }
    #pragma unroll
    for (int t = 0; t < 4; ++t) {
      *(uint4*)&Ahs[row*72 + m0 + t*8] = make_uint4(hp[t*4+0],hp[t*4+1],hp[t*4+2],hp[t*4+3]);
      *(uint4*)&Als[row*72 + m0 + t*8] = make_uint4(lp[t*4+0],lp[t*4+1],lp[t*4+2],lp[t*4+3]);
    }
    const unsigned short* ph = WTh + (size_t)(bn + row)*64 + m0;
    const unsigned short* pl = WTl + (size_t)(bn + row)*64 + m0;
    #pragma unroll
    for (int t = 0; t < 4; ++t) {
      *(uint4*)&Bhs[row*72 + m0 + t*8] = *(const uint4*)(ph + t*8);
      *(uint4*)&Bls[row*72 + m0 + t*8] = *(const uint4*)(pl + t*8);
    }
  }
  __syncthreads();

  f32x4 acc[4][4] = {};
  #pragma unroll
  for (int ks = 0; ks < 2; ++ks) {
    bf16x8 ah[4], al[4], bh[4], bl[4];
    #pragma unroll
    for (int i = 0; i < 4; ++i) {
      ah[i] = *(const bf16x8*)&Ahs[(wm + i*16 + fml)*72 + ks*32 + q*8];
      al[i] = *(const bf16x8*)&Als[(wm + i*16 + fml)*72 + ks*32 + q*8];
    }
    #pragma unroll
    for (int j = 0; j < 4; ++j) {
      bh[j] = *(const bf16x8*)&Bhs[(wn + j*16 + fml)*72 + ks*32 + q*8];
      bl[j] = *(const bf16x8*)&Bls[(wn + j*16 + fml)*72 + ks*32 + q*8];
    }
    #pragma unroll
    for (int i = 0; i < 4; ++i)
      #pragma unroll
      for (int j = 0; j < 4; ++j) {
        acc[i][j] = __builtin_amdgcn_mfma_f32_16x16x32_bf16(al[i], bh[j], acc[i][j], 0, 0, 0);
        acc[i][j] = __builtin_amdgcn_mfma_f32_16x16x32_bf16(ah[i], bl[j], acc[i][j], 0, 0, 0);
        acc[i][j] = __builtin_amdgcn_mfma_f32_16x16x32_bf16(ah[i], bh[j], acc[i][j], 0, 0, 0);
      }
  }

  #pragma unroll
  for (int j = 0; j < 4; ++j) {
    const int col = bn + wn + j*16 + fml;
    const float bv = bias[col];
    #pragma unroll
    for (int i = 0; i < 4; ++i) {
      #pragma unroll
      for (int r = 0; r < 4; ++r) {
        const int row = bm + wm + i*16 + q*4 + r;
        rates[(size_t)row*H_ + col] = f2bf(sigf(acc[i][j][r] + bv));
      }
    }
  }
}

// ---------------------------------------------------------------- c2s 256-col slice -> f32 (fallback path)
__global__ __launch_bounds__(256) void k_c2sS(const float* __restrict__ eoutTok,
    const float* __restrict__ W, int coff,
    const float* __restrict__ bias, float* __restrict__ rat)
{
  __shared__ float ml[8][64];
  const int tid = threadIdx.x;
  const int n0 = blockIdx.x * 8;
  for (int i = tid; i < 512; i += 256) {
    int t = i >> 6, m = i & 63;
    ml[t][m] = eoutTok[(size_t)(n0+t)*128 + m] + eoutTok[(size_t)(n0+t)*128 + 64 + m];
  }
  __syncthreads();
  float acc[8] = {};
  for (int m = 0; m < 64; ++m) {
    float wv = W[(size_t)m*H_ + coff + tid];
    #pragma unroll
    for (int t = 0; t < 8; ++t) acc[t] += ml[t][m] * wv;
  }
  float bv = bias[coff + tid];
  #pragma unroll
  for (int t = 0; t < 8; ++t)
    rat[(size_t)(n0+t)*256 + tid] = sigf(acc[t] + bv);
}

// ---------------------------------------------------------------- f32 -> bf16 transpose (dec_W [R][C] -> out [C][R])
__global__ __launch_bounds__(256) void k_transb(const float* __restrict__ in,
    unsigned short* __restrict__ out, int R, int C) {
  __shared__ unsigned short t[32][33];
  int c0 = blockIdx.x*32, r0 = blockIdx.y*32;
  int tx = threadIdx.x & 31, ty = threadIdx.x >> 5;
  #pragma unroll
  for (int i = 0; i < 32; i += 8)
    t[ty+i][tx] = f2bf(in[(size_t)(r0+ty+i)*C + (c0+tx)]);
  __syncthreads();
  #pragma unroll
  for (int i = 0; i < 32; i += 8)
    out[(size_t)(c0+ty+i)*R + (r0+tx)] = t[tx][ty+i];
}

// ---------------------------------------------------------------- dec MFMA GEMM + XCD bijective swizzle
__global__ __launch_bounds__(256) void k_dgemm(
    const unsigned short* __restrict__ A,
    const unsigned short* __restrict__ BT,
    const float* __restrict__ bias,
    const float* __restrict__ gains,
    float* __restrict__ C)
{
  __shared__ __align__(16) unsigned short As[128*40];
  __shared__ __align__(16) unsigned short Bs[128*40];
  const int tid  = threadIdx.x;
  const int lane = tid & 63;
  const int wave = tid >> 6;
  const int wm = (wave >> 1) * 64;
  const int wn = (wave & 1) * 64;
  // XCD-aware bijective swizzle: nwg = 8*gy (%8==0)
  const int gy   = gridDim.y;
  const int flat = blockIdx.y * 8 + blockIdx.x;
  const int swz  = (flat & 7) * gy + (flat >> 3);
  const int bn = (swz & 7) * 128;
  const int bm = (swz >> 3) * 128;
  const int fml = lane & 15;
  const int q  = lane >> 4;
  const int r0a  = tid >> 2;
  const int sseg = tid & 3;

  f32x4 acc[4][4] = {};

  for (int k0 = 0; k0 < H_; k0 += 32) {
    #pragma unroll
    for (int half = 0; half < 2; ++half) {
      int r = r0a + half*64;
      *(uint4*)(&As[r*40 + sseg*8]) = *(const uint4*)(A + (size_t)(bm + r)*H_ + k0 + sseg*8);
      *(uint4*)(&Bs[r*40 + sseg*8]) = *(const uint4*)(BT + (size_t)(bn + r)*H_ + k0 + sseg*8);
    }
    __syncthreads();
    bf16x8 af[4], bfr[4];
    #pragma unroll
    for (int i = 0; i < 4; ++i)
      af[i] = *(const bf16x8*)(&As[(wm + i*16 + fml)*40 + q*8]);
    #pragma unroll
    for (int j = 0; j < 4; ++j)
      bfr[j] = *(const bf16x8*)(&Bs[(wn + j*16 + fml)*40 + q*8]);
    #pragma unroll
    for (int i = 0; i < 4; ++i)
      #pragma unroll
      for (int j = 0; j < 4; ++j)
        acc[i][j] = __builtin_amdgcn_mfma_f32_16x16x32_bf16(af[i], bfr[j], acc[i][j], 0, 0, 0);
    __syncthreads();
  }
  #pragma unroll
  for (int i = 0; i < 4; ++i) {
    #pragma unroll
    for (int j = 0; j < 4; ++j) {
      int col = bn + wn + j*16 + fml;
      float bv = bias[col];
      #pragma unroll
      for (int r = 0; r < 4; ++r) {
        int row = bm + wm + i*16 + q*4 + r;
        C[(size_t)row*D_ + col] = gains[row]*acc[i][j][r] + bv;
      }
    }
  }
}

// ---------------------------------------------------------------- layernorm D=1024 in-place
__global__ __launch_bounds__(256) void k_ln(float* __restrict__ X,
    const float* __restrict__ g, const float* __restrict__ b)
{
  const int n = blockIdx.x, tid = threadIdx.x;
  float4* row = (float4*)(X + (size_t)n*D_);
  const float4 xv = row[tid];
  float xa[4] = {xv.x, xv.y, xv.z, xv.w};
  float s = xa[0]+xa[1]+xa[2]+xa[3];
  float ss = xa[0]*xa[0]+xa[1]*xa[1]+xa[2]*xa[2]+xa[3]*xa[3];
  #pragma unroll
  for (int off = 32; off >= 1; off >>= 1) {
    s  += __shfl_down(s, off);
    ss += __shfl_down(ss, off);
  }
  __shared__ float rs[4], rss[4];
  const int lane = tid & 63, wv = tid >> 6;
  if (lane == 0) { rs[wv] = s; rss[wv] = ss; }
  __syncthreads();
  float S0 = rs[0]+rs[1]+rs[2]+rs[3];
  float SS = rss[0]+rss[1]+rss[2]+rss[3];
  float mu = S0 * (1.f/(float)D_);
  float var = SS * (1.f/(float)D_) - mu*mu;
  float inv = rsqrtf(var + 1e-5f);
  int idx = tid*4;
  float4 o;
  o.x = (xa[0]-mu)*inv*g[idx+0] + b[idx+0];
  o.y = (xa[1]-mu)*inv*g[idx+1] + b[idx+1];
  o.z = (xa[2]-mu)*inv*g[idx+2] + b[idx+2];
  o.w = (xa[3]-mu)*inv*g[idx+3] + b[idx+3];
  row[tid] = o;
}

// ----------------------------------------------------------------
// ws layout:
//   [0x000000,0x200000) cont f32[8192][64]
//   [0x200000,0x300000) c2s_WT hi/lo bf16 [2048][64] (path A only)
//   [0x300000,0x380000) s2c_WT hi/lo bf16 [64][2048] (encM only)
//   [0x400000,0x800000) eout f32[16384][64]
//   0x800000 gains | 0x808000 cnt | 0x809000 list | 0x849000 lw
//   [0x890000,0x8D0000) vinitF float[16*4096] (enc+dec GIF, CS=128)
//   0x900000 (4 MiB): WhT (enc) -> expert weights w1th/w1tl/w2th/w2tl -> decWT (dec)
//   0xD00000 (4 MiB): WlT (enc)  -> rates (dec path A, T*4 KiB from 0xD00000)
//   [0x1100000,0x3100000) encAh/encAl bf16 [8192][1024] each (enc pre-split, needs ws>=50 MiB)
// Enc scratch cur f32[8192][1024] = 32 MiB per H-chunk lives in d_out.
extern "C" void kernel_launch(void* const* d_in, const int* in_sizes, int n_in,
                              void* d_out, int out_size, void* d_ws, size_t ws_size,
                              hipStream_t stream) {
  (void)in_sizes; (void)n_in; (void)out_size;
  const float* embeds = (const float*)d_in[0];
  const int*   ids    = (const int*)d_in[1];
  const float* pros   = (const float*)d_in[2];
  const float* enc_W  = (const float*)d_in[3];
  const float* enc_b  = (const float*)d_in[4];
  const float* s2c_W  = (const float*)d_in[5];
  const float* s2c_b  = (const float*)d_in[6];
  const float* r_W1   = (const float*)d_in[7];
  const float* r_b1   = (const float*)d_in[8];
  const float* r_W2   = (const float*)d_in[9];
  const float* r_b2   = (const float*)d_in[10];
  const float* e_W1   = (const float*)d_in[11];
  const float* e_b1   = (const float*)d_in[12];
  const float* e_W2   = (const float*)d_in[13];
  const float* e_b2   = (const float*)d_in[14];
  const float* c2s_W  = (const float*)d_in[15];
  const float* c2s_b  = (const float*)d_in[16];
  const float* dec_W  = (const float*)d_in[17];
  const float* dec_b  = (const float*)d_in[18];
  const float* ln_g   = (const float*)d_in[19];
  const float* ln_b   = (const float*)d_in[20];

  char* ws = (char*)d_ws;
  float*          contp = (float*)ws;
  unsigned short* c2sWTh= (unsigned short*)(ws + (size_t)0x200000); // 256 KiB
  unsigned short* c2sWTl= (unsigned short*)(ws + (size_t)0x280000); // 256 KiB
  unsigned short* s2cWTh= (unsigned short*)(ws + (size_t)0x300000); // 256 KiB
  unsigned short* s2cWTl= (unsigned short*)(ws + (size_t)0x340000); // 256 KiB
  float*          eout  = (float*)(ws + (size_t)0x400000);
  float*          gains = (float*)(ws + (size_t)0x800000);
  int*            cnt   = (int*)(ws + (size_t)0x808000);
  unsigned int*   list  = (unsigned int*)(ws + (size_t)0x809000);
  float*          lw    = (float*)(ws + (size_t)0x849000);
  float*          vinitF= (float*)(ws + (size_t)0x890000);          // GIF f32 (256 KiB)
  unsigned short* WhT   = (unsigned short*)(ws + (size_t)0x900000); // -> expert w / decWT
  unsigned short* WlT   = (unsigned short*)(ws + (size_t)0xD00000); // -> rates
  unsigned short* encAh = (unsigned short*)(ws + (size_t)0x1100000); // 16 MiB (enc only)
  unsigned short* encAl = (unsigned short*)(ws + (size_t)0x2100000); // 16 MiB (enc only)
  unsigned short* decWT = WhT;
  unsigned short* rates = WlT;
  float*          ratSf = (float*)ws;              // fallback overlay of cont
  float*          cur   = (float*)d_out;           // enc scratch [8192][1024]

  // expert split-bf16 weights live in the WhT window between enc GEMM and k_transb
  unsigned short* w1th = WhT;                         // [8][1024][64] 1 MiB
  unsigned short* w1tl = w1th + (size_t)8*1024*64;    // 1 MiB
  unsigned short* w2th = w1tl + (size_t)8*1024*64;    // [8][64][1024] 1 MiB
  unsigned short* w2tl = w2th + (size_t)8*1024*64;    // 1 MiB (ends at 0xD00000)

  const int encM  = (ws_size >= (size_t)18*1024*1024) ? 1 : 0;
  const int encPA = (encM && ws_size >= (size_t)50*1024*1024) ? 1 : 0;
  const int T = (ws_size >= (size_t)46*1024*1024) ? 8192
              : (ws_size >= (size_t)30*1024*1024) ? 4096 : 0;

  k_gains<<<N_TOK/256, 256, 0, stream>>>(ids, pros, gains, cnt);

  // ---- encoder: 2 H-chunks of 1024; GIF f32 at CS=128; MFMA s2c (K-split x4, atomic) ----
  if (encM) {
    hipMemsetAsync(contp, 0, (size_t)N_TOK*64*sizeof(float), stream);
    k_splitT<<<dim3(64, 32), 256, 0, stream>>>(enc_W, WhT, WlT);
    k_tsplit<<<dim3(2, 64, 1), 256, 0, stream>>>(s2c_W, s2cWTh, s2cWTl, 2048, 64);
    if (encPA)
      k_asplit<<<4096, 256, 0, stream>>>(embeds, encAh, encAl);
    for (int c = 0; c < 2; ++c) {
      if (encPA) {
        k_egemm3<<<dim3(8, 64), 256, 0, stream>>>(
            encAh, encAl, WhT + (size_t)c*1024*1024, WlT + (size_t)c*1024*1024,
            enc_b + c*1024, gains, cur);
      } else {
        k_egemm<<<dim3(8, 64), 256, 0, stream>>>(
            embeds, WhT + (size_t)c*1024*1024, WlT + (size_t)c*1024*1024,
            enc_b + c*1024, gains, cur);
      }
      k_gif_warm32<<<dim3(16, 16), 256, 0, stream>>>(cur, vinitF, 1024, 128, S_);
      k_gif_emit32<<<dim3(16, 16), 256, 0, stream>>>(cur, vinitF, 1024, 128, S_);
      k_s2cM<<<dim3(N_TOK/64, 4), 256, 0, stream>>>(cur, s2cWTh, s2cWTl, (size_t)c*1024,
          contp, (c == 1) ? s2c_b : (const float*)nullptr);
    }
    // enc done reading WhT/WlT -> build expert split-bf16 weights in that window
    k_tsplit<<<dim3(32, 2, 8), 256, 0, stream>>>(e_W1, w1th, w1tl, 64, 1024);
    k_tsplit<<<dim3(2, 32, 8), 256, 0, stream>>>(e_W2, w2th, w2tl, 1024, 64);
  } else {
    for (int c = 0; c < 2; ++c) {
      k_genc<<<dim3(8, 64), 256, 0, stream>>>(
          embeds, D_, enc_W, H_, c*1024, enc_b, gains, cur, 1024, D_, 3);
      k_gif_warm32<<<dim3(16, 16), 256, 0, stream>>>(cur, vinitF, 1024, 128, S_);
      k_gif_emit32<<<dim3(16, 16), 256, 0, stream>>>(cur, vinitF, 1024, 128, S_);
      k_s2c<<<N_TOK/16, 256, 0, stream>>>(cur, 1024, 1024,
          s2c_W, (size_t)c*1024*64, contp, (c > 0),
          (c == 1) ? s2c_b : (const float*)nullptr);
    }
  }

  // ---- router: fused hidden + top-2 (f32) ----
  k_router2<<<N_TOK/16, 256, 0, stream>>>(contp, r_W1, r_b1, r_W2, r_b2,
                                          gains, cnt, list, lw);

  if (encM) {
    k_expmfma<<<dim3(128, 8), 256, 0, stream>>>(contp, list, lw, cnt,
        w1th, w1tl, e_b1, w2th, w2tl, e_b2, eout);
  } else {
    k_expgrp<<<dim3(128, 8), 256, 0, stream>>>(contp, list, lw, cnt,
        e_W1, e_b1, e_W2, e_b2, eout);
  }

  if (T > 0) {
    // ---- decoder path A: bf16 MFMA; GIF f32 at CS=128 ----
    k_transb<<<dim3(32, 64), 256, 0, stream>>>(dec_W, decWT, H_, D_);
    k_tsplit<<<dim3(64, 2, 1), 256, 0, stream>>>(c2s_W, c2sWTh, c2sWTl, 64, H_);
    for (int tok0 = 0; tok0 < N_TOK; tok0 += T) {
      k_c2sM<<<dim3(H_/128, T/128), 256, 0, stream>>>(eout + (size_t)tok0*128,
          c2sWTh, c2sWTl, c2s_b, rates);
      float* cur2 = (float*)d_out + (size_t)tok0*D_;
      k_dgemm<<<dim3(D_/128, T/128), 256, 0, stream>>>(
          rates, decWT, dec_b, gains + tok0, cur2);
      int channels = (T/2048)*1024;
      k_gif_warm32<<<dim3(channels/256, 16), 256, 0, stream>>>(cur2, vinitF, D_, 128, S_);
      k_gif_emit32<<<dim3(channels/256, 16), 256, 0, stream>>>(cur2, vinitF, D_, 128, S_);
      k_ln<<<T, 256, 0, stream>>>(cur2, ln_g, ln_b);
    }
  } else {
    // ---- decoder fallback: f32 SIMT, 2 halves x 8 K-slices ----
    for (int hb = 0; hb < 2; ++hb) {
      float* cur2 = (float*)d_out + (size_t)hb*4096*D_;
      for (int kh = 0; kh < 8; ++kh) {
        k_c2sS<<<4096/8, 256, 0, stream>>>(eout + (size_t)hb*4096*128,
            c2s_W, kh*256, c2s_b, ratSf);
        int mode = (kh == 0) ? 0 : ((kh < 7) ? 1 : 2);
        k_genc<<<dim3(8, 32), 256, 0, stream>>>(
            ratSf, 256, dec_W + (size_t)kh*256*D_, D_, 0, dec_b,
            gains + hb*4096, cur2, D_, 256, mode);
      }
      k_gif_warm32<<<dim3(8, 16), 256, 0, stream>>>(cur2, vinitF, D_, 128, S_);
      k_gif_emit32<<<dim3(8, 16), 256, 0, stream>>>(cur2, vinitF, D_, 128, S_);
      k_ln<<<4096, 256, 0, stream>>>(cur2, ln_g, ln_b);
    }
  }
}